// Round 3
// baseline (702.917 us; speedup 1.0000x reference)
//
#include <hip/hip_runtime.h>
#include <stdint.h>

// ---------------------------------------------------------------------------
// decoder_80487687127254 : B=4096 T=7 H=512 L=256 D=1024
// Pipeline: softsign(noise@W) -> biLSTM -> growing-key attention -> GEMM ->
//           3x deconv + softmax(axis=H) -> out (4096,7,3,24) f32
// ---------------------------------------------------------------------------

typedef __attribute__((ext_vector_type(4))) float f32x4;
typedef __attribute__((ext_vector_type(8))) short bf16x8;
typedef __attribute__((ext_vector_type(4))) unsigned short us4;

__device__ __forceinline__ unsigned short f2b(float f) {
  union { float f; unsigned u; } x; x.f = f;
  unsigned r = x.u + 0x7FFFu + ((x.u >> 16) & 1u);   // RNE
  return (unsigned short)(r >> 16);
}
__device__ __forceinline__ float b2f(unsigned short s) {
  union { unsigned u; float f; } x; x.u = ((unsigned)s) << 16; return x.f;
}
__device__ __forceinline__ float sigmoidf(float x) {
  return 1.f / (1.f + __expf(-x));
}
__device__ __forceinline__ float fast_tanh(float x) {
  x = fminf(15.f, fmaxf(-15.f, x));
  float e = __expf(2.f * x);
  return (e - 1.f) / (e + 1.f);
}

// async global->LDS, 16B per lane; LDS dest = wave-uniform base + lane*16
__device__ __forceinline__ void gl_lds16(const void* g, void* l) {
  auto gp = reinterpret_cast<const __attribute__((address_space(1))) unsigned int*>(
      reinterpret_cast<uintptr_t>(g));
  auto lp = reinterpret_cast<__attribute__((address_space(3))) unsigned int*>(
      reinterpret_cast<uintptr_t>(l));
  __builtin_amdgcn_global_load_lds(gp, lp, 16, 0, 0);
}

// stage a 128x64 bf16 tile (row-major, linear LDS). src points at (row0,col0).
__device__ __forceinline__ void stage128x64(const unsigned short* src, int ld,
                                            unsigned short* lds, int wv, int lane) {
#pragma unroll
  for (int r = 0; r < 4; ++r) {
    int row = r * 32 + wv * 8 + (lane >> 3);
    int col = (lane & 7) * 8;
    gl_lds16(src + (size_t)row * ld + col, lds + (r * 32 + wv * 8) * 64);
  }
}

// 128x128 tile compute: 4 waves (2x2), acc[4][4] of 16x16 frags, BK=64
__device__ __forceinline__ void mfma_tile(const unsigned short* As, const unsigned short* Bs,
                                          int wm, int wn, int lane, f32x4 acc[4][4]) {
#pragma unroll
  for (int kk = 0; kk < 2; ++kk) {
    int ko = kk * 32 + (lane >> 4) * 8;
    bf16x8 a[4], b[4];
#pragma unroll
    for (int i = 0; i < 4; ++i)
      a[i] = *(const bf16x8*)(As + (size_t)(wm * 64 + i * 16 + (lane & 15)) * 64 + ko);
#pragma unroll
    for (int i = 0; i < 4; ++i)
      b[i] = *(const bf16x8*)(Bs + (size_t)(wn * 64 + i * 16 + (lane & 15)) * 64 + ko);
#pragma unroll
    for (int mi = 0; mi < 4; ++mi)
#pragma unroll
      for (int ni = 0; ni < 4; ++ni)
        acc[mi][ni] = __builtin_amdgcn_mfma_f32_16x16x32_bf16(a[mi], b[ni], acc[mi][ni], 0, 0, 0);
  }
}

#define ACC_ZERO(acc)                                   \
  _Pragma("unroll") for (int _i = 0; _i < 4; ++_i)      \
  _Pragma("unroll") for (int _j = 0; _j < 4; ++_j)      \
      acc[_i][_j] = (f32x4){0.f, 0.f, 0.f, 0.f};

// ---------------------------------------------------------------------------
// pack: bf16 conversions + transposes + LSTM weight gate-interleave
// ---------------------------------------------------------------------------
__global__ __launch_bounds__(256) void pack_kernel(
    const float* __restrict__ noise, const float* __restrict__ erep_w,
    const float* __restrict__ emb_w,
    const float* __restrict__ wih_f, const float* __restrict__ whh_f,
    const float* __restrict__ bih_f, const float* __restrict__ bhh_f,
    const float* __restrict__ wih_b, const float* __restrict__ whh_b,
    const float* __restrict__ bih_b, const float* __restrict__ bhh_b,
    unsigned short* __restrict__ noiseb, unsigned short* __restrict__ erepT,
    unsigned short* __restrict__ embT, unsigned short* __restrict__ lstmW,
    float* __restrict__ lstmB) {
  const int N0 = 4096 * 256;      // noise
  const int N1 = 1792 * 256;      // erepT
  const int N2 = 1024 * 1024;     // embT
  const int N3 = 2 * 2048 * 768;  // lstmW
  const int N4 = 2 * 2048;        // lstmB
  const int total = N0 + N1 + N2 + N3 + N4;
  for (int i = blockIdx.x * 256 + threadIdx.x; i < total; i += gridDim.x * 256) {
    int x = i;
    if (x < N0) { noiseb[x] = f2b(noise[x]); continue; }
    x -= N0;
    if (x < N1) { int n = x >> 8, k = x & 255; erepT[x] = f2b(erep_w[k * 1792 + n]); continue; }
    x -= N1;
    if (x < N2) {
      int n = x >> 10, k = x & 1023;
      int o = (n & 63) * 16 + (n >> 6);
      embT[x] = f2b(emb_w[k * 1024 + o]);
      continue;
    }
    x -= N2;
    if (x < N3) {
      int dir = x / (2048 * 768);
      int r = x - dir * (2048 * 768);
      int npk = r / 768, k = r - (r / 768) * 768;
      int blk = npk >> 6, g = (npk >> 4) & 3, u = npk & 15;
      int o = g * 512 + blk * 16 + u;
      const float* wih = dir ? wih_b : wih_f;
      const float* whh = dir ? whh_b : whh_f;
      float v = (k < 256) ? wih[k * 2048 + o] : whh[(k - 256) * 2048 + o];
      lstmW[x] = f2b(v);
      continue;
    }
    x -= N3;
    {
      int dir = x >> 11, npk = x & 2047;
      int blk = npk >> 6, g = (npk >> 4) & 3, u = npk & 15;
      int o = g * 512 + blk * 16 + u;
      lstmB[x] = dir ? (bih_b[o] + bhh_b[o]) : (bih_f[o] + bhh_f[o]);
    }
  }
}

// ---------------------------------------------------------------------------
// rep = softsign(noise @ erep_w + b), stored as rep_t[t][b][l] bf16
// ---------------------------------------------------------------------------
__global__ __launch_bounds__(256) void gemm_rep_kernel(
    const unsigned short* __restrict__ A, const unsigned short* __restrict__ Bt,
    const float* __restrict__ bias, unsigned short* __restrict__ rep_t) {
  __shared__ unsigned short As[128 * 64];
  __shared__ unsigned short Bs[128 * 64];
  const int lane = threadIdx.x & 63, wv = threadIdx.x >> 6;
  const int wm = wv >> 1, wn = wv & 1;
  const int m0 = blockIdx.y * 128, n0 = blockIdx.x * 128;
  f32x4 acc[4][4];
  ACC_ZERO(acc)
  for (int k0 = 0; k0 < 256; k0 += 64) {
    stage128x64(A + (size_t)m0 * 256 + k0, 256, As, wv, lane);
    stage128x64(Bt + (size_t)n0 * 256 + k0, 256, Bs, wv, lane);
    __syncthreads();
    mfma_tile(As, Bs, wm, wn, lane, acc);
    __syncthreads();
  }
#pragma unroll
  for (int ni = 0; ni < 4; ++ni) {
    int n = n0 + wn * 64 + ni * 16 + (lane & 15);
    float bv = bias[n];
    int t = n >> 8, l = n & 255;
#pragma unroll
    for (int mi = 0; mi < 4; ++mi)
#pragma unroll
      for (int r = 0; r < 4; ++r) {
        int m = m0 + wm * 64 + mi * 16 + (lane >> 4) * 4 + r;
        float v = acc[mi][ni][r] + bv;
        v = v / (1.f + fabsf(v));
        rep_t[((size_t)t * 4096 + m) * 256 + l] = f2b(v);
      }
  }
}

// ---------------------------------------------------------------------------
// one LSTM step, both directions: gates = [x_t|h] @ Wp + bias, fused cell.
// ---------------------------------------------------------------------------
__global__ __launch_bounds__(256) void lstm_step_kernel(
    const unsigned short* __restrict__ rep_t, const unsigned short* __restrict__ Wp,
    const float* __restrict__ biasP, unsigned short* __restrict__ hbuf,
    float* __restrict__ cbuf, unsigned short* __restrict__ lstm1, int step) {
  __shared__ unsigned short As[128 * 64];
  __shared__ unsigned short Bs[128 * 64];
  const int lane = threadIdx.x & 63, wv = threadIdx.x >> 6;
  const int wm = wv >> 1, wn = wv & 1;
  const int m0 = blockIdx.y * 128, n0 = blockIdx.x * 128;
  const int dir = blockIdx.z;
  const int t_proc = dir ? (6 - step) : step;
  const unsigned short* W = Wp + (size_t)dir * 2048 * 768;
  const unsigned short* hin = hbuf + ((size_t)(step & 1) * 2 + dir) * (4096 * 512);
  unsigned short* hout = hbuf + ((size_t)((step + 1) & 1) * 2 + dir) * (4096 * 512);
  float* cp = cbuf + (size_t)dir * (4096 * 512);
  const unsigned short* xsrc = rep_t + (size_t)t_proc * 4096 * 256;

  f32x4 acc[4][4];
  ACC_ZERO(acc)
  for (int k0 = 0; k0 < 768; k0 += 64) {
    if (k0 < 256)
      stage128x64(xsrc + (size_t)m0 * 256 + k0, 256, As, wv, lane);
    else
      stage128x64(hin + (size_t)m0 * 512 + (k0 - 256), 512, As, wv, lane);
    stage128x64(W + (size_t)n0 * 768 + k0, 768, Bs, wv, lane);
    __syncthreads();
    mfma_tile(As, Bs, wm, wn, lane, acc);
    __syncthreads();
  }
  const int u = lane & 15;
  const int blk = (n0 + wn * 64) >> 6;
  const int j = blk * 16 + u;
  const float bz0 = biasP[dir * 2048 + blk * 64 + 0 * 16 + u];
  const float bz1 = biasP[dir * 2048 + blk * 64 + 1 * 16 + u];
  const float bz2 = biasP[dir * 2048 + blk * 64 + 2 * 16 + u];
  const float bz3 = biasP[dir * 2048 + blk * 64 + 3 * 16 + u];
#pragma unroll
  for (int mi = 0; mi < 4; ++mi)
#pragma unroll
    for (int r = 0; r < 4; ++r) {
      int row = m0 + wm * 64 + mi * 16 + (lane >> 4) * 4 + r;
      float gi = acc[mi][0][r] + bz0;
      float gf = acc[mi][1][r] + bz1;
      float gg = acc[mi][2][r] + bz2;
      float go = acc[mi][3][r] + bz3;
      size_t ci = (size_t)row * 512 + j;
      float c = sigmoidf(gf) * cp[ci] + sigmoidf(gi) * fast_tanh(gg);
      cp[ci] = c;
      float h = sigmoidf(go) * fast_tanh(c);
      unsigned short hb = f2b(h);
      hout[ci] = hb;
      lstm1[((size_t)row * 7 + t_proc) * 1024 + dir * 512 + j] = hb;
    }
}

// ---------------------------------------------------------------------------
// attention part 1: per row, Gram matrix G(7x14) = Q . [E;Q]^T, then the
// 7-step recursion in 7x14 coefficient space -> C written to c_ws.
// Block = 1 row, 4 waves each owning a 256-dim slice (4 f32/lane).
// sG[i*14+7+m] stays 0 for m>=i; sC[j][7+m] stays 0 for m>j.
// ---------------------------------------------------------------------------
__global__ __launch_bounds__(256) void att_gram_kernel(
    const float* __restrict__ enc, const unsigned short* __restrict__ lstm1,
    float* __restrict__ c_ws) {
  __shared__ float part[4][98];
  __shared__ float sG[98];
  __shared__ float sC[7][14];
  __shared__ float sA[16];
  const int tid = threadIdx.x, lane = tid & 63, wv = tid >> 6;
  const int b = blockIdx.x;
  const float* Eb = enc + (size_t)b * 7168;
  const unsigned short* Qb = lstm1 + (size_t)b * 7168;
  const int d0 = wv * 256 + lane * 4;

  for (int x = lane; x < 98; x += 64) part[wv][x] = 0.f;
  if (tid < 98) ((float*)sC)[tid] = 0.f;

  float q[7][4];
#pragma unroll
  for (int i = 0; i < 7; ++i) {
    us4 qv = *(const us4*)(Qb + i * 1024 + d0);
#pragma unroll
    for (int e = 0; e < 4; ++e) q[i][e] = b2f(qv[e]);
  }
  // E dots: G[i][t] partials
#pragma unroll
  for (int t = 0; t < 7; ++t) {
    f32x4 k = *(const f32x4*)(Eb + t * 1024 + d0);
#pragma unroll
    for (int i = 0; i < 7; ++i) {
      float p = q[i][0] * k[0] + q[i][1] * k[1] + q[i][2] * k[2] + q[i][3] * k[3];
#pragma unroll
      for (int off = 32; off >= 1; off >>= 1) p += __shfl_xor(p, off);
      if (lane == 0) part[wv][i * 14 + t] = p;
    }
  }
  // QQ dots (m < i): G[i][7+m] partials
#pragma unroll
  for (int m = 0; m < 6; ++m) {
#pragma unroll
    for (int i = m + 1; i < 7; ++i) {
      float p = q[i][0] * q[m][0] + q[i][1] * q[m][1] + q[i][2] * q[m][2] + q[i][3] * q[m][3];
#pragma unroll
      for (int off = 32; off >= 1; off >>= 1) p += __shfl_xor(p, off);
      if (lane == 0) part[wv][i * 14 + 7 + m] = p;
    }
  }
  __syncthreads();
  if (tid < 98) sG[tid] = part[0][tid] + part[1][tid] + part[2][tid] + part[3][tid];
  __syncthreads();
  if (wv == 0) {
    for (int i = 0; i < 7; ++i) {
      const int nt = 7 + i;
      float s = -1e30f;
      if (lane < 7) {
        s = sG[i * 14 + lane];
      } else if (lane < nt) {
        int j = lane - 7;
        float a2 = 0.f;
#pragma unroll
        for (int v = 0; v < 14; ++v) a2 += sC[j][v] * sG[i * 14 + v];
        s = a2;
      }
      float mx = s;
#pragma unroll
      for (int off = 8; off >= 1; off >>= 1) mx = fmaxf(mx, __shfl_xor(mx, off, 16));
      float e = (lane < nt) ? __expf(s - mx) : 0.f;
      float sum = e;
#pragma unroll
      for (int off = 8; off >= 1; off >>= 1) sum += __shfl_xor(sum, off, 16);
      float a = e / sum;
      if (lane < 16) sA[lane] = a;
      if (lane < 14) {
        float c = (lane < 7) ? sA[lane] : 0.f;
        for (int j = 0; j < i; ++j) c += sA[7 + j] * sC[j][lane];
        if (lane == 7 + i) c += 1.f;
        sC[i][lane] = c;
      }
    }
    for (int x = lane; x < 98; x += 64) c_ws[(size_t)b * 98 + x] = ((float*)sC)[x];
  }
}

// ---------------------------------------------------------------------------
// attention part 2: att rows = C @ [E;Q]. Pure streaming, no reductions.
// Block = 1 row, 4 waves each owning a 256-dim slice (4 f32/lane).
// ---------------------------------------------------------------------------
__global__ __launch_bounds__(256) void att_out_kernel(
    const float* __restrict__ enc, const unsigned short* __restrict__ lstm1,
    const float* __restrict__ c_ws, unsigned short* __restrict__ att) {
  __shared__ float sC[98];
  const int tid = threadIdx.x, lane = tid & 63, wv = tid >> 6;
  const int b = blockIdx.x;
  if (tid < 98) sC[tid] = c_ws[(size_t)b * 98 + tid];
  const float* Eb = enc + (size_t)b * 7168;
  const unsigned short* Qb = lstm1 + (size_t)b * 7168;
  unsigned short* Ab = att + (size_t)b * 7168;
  const int d0 = wv * 256 + lane * 4;
  __syncthreads();
  float acc[7][4];
#pragma unroll
  for (int i = 0; i < 7; ++i)
#pragma unroll
    for (int e = 0; e < 4; ++e) acc[i][e] = 0.f;
#pragma unroll
  for (int v = 0; v < 7; ++v) {
    f32x4 k = *(const f32x4*)(Eb + v * 1024 + d0);
#pragma unroll
    for (int i = 0; i < 7; ++i) {
      float c = sC[i * 14 + v];
#pragma unroll
      for (int e = 0; e < 4; ++e) acc[i][e] += c * k[e];
    }
  }
#pragma unroll
  for (int m = 0; m < 7; ++m) {
    us4 qv = *(const us4*)(Qb + m * 1024 + d0);
    float k[4];
#pragma unroll
    for (int e = 0; e < 4; ++e) k[e] = b2f(qv[e]);
#pragma unroll
    for (int i = m; i < 7; ++i) {   // sC[i][7+m] == 0 for i < m
      float c = sC[i * 14 + 7 + m];
#pragma unroll
      for (int e = 0; e < 4; ++e) acc[i][e] += c * k[e];
    }
  }
#pragma unroll
  for (int i = 0; i < 7; ++i) {
    us4 r;
#pragma unroll
    for (int e = 0; e < 4; ++e) r[e] = f2b(acc[i][e]);
    *(us4*)(Ab + i * 1024 + d0) = r;
  }
}

// ---------------------------------------------------------------------------
// up_t = softsign(att @ emb_w + emb_b), columns permuted so layout = [img][w][ic]
// ---------------------------------------------------------------------------
__global__ __launch_bounds__(256) void gemm_emb_kernel(
    const unsigned short* __restrict__ A, const unsigned short* __restrict__ Bt,
    const float* __restrict__ bias, unsigned short* __restrict__ up_t) {
  __shared__ unsigned short As[128 * 64];
  __shared__ unsigned short Bs[128 * 64];
  const int lane = threadIdx.x & 63, wv = threadIdx.x >> 6;
  const int wm = wv >> 1, wn = wv & 1;
  const int m0 = blockIdx.y * 128, n0 = blockIdx.x * 128;
  f32x4 acc[4][4];
  ACC_ZERO(acc)
  for (int k0 = 0; k0 < 1024; k0 += 64) {
    stage128x64(A + (size_t)m0 * 1024 + k0, 1024, As, wv, lane);
    stage128x64(Bt + (size_t)n0 * 1024 + k0, 1024, Bs, wv, lane);
    __syncthreads();
    mfma_tile(As, Bs, wm, wn, lane, acc);
    __syncthreads();
  }
#pragma unroll
  for (int ni = 0; ni < 4; ++ni) {
    int np = n0 + wn * 64 + ni * 16 + (lane & 15);
    int o = (np & 63) * 16 + (np >> 6);
    float bv = bias[o];
#pragma unroll
    for (int mi = 0; mi < 4; ++mi)
#pragma unroll
      for (int r = 0; r < 4; ++r) {
        int m = m0 + wm * 64 + mi * 16 + (lane >> 4) * 4 + r;
        float v = acc[mi][ni][r] + bv;
        v = v / (1.f + fabsf(v));
        up_t[(size_t)m * 1024 + np] = f2b(v);
      }
  }
}

// ---------------------------------------------------------------------------
// dc3: y1[img,ow,oc] = leaky( sum_{j,ic} up[img,ow-j,ic]*w3[ic,oc,j] + b3[oc] )
// ---------------------------------------------------------------------------
__global__ __launch_bounds__(256) void dc3_kernel(const unsigned short* __restrict__ up_t,
                                                  const float* __restrict__ w3,
                                                  const float* __restrict__ b3,
                                                  unsigned short* __restrict__ y1_t) {
  const int lane = threadIdx.x & 63, wv = threadIdx.x >> 6;
  const int kq = (lane >> 4) * 8;
  const int oc = lane & 15;
  bf16x8 bf[2][6];
#pragma unroll
  for (int nt = 0; nt < 2; ++nt)
#pragma unroll
    for (int kk = 0; kk < 6; ++kk) {
      bf16x8 v;
#pragma unroll
      for (int t = 0; t < 8; ++t) {
        int k = kk * 32 + kq + t;
        int jj = k >> 6, ic = k & 63;
        v[t] = (short)f2b(w3[((size_t)ic * 32 + nt * 16 + oc) * 3 + jj]);
      }
      bf[nt][kk] = v;
    }
  const float bia0 = b3[oc], bia1 = b3[16 + oc];
  const int base_chunk = blockIdx.x * 32 + wv * 8;
  for (int cc = 0; cc < 8; ++cc) {
    const int chunk = base_chunk + cc;
    int m = chunk * 16 + (lane & 15);
    int img = m / 18, ow = m - img * 18;
    const unsigned short* arow = up_t + (size_t)img * 1024;
    f32x4 acc0 = {0.f, 0.f, 0.f, 0.f}, acc1 = {0.f, 0.f, 0.f, 0.f};
#pragma unroll
    for (int kk = 0; kk < 6; ++kk) {
      int jj = kk >> 1;
      int ic0 = (kk & 1) * 32 + kq;
      int iw = ow - jj;
      bf16x8 a = {0, 0, 0, 0, 0, 0, 0, 0};
      if ((unsigned)iw < 16u) a = *(const bf16x8*)(arow + iw * 64 + ic0);
      acc0 = __builtin_amdgcn_mfma_f32_16x16x32_bf16(a, bf[0][kk], acc0, 0, 0, 0);
      acc1 = __builtin_amdgcn_mfma_f32_16x16x32_bf16(a, bf[1][kk], acc1, 0, 0, 0);
    }
#pragma unroll
    for (int r = 0; r < 4; ++r) {
      int mm = chunk * 16 + (lane >> 4) * 4 + r;
      float v0 = acc0[r] + bia0; v0 = v0 > 0.f ? v0 : 0.01f * v0;
      float v1 = acc1[r] + bia1; v1 = v1 > 0.f ? v1 : 0.01f * v1;
      y1_t[(size_t)mm * 32 + oc] = f2b(v0);
      y1_t[(size_t)mm * 32 + 16 + oc] = f2b(v1);
    }
  }
}

// ---------------------------------------------------------------------------
// dc1: y2[img,ow,oc] = leaky( sum_{j<5,ic<32} y1[img,ow-j,ic]*w1[ic,oc,j] + b1[oc] )
// ---------------------------------------------------------------------------
__global__ __launch_bounds__(256) void dc1_kernel(const unsigned short* __restrict__ y1_t,
                                                  const float* __restrict__ w1,
                                                  const float* __restrict__ b1,
                                                  unsigned short* __restrict__ y2_t) {
  const int lane = threadIdx.x & 63, wv = threadIdx.x >> 6;
  const int kq = (lane >> 4) * 8;
  const int oc = lane & 15;
  bf16x8 bf[5];
#pragma unroll
  for (int kk = 0; kk < 5; ++kk) {
    bf16x8 v;
#pragma unroll
    for (int t = 0; t < 8; ++t) {
      int ic = kq + t;
      v[t] = (short)f2b(w1[((size_t)ic * 16 + oc) * 5 + kk]);
    }
    bf[kk] = v;
  }
  const float bia = b1[oc];
  const int base_chunk = blockIdx.x * 32 + wv * 8;
  for (int cc = 0; cc < 8; ++cc) {
    const int chunk = base_chunk + cc;
    int m = chunk * 16 + (lane & 15);
    int img = m / 22, ow = m - img * 22;
    const unsigned short* abase = y1_t + (size_t)img * 18 * 32;
    f32x4 acc = {0.f, 0.f, 0.f, 0.f};
#pragma unroll
    for (int kk = 0; kk < 5; ++kk) {
      int iw = ow - kk;
      bf16x8 a = {0, 0, 0, 0, 0, 0, 0, 0};
      if ((unsigned)iw < 18u) a = *(const bf16x8*)(abase + iw * 32 + kq);
      acc = __builtin_amdgcn_mfma_f32_16x16x32_bf16(a, bf[kk], acc, 0, 0, 0);
    }
#pragma unroll
    for (int r = 0; r < 4; ++r) {
      int mm = chunk * 16 + (lane >> 4) * 4 + r;
      float v = acc[r] + bia;
      v = v > 0.f ? v : 0.01f * v;
      y2_t[(size_t)mm * 16 + oc] = f2b(v);
    }
  }
}

// ---------------------------------------------------------------------------
// dc2 + softmax over oh
// ---------------------------------------------------------------------------
__global__ __launch_bounds__(256) void dc2_kernel(const unsigned short* __restrict__ y2_t,
                                                  const float* __restrict__ w2,
                                                  const float* __restrict__ b2,
                                                  float* __restrict__ out) {
  int idx = blockIdx.x * 256 + threadIdx.x;   // 28672*24 exactly
  int img = idx / 24, ow = idx - img * 24;
  float lg0 = b2[0], lg1 = b2[0], lg2 = b2[0];
#pragma unroll
  for (int jj = 0; jj < 3; ++jj) {
    int iw = ow - jj;
    if ((unsigned)iw >= 22u) continue;
    const unsigned short* row = y2_t + ((size_t)img * 22 + iw) * 16;
    bf16x8 v0 = *(const bf16x8*)(row);
    bf16x8 v1 = *(const bf16x8*)(row + 8);
    float x[16];
#pragma unroll
    for (int ic = 0; ic < 8; ++ic) {
      x[ic] = b2f((unsigned short)v0[ic]);
      x[8 + ic] = b2f((unsigned short)v1[ic]);
    }
#pragma unroll
    for (int ic = 0; ic < 16; ++ic) {
      lg0 += x[ic] * w2[ic * 9 + 0 * 3 + jj];
      lg1 += x[ic] * w2[ic * 9 + 1 * 3 + jj];
      lg2 += x[ic] * w2[ic * 9 + 2 * 3 + jj];
    }
  }
  lg0 = lg0 > 0.f ? lg0 : 0.01f * lg0;
  lg1 = lg1 > 0.f ? lg1 : 0.01f * lg1;
  lg2 = lg2 > 0.f ? lg2 : 0.01f * lg2;
  float mx = fmaxf(lg0, fmaxf(lg1, lg2));
  float e0 = __expf(lg0 - mx), e1 = __expf(lg1 - mx), e2 = __expf(lg2 - mx);
  float inv = 1.f / (e0 + e1 + e2);
  size_t ob = (size_t)img * 72 + ow;
  out[ob] = e0 * inv;
  out[ob + 24] = e1 * inv;
  out[ob + 48] = e2 * inv;
}

// ---------------------------------------------------------------------------
extern "C" void kernel_launch(void* const* d_in, const int* in_sizes, int n_in,
                              void* d_out, int out_size, void* d_ws, size_t ws_size,
                              hipStream_t stream) {
  (void)in_sizes; (void)n_in; (void)out_size; (void)ws_size;
  const float* enc    = (const float*)d_in[0];
  const float* noise  = (const float*)d_in[1];
  const float* erep_w = (const float*)d_in[2];
  const float* erep_b = (const float*)d_in[3];
  const float* wih_f  = (const float*)d_in[4];
  const float* whh_f  = (const float*)d_in[5];
  const float* bih_f  = (const float*)d_in[6];
  const float* bhh_f  = (const float*)d_in[7];
  const float* wih_b  = (const float*)d_in[8];
  const float* whh_b  = (const float*)d_in[9];
  const float* bih_b  = (const float*)d_in[10];
  const float* bhh_b  = (const float*)d_in[11];
  const float* emb_w  = (const float*)d_in[12];
  const float* emb_b  = (const float*)d_in[13];
  const float* dc3w   = (const float*)d_in[14];
  const float* dc3b   = (const float*)d_in[15];
  const float* dc1w   = (const float*)d_in[16];
  const float* dc1b   = (const float*)d_in[17];
  const float* dc2w   = (const float*)d_in[18];
  const float* dc2b   = (const float*)d_in[19];
  float* out = (float*)d_out;

  char* p = (char*)d_ws;
  auto carve = [&p](size_t bytes) {
    char* r = p;
    p += (bytes + 255) & ~(size_t)255;
    return r;
  };
  unsigned short* rep_t  = (unsigned short*)carve(7ull * 4096 * 256 * 2);
  unsigned short* lstmW  = (unsigned short*)carve(2ull * 2048 * 768 * 2);
  float*          lstmB  = (float*)carve(2ull * 2048 * 4);
  unsigned short* noiseb = (unsigned short*)carve(4096ull * 256 * 2);
  unsigned short* erepT  = (unsigned short*)carve(1792ull * 256 * 2);
  unsigned short* embT   = (unsigned short*)carve(1024ull * 1024 * 2);
  unsigned short* hbuf   = (unsigned short*)carve(4ull * 4096 * 512 * 2);   // [pp][dir]
  float*          cbuf   = (float*)carve(2ull * 4096 * 512 * 4);            // [dir]
  unsigned short* lstm1  = (unsigned short*)carve(4096ull * 7 * 1024 * 2);
  float*          c_ws   = (float*)carve(4096ull * 98 * 4);
  unsigned short* att    = (unsigned short*)carve(28672ull * 1024 * 2);
  unsigned short* up_t   = (unsigned short*)carve(28672ull * 1024 * 2);
  unsigned short* y1_t   = (unsigned short*)carve(28672ull * 18 * 32 * 2);
  unsigned short* y2_t   = (unsigned short*)carve(28672ull * 22 * 16 * 2);

  // h0 = c0 = 0 (ping buffers read by step 0)
  hipMemsetAsync(hbuf, 0, 2ull * 4096 * 512 * 2, stream);
  hipMemsetAsync(cbuf, 0, 2ull * 4096 * 512 * 4, stream);

  pack_kernel<<<2048, 256, 0, stream>>>(noise, erep_w, emb_w, wih_f, whh_f, bih_f, bhh_f,
                                        wih_b, whh_b, bih_b, bhh_b,
                                        noiseb, erepT, embT, lstmW, lstmB);
  gemm_rep_kernel<<<dim3(14, 32), 256, 0, stream>>>(noiseb, erepT, erep_b, rep_t);
  for (int s = 0; s < 7; ++s)
    lstm_step_kernel<<<dim3(16, 32, 2), 256, 0, stream>>>(rep_t, lstmW, lstmB, hbuf, cbuf,
                                                          lstm1, s);
  att_gram_kernel<<<4096, 256, 0, stream>>>(enc, lstm1, c_ws);
  att_out_kernel<<<4096, 256, 0, stream>>>(enc, lstm1, c_ws, att);
  gemm_emb_kernel<<<dim3(8, 224), 256, 0, stream>>>(att, embT, emb_b, up_t);
  dc3_kernel<<<1008, 256, 0, stream>>>(up_t, dc3w, dc3b, y1_t);   // 32256 chunks / 32
  dc1_kernel<<<1232, 256, 0, stream>>>(y1_t, dc1w, dc1b, y2_t);   // 39424 chunks / 32
  dc2_kernel<<<2688, 256, 0, stream>>>(y2_t, dc2w, dc2b, out);    // 688128 threads
}

// Round 4
// 593.197 us; speedup vs baseline: 1.1850x; 1.1850x over previous
//
#include <hip/hip_runtime.h>
#include <stdint.h>

// ---------------------------------------------------------------------------
// decoder_80487687127254 : B=4096 T=7 H=512 L=256 D=1024
// ---------------------------------------------------------------------------

typedef __attribute__((ext_vector_type(4))) float f32x4;
typedef __attribute__((ext_vector_type(8))) short bf16x8;
typedef __attribute__((ext_vector_type(4))) unsigned short us4;

__device__ __forceinline__ unsigned short f2b(float f) {
  union { float f; unsigned u; } x; x.f = f;
  unsigned r = x.u + 0x7FFFu + ((x.u >> 16) & 1u);   // RNE
  return (unsigned short)(r >> 16);
}
__device__ __forceinline__ float b2f(unsigned short s) {
  union { unsigned u; float f; } x; x.u = ((unsigned)s) << 16; return x.f;
}
__device__ __forceinline__ float sigmoidf(float x) {
  return 1.f / (1.f + __expf(-x));
}
__device__ __forceinline__ float fast_tanh(float x) {
  x = fminf(15.f, fmaxf(-15.f, x));
  float e = __expf(2.f * x);
  return (e - 1.f) / (e + 1.f);
}

// async global->LDS, 16B per lane; LDS dest must be wave-uniform (HW adds lane*16)
__device__ __forceinline__ void gl_lds16(const void* g, void* l) {
  auto gp = reinterpret_cast<const __attribute__((address_space(1))) unsigned int*>(
      reinterpret_cast<uintptr_t>(g));
  auto lp = reinterpret_cast<__attribute__((address_space(3))) unsigned int*>(
      reinterpret_cast<uintptr_t>(l));
  __builtin_amdgcn_global_load_lds(gp, lp, 16, 0, 0);
}

// ===========================================================================
// 256x256 8-wave GEMM core (BK=64, dbuf LDS, counted vmcnt, XOR-swizzled LDS)
// LDS tile layout: row-major [256][64] bf16 with involution
//   lds_elem(row, ko) = row*64 + (ko ^ ((row&7)<<3))
// global_load_lds writes linearly -> source column granule pre-swizzled:
//   thread tid (of 512), round r: row = r*64 + (tid>>3),
//   fetches global granule (tid&7)^((tid>>3)&7) of that row.
// 4 rounds per 256x64 tile = 4 gl_lds/thread; A+B = 8/thread per K-tile.
// ===========================================================================
__device__ __forceinline__ void stage256x64_swz(const unsigned short* src, int ld,
                                                unsigned short* lds, int tid) {
  const int wv = tid >> 6;
  const int g = (tid & 7) ^ ((tid >> 3) & 7);
  const int rowin = tid >> 3;
#pragma unroll
  for (int r = 0; r < 4; ++r) {
    int row = r * 64 + rowin;
    gl_lds16(src + (size_t)row * ld + g * 8, lds + r * 4096 + wv * 512);
  }
}

__device__ __forceinline__ bf16x8 lds_frag(const unsigned short* base, int row, int ko) {
  return *(const bf16x8*)(base + row * 64 + (ko ^ ((row & 7) << 3)));
}

// one K-tile of compute: wave (wm in 0..1, wn in 0..3) owns 128x64 of C.
__device__ __forceinline__ void ktile_256(const unsigned short* As, const unsigned short* Bs,
                                          int wm, int wn, int lane, f32x4 acc[8][4]) {
  const int lr = lane & 15, lq = (lane >> 4) * 8;
  bf16x8 b[4][2];
#pragma unroll
  for (int ni = 0; ni < 4; ++ni) {
    int brow = wn * 64 + ni * 16 + lr;
    b[ni][0] = lds_frag(Bs, brow, lq);
    b[ni][1] = lds_frag(Bs, brow, 32 + lq);
  }
#pragma unroll
  for (int mi = 0; mi < 8; ++mi) {
    int arow = wm * 128 + mi * 16 + lr;
    bf16x8 a0 = lds_frag(As, arow, lq);
    bf16x8 a1 = lds_frag(As, arow, 32 + lq);
#pragma unroll
    for (int ni = 0; ni < 4; ++ni) {
      acc[mi][ni] = __builtin_amdgcn_mfma_f32_16x16x32_bf16(a0, b[ni][0], acc[mi][ni], 0, 0, 0);
      acc[mi][ni] = __builtin_amdgcn_mfma_f32_16x16x32_bf16(a1, b[ni][1], acc[mi][ni], 0, 0, 0);
    }
  }
}

#define KLOOP_GATE(kt, NT)                                         \
  if ((kt) + 1 < (NT)) asm volatile("s_waitcnt vmcnt(8)" ::: "memory"); \
  else                 asm volatile("s_waitcnt vmcnt(0)" ::: "memory"); \
  __builtin_amdgcn_s_barrier();                                    \
  __builtin_amdgcn_sched_barrier(0);

#define KLOOP_FREE()                                               \
  __builtin_amdgcn_sched_barrier(0);                               \
  __builtin_amdgcn_s_barrier();

// ---------------------------------------------------------------------------
// 128x128 core (kept for gemm_rep: small grid needs more blocks)
// ---------------------------------------------------------------------------
__device__ __forceinline__ void stage128x64(const unsigned short* src, int ld,
                                            unsigned short* lds, int wv, int lane) {
#pragma unroll
  for (int r = 0; r < 4; ++r) {
    int row = r * 32 + wv * 8 + (lane >> 3);
    gl_lds16(src + (size_t)row * ld + (lane & 7) * 8, lds + (r * 32 + wv * 8) * 64);
  }
}
__device__ __forceinline__ void mfma_tile(const unsigned short* As, const unsigned short* Bs,
                                          int wm, int wn, int lane, f32x4 acc[4][4]) {
#pragma unroll
  for (int kk = 0; kk < 2; ++kk) {
    int ko = kk * 32 + (lane >> 4) * 8;
    bf16x8 a[4], b[4];
#pragma unroll
    for (int i = 0; i < 4; ++i)
      a[i] = *(const bf16x8*)(As + (size_t)(wm * 64 + i * 16 + (lane & 15)) * 64 + ko);
#pragma unroll
    for (int i = 0; i < 4; ++i)
      b[i] = *(const bf16x8*)(Bs + (size_t)(wn * 64 + i * 16 + (lane & 15)) * 64 + ko);
#pragma unroll
    for (int mi = 0; mi < 4; ++mi)
#pragma unroll
      for (int ni = 0; ni < 4; ++ni)
        acc[mi][ni] = __builtin_amdgcn_mfma_f32_16x16x32_bf16(a[mi], b[ni], acc[mi][ni], 0, 0, 0);
  }
}

// ---------------------------------------------------------------------------
// pack: bf16 conversions + transposes + LSTM weight gate-interleave
// ---------------------------------------------------------------------------
__global__ __launch_bounds__(256) void pack_kernel(
    const float* __restrict__ noise, const float* __restrict__ erep_w,
    const float* __restrict__ emb_w,
    const float* __restrict__ wih_f, const float* __restrict__ whh_f,
    const float* __restrict__ bih_f, const float* __restrict__ bhh_f,
    const float* __restrict__ wih_b, const float* __restrict__ whh_b,
    const float* __restrict__ bih_b, const float* __restrict__ bhh_b,
    unsigned short* __restrict__ noiseb, unsigned short* __restrict__ erepT,
    unsigned short* __restrict__ embT, unsigned short* __restrict__ lstmW,
    float* __restrict__ lstmB) {
  const int N0 = 4096 * 256;
  const int N1 = 1792 * 256;
  const int N2 = 1024 * 1024;
  const int N3 = 2 * 2048 * 768;
  const int N4 = 2 * 2048;
  const int total = N0 + N1 + N2 + N3 + N4;
  for (int i = blockIdx.x * 256 + threadIdx.x; i < total; i += gridDim.x * 256) {
    int x = i;
    if (x < N0) { noiseb[x] = f2b(noise[x]); continue; }
    x -= N0;
    if (x < N1) { int n = x >> 8, k = x & 255; erepT[x] = f2b(erep_w[k * 1792 + n]); continue; }
    x -= N1;
    if (x < N2) {
      int n = x >> 10, k = x & 1023;
      int o = (n & 63) * 16 + (n >> 6);
      embT[x] = f2b(emb_w[k * 1024 + o]);
      continue;
    }
    x -= N2;
    if (x < N3) {
      int dir = x / (2048 * 768);
      int r = x - dir * (2048 * 768);
      int npk = r / 768, k = r - (r / 768) * 768;
      int blk = npk >> 6, g = (npk >> 4) & 3, u = npk & 15;
      int o = g * 512 + blk * 16 + u;
      const float* wih = dir ? wih_b : wih_f;
      const float* whh = dir ? whh_b : whh_f;
      float v = (k < 256) ? wih[k * 2048 + o] : whh[(k - 256) * 2048 + o];
      lstmW[x] = f2b(v);
      continue;
    }
    x -= N3;
    {
      int dir = x >> 11, npk = x & 2047;
      int blk = npk >> 6, g = (npk >> 4) & 3, u = npk & 15;
      int o = g * 512 + blk * 16 + u;
      lstmB[x] = dir ? (bih_b[o] + bhh_b[o]) : (bih_f[o] + bhh_f[o]);
    }
  }
}

// ---------------------------------------------------------------------------
// rep = softsign(noise @ erep_w + b)  (128x128 core, M=4096 K=256 N=1792)
// ---------------------------------------------------------------------------
__global__ __launch_bounds__(256) void gemm_rep_kernel(
    const unsigned short* __restrict__ A, const unsigned short* __restrict__ Bt,
    const float* __restrict__ bias, unsigned short* __restrict__ rep_t) {
  __shared__ unsigned short As[128 * 64];
  __shared__ unsigned short Bs[128 * 64];
  const int lane = threadIdx.x & 63, wv = threadIdx.x >> 6;
  const int wm = wv >> 1, wn = wv & 1;
  const int m0 = blockIdx.y * 128, n0 = blockIdx.x * 128;
  f32x4 acc[4][4];
#pragma unroll
  for (int i = 0; i < 4; ++i)
#pragma unroll
    for (int j = 0; j < 4; ++j) acc[i][j] = (f32x4){0.f, 0.f, 0.f, 0.f};
  for (int k0 = 0; k0 < 256; k0 += 64) {
    stage128x64(A + (size_t)m0 * 256 + k0, 256, As, wv, lane);
    stage128x64(Bt + (size_t)n0 * 256 + k0, 256, Bs, wv, lane);
    __syncthreads();
    mfma_tile(As, Bs, wm, wn, lane, acc);
    __syncthreads();
  }
#pragma unroll
  for (int ni = 0; ni < 4; ++ni) {
    int n = n0 + wn * 64 + ni * 16 + (lane & 15);
    float bv = bias[n];
    int t = n >> 8, l = n & 255;
#pragma unroll
    for (int mi = 0; mi < 4; ++mi)
#pragma unroll
      for (int r = 0; r < 4; ++r) {
        int m = m0 + wm * 64 + mi * 16 + (lane >> 4) * 4 + r;
        float v = acc[mi][ni][r] + bv;
        v = v / (1.f + fabsf(v));
        rep_t[((size_t)t * 4096 + m) * 256 + l] = f2b(v);
      }
  }
}

// ---------------------------------------------------------------------------
// LSTM step, 256x256 core. Grid: 256 blocks (8 N-tiles x 16 M-tiles x 2 dirs),
// XCD-swizzled. gates = [x_t|h] @ Wp + bias, fused cell epilogue.
// ---------------------------------------------------------------------------
__global__ __launch_bounds__(512, 2) void lstm_step256_kernel(
    const unsigned short* __restrict__ rep_t, const unsigned short* __restrict__ Wp,
    const float* __restrict__ biasP, unsigned short* __restrict__ hbuf,
    float* __restrict__ cbuf, unsigned short* __restrict__ lstm1, int step) {
  __shared__ unsigned short AsB[2][256 * 64];
  __shared__ unsigned short BsB[2][256 * 64];
  const int tid = threadIdx.x, lane = tid & 63, wv = tid >> 6;
  const int wm = wv >> 2, wn = wv & 3;
  // XCD-aware bijective swizzle of 256 blocks
  const int swz = (blockIdx.x & 7) * 32 + (blockIdx.x >> 3);
  const int dir = swz >> 7;
  const int by = (swz & 127) >> 3, bx = swz & 7;
  const int m0 = by * 256, n0 = bx * 256;
  const int t_proc = dir ? (6 - step) : step;
  const unsigned short* W = Wp + (size_t)dir * 2048 * 768;
  const unsigned short* hin = hbuf + ((size_t)(step & 1) * 2 + dir) * (4096 * 512);
  unsigned short* hout = hbuf + ((size_t)((step + 1) & 1) * 2 + dir) * (4096 * 512);
  float* cp = cbuf + (size_t)dir * (4096 * 512);
  const unsigned short* xsrc = rep_t + (size_t)t_proc * 4096 * 256;

  f32x4 acc[8][4];
#pragma unroll
  for (int i = 0; i < 8; ++i)
#pragma unroll
    for (int j = 0; j < 4; ++j) acc[i][j] = (f32x4){0.f, 0.f, 0.f, 0.f};

  // K = 768: kt 0..3 from xsrc (ld 256), kt 4..11 from hin (ld 512)
#define LSTM_STAGE_A(kt, buf)                                                     \
  if ((kt) < 4) stage256x64_swz(xsrc + (size_t)m0 * 256 + (kt) * 64, 256, AsB[buf], tid); \
  else          stage256x64_swz(hin + (size_t)m0 * 512 + ((kt) - 4) * 64, 512, AsB[buf], tid);

  LSTM_STAGE_A(0, 0)
  stage256x64_swz(W + (size_t)n0 * 768 + 0, 768, BsB[0], tid);
  LSTM_STAGE_A(1, 1)
  stage256x64_swz(W + (size_t)n0 * 768 + 64, 768, BsB[1], tid);

  for (int kt = 0; kt < 12; ++kt) {
    const int cur = kt & 1;
    KLOOP_GATE(kt, 12)
    ktile_256(AsB[cur], BsB[cur], wm, wn, lane, acc);
    KLOOP_FREE()
    if (kt + 2 < 12) {
      LSTM_STAGE_A(kt + 2, cur)
      stage256x64_swz(W + (size_t)n0 * 768 + (kt + 2) * 64, 768, BsB[cur], tid);
    }
  }
#undef LSTM_STAGE_A

  const int u = lane & 15;
  const int blk = (n0 + wn * 64) >> 6;
  const int j = blk * 16 + u;
  const float bz0 = biasP[dir * 2048 + blk * 64 + 0 * 16 + u];
  const float bz1 = biasP[dir * 2048 + blk * 64 + 1 * 16 + u];
  const float bz2 = biasP[dir * 2048 + blk * 64 + 2 * 16 + u];
  const float bz3 = biasP[dir * 2048 + blk * 64 + 3 * 16 + u];
#pragma unroll
  for (int mi = 0; mi < 8; ++mi)
#pragma unroll
    for (int r = 0; r < 4; ++r) {
      int row = m0 + wm * 128 + mi * 16 + (lane >> 4) * 4 + r;
      float gi = acc[mi][0][r] + bz0;
      float gf = acc[mi][1][r] + bz1;
      float gg = acc[mi][2][r] + bz2;
      float go = acc[mi][3][r] + bz3;
      size_t ci = (size_t)row * 512 + j;
      float c = sigmoidf(gf) * cp[ci] + sigmoidf(gi) * fast_tanh(gg);
      cp[ci] = c;
      float h = sigmoidf(go) * fast_tanh(c);
      unsigned short hb = f2b(h);
      hout[ci] = hb;
      lstm1[((size_t)row * 7 + t_proc) * 1024 + dir * 512 + j] = hb;
    }
}

// ---------------------------------------------------------------------------
// attention part 1: Gram + recursion -> C (7x14 per row)
// ---------------------------------------------------------------------------
__global__ __launch_bounds__(256) void att_gram_kernel(
    const float* __restrict__ enc, const unsigned short* __restrict__ lstm1,
    float* __restrict__ c_ws) {
  __shared__ float part[4][98];
  __shared__ float sG[98];
  __shared__ float sC[7][14];
  __shared__ float sA[16];
  const int tid = threadIdx.x, lane = tid & 63, wv = tid >> 6;
  const int b = blockIdx.x;
  const float* Eb = enc + (size_t)b * 7168;
  const unsigned short* Qb = lstm1 + (size_t)b * 7168;
  const int d0 = wv * 256 + lane * 4;

  for (int x = lane; x < 98; x += 64) part[wv][x] = 0.f;
  if (tid < 98) ((float*)sC)[tid] = 0.f;

  float q[7][4];
#pragma unroll
  for (int i = 0; i < 7; ++i) {
    us4 qv = *(const us4*)(Qb + i * 1024 + d0);
#pragma unroll
    for (int e = 0; e < 4; ++e) q[i][e] = b2f(qv[e]);
  }
#pragma unroll
  for (int t = 0; t < 7; ++t) {
    f32x4 k = *(const f32x4*)(Eb + t * 1024 + d0);
#pragma unroll
    for (int i = 0; i < 7; ++i) {
      float p = q[i][0] * k[0] + q[i][1] * k[1] + q[i][2] * k[2] + q[i][3] * k[3];
#pragma unroll
      for (int off = 32; off >= 1; off >>= 1) p += __shfl_xor(p, off);
      if (lane == 0) part[wv][i * 14 + t] = p;
    }
  }
#pragma unroll
  for (int m = 0; m < 6; ++m) {
#pragma unroll
    for (int i = m + 1; i < 7; ++i) {
      float p = q[i][0] * q[m][0] + q[i][1] * q[m][1] + q[i][2] * q[m][2] + q[i][3] * q[m][3];
#pragma unroll
      for (int off = 32; off >= 1; off >>= 1) p += __shfl_xor(p, off);
      if (lane == 0) part[wv][i * 14 + 7 + m] = p;
    }
  }
  __syncthreads();
  if (tid < 98) sG[tid] = part[0][tid] + part[1][tid] + part[2][tid] + part[3][tid];
  __syncthreads();
  if (wv == 0) {
    for (int i = 0; i < 7; ++i) {
      const int nt = 7 + i;
      float s = -1e30f;
      if (lane < 7) {
        s = sG[i * 14 + lane];
      } else if (lane < nt) {
        int jj = lane - 7;
        float a2 = 0.f;
#pragma unroll
        for (int v = 0; v < 14; ++v) a2 += sC[jj][v] * sG[i * 14 + v];
        s = a2;
      }
      float mx = s;
#pragma unroll
      for (int off = 8; off >= 1; off >>= 1) mx = fmaxf(mx, __shfl_xor(mx, off, 16));
      float e = (lane < nt) ? __expf(s - mx) : 0.f;
      float sum = e;
#pragma unroll
      for (int off = 8; off >= 1; off >>= 1) sum += __shfl_xor(sum, off, 16);
      float a = e / sum;
      if (lane < 16) sA[lane] = a;
      if (lane < 14) {
        float c = (lane < 7) ? sA[lane] : 0.f;
        for (int jj = 0; jj < i; ++jj) c += sA[7 + jj] * sC[jj][lane];
        if (lane == 7 + i) c += 1.f;
        sC[i][lane] = c;
      }
    }
    for (int x = lane; x < 98; x += 64) c_ws[(size_t)b * 98 + x] = ((float*)sC)[x];
  }
}

// ---------------------------------------------------------------------------
// attention part 2: att = C @ [E;Q], streaming
// ---------------------------------------------------------------------------
__global__ __launch_bounds__(256) void att_out_kernel(
    const float* __restrict__ enc, const unsigned short* __restrict__ lstm1,
    const float* __restrict__ c_ws, unsigned short* __restrict__ att) {
  __shared__ float sC[98];
  const int tid = threadIdx.x, lane = tid & 63, wv = tid >> 6;
  const int b = blockIdx.x;
  if (tid < 98) sC[tid] = c_ws[(size_t)b * 98 + tid];
  const float* Eb = enc + (size_t)b * 7168;
  const unsigned short* Qb = lstm1 + (size_t)b * 7168;
  unsigned short* Ab = att + (size_t)b * 7168;
  const int d0 = wv * 256 + lane * 4;
  __syncthreads();
  float acc[7][4];
#pragma unroll
  for (int i = 0; i < 7; ++i)
#pragma unroll
    for (int e = 0; e < 4; ++e) acc[i][e] = 0.f;
#pragma unroll
  for (int v = 0; v < 7; ++v) {
    f32x4 k = *(const f32x4*)(Eb + v * 1024 + d0);
#pragma unroll
    for (int i = 0; i < 7; ++i) {
      float c = sC[i * 14 + v];
#pragma unroll
      for (int e = 0; e < 4; ++e) acc[i][e] += c * k[e];
    }
  }
#pragma unroll
  for (int m = 0; m < 7; ++m) {
    us4 qv = *(const us4*)(Qb + m * 1024 + d0);
    float k[4];
#pragma unroll
    for (int e = 0; e < 4; ++e) k[e] = b2f(qv[e]);
#pragma unroll
    for (int i = m; i < 7; ++i) {
      float c = sC[i * 14 + 7 + m];
#pragma unroll
      for (int e = 0; e < 4; ++e) acc[i][e] += c * k[e];
    }
  }
#pragma unroll
  for (int i = 0; i < 7; ++i) {
    us4 r;
#pragma unroll
    for (int e = 0; e < 4; ++e) r[e] = f2b(acc[i][e]);
    *(us4*)(Ab + i * 1024 + d0) = r;
  }
}

// ---------------------------------------------------------------------------
// up_t = softsign(att @ emb_w + emb_b), 256x256 core. M=28672 K=1024 N=1024.
// Grid 448 blocks (4 N-tiles x 112 M-tiles), XCD-swizzled.
// ---------------------------------------------------------------------------
__global__ __launch_bounds__(512, 2) void gemm_emb256_kernel(
    const unsigned short* __restrict__ A, const unsigned short* __restrict__ Bt,
    const float* __restrict__ bias, unsigned short* __restrict__ up_t) {
  __shared__ unsigned short AsB[2][256 * 64];
  __shared__ unsigned short BsB[2][256 * 64];
  const int tid = threadIdx.x, lane = tid & 63, wv = tid >> 6;
  const int wm = wv >> 2, wn = wv & 3;
  const int swz = (blockIdx.x & 7) * 56 + (blockIdx.x >> 3);
  const int by = swz >> 2, bx = swz & 3;
  const int m0 = by * 256, n0 = bx * 256;

  f32x4 acc[8][4];
#pragma unroll
  for (int i = 0; i < 8; ++i)
#pragma unroll
    for (int j = 0; j < 4; ++j) acc[i][j] = (f32x4){0.f, 0.f, 0.f, 0.f};

  stage256x64_swz(A + (size_t)m0 * 1024 + 0, 1024, AsB[0], tid);
  stage256x64_swz(Bt + (size_t)n0 * 1024 + 0, 1024, BsB[0], tid);
  stage256x64_swz(A + (size_t)m0 * 1024 + 64, 1024, AsB[1], tid);
  stage256x64_swz(Bt + (size_t)n0 * 1024 + 64, 1024, BsB[1], tid);

  for (int kt = 0; kt < 16; ++kt) {
    const int cur = kt & 1;
    KLOOP_GATE(kt, 16)
    ktile_256(AsB[cur], BsB[cur], wm, wn, lane, acc);
    KLOOP_FREE()
    if (kt + 2 < 16) {
      stage256x64_swz(A + (size_t)m0 * 1024 + (kt + 2) * 64, 1024, AsB[cur], tid);
      stage256x64_swz(Bt + (size_t)n0 * 1024 + (kt + 2) * 64, 1024, BsB[cur], tid);
    }
  }

#pragma unroll
  for (int ni = 0; ni < 4; ++ni) {
    int np = n0 + wn * 64 + ni * 16 + (lane & 15);
    int o = (np & 63) * 16 + (np >> 6);
    float bv = bias[o];
#pragma unroll
    for (int mi = 0; mi < 8; ++mi)
#pragma unroll
      for (int r = 0; r < 4; ++r) {
        int m = m0 + wm * 128 + mi * 16 + (lane >> 4) * 4 + r;
        float v = acc[mi][ni][r] + bv;
        v = v / (1.f + fabsf(v));
        up_t[(size_t)m * 1024 + np] = f2b(v);
      }
  }
}

// ---------------------------------------------------------------------------
// dc3: y1[img,ow,oc] via MFMA, weights in VGPRs
// ---------------------------------------------------------------------------
__global__ __launch_bounds__(256) void dc3_kernel(const unsigned short* __restrict__ up_t,
                                                  const float* __restrict__ w3,
                                                  const float* __restrict__ b3,
                                                  unsigned short* __restrict__ y1_t) {
  const int lane = threadIdx.x & 63, wv = threadIdx.x >> 6;
  const int kq = (lane >> 4) * 8;
  const int oc = lane & 15;
  bf16x8 bf[2][6];
#pragma unroll
  for (int nt = 0; nt < 2; ++nt)
#pragma unroll
    for (int kk = 0; kk < 6; ++kk) {
      bf16x8 v;
#pragma unroll
      for (int t = 0; t < 8; ++t) {
        int k = kk * 32 + kq + t;
        int jj = k >> 6, ic = k & 63;
        v[t] = (short)f2b(w3[((size_t)ic * 32 + nt * 16 + oc) * 3 + jj]);
      }
      bf[nt][kk] = v;
    }
  const float bia0 = b3[oc], bia1 = b3[16 + oc];
  const int base_chunk = blockIdx.x * 32 + wv * 8;
  for (int cc = 0; cc < 8; ++cc) {
    const int chunk = base_chunk + cc;
    int m = chunk * 16 + (lane & 15);
    int img = m / 18, ow = m - img * 18;
    const unsigned short* arow = up_t + (size_t)img * 1024;
    f32x4 acc0 = {0.f, 0.f, 0.f, 0.f}, acc1 = {0.f, 0.f, 0.f, 0.f};
#pragma unroll
    for (int kk = 0; kk < 6; ++kk) {
      int jj = kk >> 1;
      int ic0 = (kk & 1) * 32 + kq;
      int iw = ow - jj;
      bf16x8 a = {0, 0, 0, 0, 0, 0, 0, 0};
      if ((unsigned)iw < 16u) a = *(const bf16x8*)(arow + iw * 64 + ic0);
      acc0 = __builtin_amdgcn_mfma_f32_16x16x32_bf16(a, bf[0][kk], acc0, 0, 0, 0);
      acc1 = __builtin_amdgcn_mfma_f32_16x16x32_bf16(a, bf[1][kk], acc1, 0, 0, 0);
    }
#pragma unroll
    for (int r = 0; r < 4; ++r) {
      int mm = chunk * 16 + (lane >> 4) * 4 + r;
      float v0 = acc0[r] + bia0; v0 = v0 > 0.f ? v0 : 0.01f * v0;
      float v1 = acc1[r] + bia1; v1 = v1 > 0.f ? v1 : 0.01f * v1;
      y1_t[(size_t)mm * 32 + oc] = f2b(v0);
      y1_t[(size_t)mm * 32 + 16 + oc] = f2b(v1);
    }
  }
}

// ---------------------------------------------------------------------------
// dc1
// ---------------------------------------------------------------------------
__global__ __launch_bounds__(256) void dc1_kernel(const unsigned short* __restrict__ y1_t,
                                                  const float* __restrict__ w1,
                                                  const float* __restrict__ b1,
                                                  unsigned short* __restrict__ y2_t) {
  const int lane = threadIdx.x & 63, wv = threadIdx.x >> 6;
  const int kq = (lane >> 4) * 8;
  const int oc = lane & 15;
  bf16x8 bf[5];
#pragma unroll
  for (int kk = 0; kk < 5; ++kk) {
    bf16x8 v;
#pragma unroll
    for (int t = 0; t < 8; ++t) {
      int ic = kq + t;
      v[t] = (short)f2b(w1[((size_t)ic * 16 + oc) * 5 + kk]);
    }
    bf[kk] = v;
  }
  const float bia = b1[oc];
  const int base_chunk = blockIdx.x * 32 + wv * 8;
  for (int cc = 0; cc < 8; ++cc) {
    const int chunk = base_chunk + cc;
    int m = chunk * 16 + (lane & 15);
    int img = m / 22, ow = m - img * 22;
    const unsigned short* abase = y1_t + (size_t)img * 18 * 32;
    f32x4 acc = {0.f, 0.f, 0.f, 0.f};
#pragma unroll
    for (int kk = 0; kk < 5; ++kk) {
      int iw = ow - kk;
      bf16x8 a = {0, 0, 0, 0, 0, 0, 0, 0};
      if ((unsigned)iw < 18u) a = *(const bf16x8*)(abase + iw * 32 + kq);
      acc = __builtin_amdgcn_mfma_f32_16x16x32_bf16(a, bf[kk], acc, 0, 0, 0);
    }
#pragma unroll
    for (int r = 0; r < 4; ++r) {
      int mm = chunk * 16 + (lane >> 4) * 4 + r;
      float v = acc[r] + bia;
      v = v > 0.f ? v : 0.01f * v;
      y2_t[(size_t)mm * 16 + oc] = f2b(v);
    }
  }
}

// ---------------------------------------------------------------------------
// dc2 + softmax over oh
// ---------------------------------------------------------------------------
__global__ __launch_bounds__(256) void dc2_kernel(const unsigned short* __restrict__ y2_t,
                                                  const float* __restrict__ w2,
                                                  const float* __restrict__ b2,
                                                  float* __restrict__ out) {
  int idx = blockIdx.x * 256 + threadIdx.x;
  int img = idx / 24, ow = idx - img * 24;
  float lg0 = b2[0], lg1 = b2[0], lg2 = b2[0];
#pragma unroll
  for (int jj = 0; jj < 3; ++jj) {
    int iw = ow - jj;
    if ((unsigned)iw >= 22u) continue;
    const unsigned short* row = y2_t + ((size_t)img * 22 + iw) * 16;
    bf16x8 v0 = *(const bf16x8*)(row);
    bf16x8 v1 = *(const bf16x8*)(row + 8);
    float x[16];
#pragma unroll
    for (int ic = 0; ic < 8; ++ic) {
      x[ic] = b2f((unsigned short)v0[ic]);
      x[8 + ic] = b2f((unsigned short)v1[ic]);
    }
#pragma unroll
    for (int ic = 0; ic < 16; ++ic) {
      lg0 += x[ic] * w2[ic * 9 + 0 * 3 + jj];
      lg1 += x[ic] * w2[ic * 9 + 1 * 3 + jj];
      lg2 += x[ic] * w2[ic * 9 + 2 * 3 + jj];
    }
  }
  lg0 = lg0 > 0.f ? lg0 : 0.01f * lg0;
  lg1 = lg1 > 0.f ? lg1 : 0.01f * lg1;
  lg2 = lg2 > 0.f ? lg2 : 0.01f * lg2;
  float mx = fmaxf(lg0, fmaxf(lg1, lg2));
  float e0 = __expf(lg0 - mx), e1 = __expf(lg1 - mx), e2 = __expf(lg2 - mx);
  float inv = 1.f / (e0 + e1 + e2);
  size_t ob = (size_t)img * 72 + ow;
  out[ob] = e0 * inv;
  out[ob + 24] = e1 * inv;
  out[ob + 48] = e2 * inv;
}

// ---------------------------------------------------------------------------
extern "C" void kernel_launch(void* const* d_in, const int* in_sizes, int n_in,
                              void* d_out, int out_size, void* d_ws, size_t ws_size,
                              hipStream_t stream) {
  (void)in_sizes; (void)n_in; (void)out_size; (void)ws_size;
  const float* enc    = (const float*)d_in[0];
  const float* noise  = (const float*)d_in[1];
  const float* erep_w = (const float*)d_in[2];
  const float* erep_b = (const float*)d_in[3];
  const float* wih_f  = (const float*)d_in[4];
  const float* whh_f  = (const float*)d_in[5];
  const float* bih_f  = (const float*)d_in[6];
  const float* bhh_f  = (const float*)d_in[7];
  const float* wih_b  = (const float*)d_in[8];
  const float* whh_b  = (const float*)d_in[9];
  const float* bih_b  = (const float*)d_in[10];
  const float* bhh_b  = (const float*)d_in[11];
  const float* emb_w  = (const float*)d_in[12];
  const float* emb_b  = (const float*)d_in[13];
  const float* dc3w   = (const float*)d_in[14];
  const float* dc3b   = (const float*)d_in[15];
  const float* dc1w   = (const float*)d_in[16];
  const float* dc1b   = (const float*)d_in[17];
  const float* dc2w   = (const float*)d_in[18];
  const float* dc2b   = (const float*)d_in[19];
  float* out = (float*)d_out;

  char* p = (char*)d_ws;
  auto carve = [&p](size_t bytes) {
    char* r = p;
    p += (bytes + 255) & ~(size_t)255;
    return r;
  };
  unsigned short* rep_t  = (unsigned short*)carve(7ull * 4096 * 256 * 2);
  unsigned short* lstmW  = (unsigned short*)carve(2ull * 2048 * 768 * 2);
  float*          lstmB  = (float*)carve(2ull * 2048 * 4);
  unsigned short* noiseb = (unsigned short*)carve(4096ull * 256 * 2);
  unsigned short* erepT  = (unsigned short*)carve(1792ull * 256 * 2);
  unsigned short* embT   = (unsigned short*)carve(1024ull * 1024 * 2);
  unsigned short* hbuf   = (unsigned short*)carve(4ull * 4096 * 512 * 2);   // [pp][dir]
  float*          cbuf   = (float*)carve(2ull * 4096 * 512 * 4);            // [dir]
  unsigned short* lstm1  = (unsigned short*)carve(4096ull * 7 * 1024 * 2);
  float*          c_ws   = (float*)carve(4096ull * 98 * 4);
  unsigned short* att    = (unsigned short*)carve(28672ull * 1024 * 2);
  unsigned short* up_t   = (unsigned short*)carve(28672ull * 1024 * 2);
  unsigned short* y1_t   = (unsigned short*)carve(28672ull * 18 * 32 * 2);
  unsigned short* y2_t   = (unsigned short*)carve(28672ull * 22 * 16 * 2);

  hipMemsetAsync(hbuf, 0, 2ull * 4096 * 512 * 2, stream);
  hipMemsetAsync(cbuf, 0, 2ull * 4096 * 512 * 4, stream);

  pack_kernel<<<2048, 256, 0, stream>>>(noise, erep_w, emb_w, wih_f, whh_f, bih_f, bhh_f,
                                        wih_b, whh_b, bih_b, bhh_b,
                                        noiseb, erepT, embT, lstmW, lstmB);
  gemm_rep_kernel<<<dim3(14, 32), 256, 0, stream>>>(noiseb, erepT, erep_b, rep_t);
  for (int s = 0; s < 7; ++s)
    lstm_step256_kernel<<<256, 512, 0, stream>>>(rep_t, lstmW, lstmB, hbuf, cbuf, lstm1, s);
  att_gram_kernel<<<4096, 256, 0, stream>>>(enc, lstm1, c_ws);
  att_out_kernel<<<4096, 256, 0, stream>>>(enc, lstm1, c_ws, att);
  gemm_emb256_kernel<<<448, 512, 0, stream>>>(att, embT, emb_b, up_t);
  dc3_kernel<<<1008, 256, 0, stream>>>(up_t, dc3w, dc3b, y1_t);
  dc1_kernel<<<1232, 256, 0, stream>>>(y1_t, dc1w, dc1b, y2_t);
  dc2_kernel<<<2688, 256, 0, stream>>>(y2_t, dc2w, dc2b, out);
}

// Round 5
// 533.032 us; speedup vs baseline: 1.3187x; 1.1129x over previous
//
#include <hip/hip_runtime.h>
#include <stdint.h>

// ---------------------------------------------------------------------------
// decoder_80487687127254 : B=4096 T=7 H=512 L=256 D=1024
// ---------------------------------------------------------------------------

typedef __attribute__((ext_vector_type(4))) float f32x4;
typedef __attribute__((ext_vector_type(8))) short bf16x8;
typedef __attribute__((ext_vector_type(4))) unsigned short us4;

__device__ __forceinline__ unsigned short f2b(float f) {
  union { float f; unsigned u; } x; x.f = f;
  unsigned r = x.u + 0x7FFFu + ((x.u >> 16) & 1u);   // RNE
  return (unsigned short)(r >> 16);
}
__device__ __forceinline__ float b2f(unsigned short s) {
  union { unsigned u; float f; } x; x.u = ((unsigned)s) << 16; return x.f;
}
__device__ __forceinline__ float sigmoidf(float x) {
  return 1.f / (1.f + __expf(-x));
}
__device__ __forceinline__ float fast_tanh(float x) {
  x = fminf(15.f, fmaxf(-15.f, x));
  float e = __expf(2.f * x);
  return (e - 1.f) / (e + 1.f);
}

// async global->LDS, 16B per lane; LDS dest must be wave-uniform (HW adds lane*16)
__device__ __forceinline__ void gl_lds16(const void* g, void* l) {
  auto gp = reinterpret_cast<const __attribute__((address_space(1))) unsigned int*>(
      reinterpret_cast<uintptr_t>(g));
  auto lp = reinterpret_cast<__attribute__((address_space(3))) unsigned int*>(
      reinterpret_cast<uintptr_t>(l));
  __builtin_amdgcn_global_load_lds(gp, lp, 16, 0, 0);
}

// ===========================================================================
// 256x256 8-wave GEMM core (BK=64, dbuf LDS, counted vmcnt, XOR-swizzled LDS)
// ===========================================================================
__device__ __forceinline__ void stage256x64_swz(const unsigned short* src, int ld,
                                                unsigned short* lds, int tid) {
  const int wv = tid >> 6;
  const int g = (tid & 7) ^ ((tid >> 3) & 7);
  const int rowin = tid >> 3;
#pragma unroll
  for (int r = 0; r < 4; ++r) {
    int row = r * 64 + rowin;
    gl_lds16(src + (size_t)row * ld + g * 8, lds + r * 4096 + wv * 512);
  }
}

__device__ __forceinline__ bf16x8 lds_frag(const unsigned short* base, int row, int ko) {
  return *(const bf16x8*)(base + row * 64 + (ko ^ ((row & 7) << 3)));
}

__device__ __forceinline__ void ktile_256(const unsigned short* As, const unsigned short* Bs,
                                          int wm, int wn, int lane, f32x4 acc[8][4]) {
  const int lr = lane & 15, lq = (lane >> 4) * 8;
  bf16x8 b[4][2];
#pragma unroll
  for (int ni = 0; ni < 4; ++ni) {
    int brow = wn * 64 + ni * 16 + lr;
    b[ni][0] = lds_frag(Bs, brow, lq);
    b[ni][1] = lds_frag(Bs, brow, 32 + lq);
  }
#pragma unroll
  for (int mi = 0; mi < 8; ++mi) {
    int arow = wm * 128 + mi * 16 + lr;
    bf16x8 a0 = lds_frag(As, arow, lq);
    bf16x8 a1 = lds_frag(As, arow, 32 + lq);
#pragma unroll
    for (int ni = 0; ni < 4; ++ni) {
      acc[mi][ni] = __builtin_amdgcn_mfma_f32_16x16x32_bf16(a0, b[ni][0], acc[mi][ni], 0, 0, 0);
      acc[mi][ni] = __builtin_amdgcn_mfma_f32_16x16x32_bf16(a1, b[ni][1], acc[mi][ni], 0, 0, 0);
    }
  }
}

#define KLOOP_GATE(kt, NT)                                         \
  if ((kt) + 1 < (NT)) asm volatile("s_waitcnt vmcnt(8)" ::: "memory"); \
  else                 asm volatile("s_waitcnt vmcnt(0)" ::: "memory"); \
  __builtin_amdgcn_s_barrier();                                    \
  __builtin_amdgcn_sched_barrier(0);

#define KLOOP_FREE()                                               \
  __builtin_amdgcn_sched_barrier(0);                               \
  __builtin_amdgcn_s_barrier();

// ---------------------------------------------------------------------------
// 128x128 core (kept for gemm_rep: small grid needs more blocks)
// ---------------------------------------------------------------------------
__device__ __forceinline__ void stage128x64(const unsigned short* src, int ld,
                                            unsigned short* lds, int wv, int lane) {
#pragma unroll
  for (int r = 0; r < 4; ++r) {
    int row = r * 32 + wv * 8 + (lane >> 3);
    gl_lds16(src + (size_t)row * ld + (lane & 7) * 8, lds + (r * 32 + wv * 8) * 64);
  }
}
__device__ __forceinline__ void mfma_tile(const unsigned short* As, const unsigned short* Bs,
                                          int wm, int wn, int lane, f32x4 acc[4][4]) {
#pragma unroll
  for (int kk = 0; kk < 2; ++kk) {
    int ko = kk * 32 + (lane >> 4) * 8;
    bf16x8 a[4], b[4];
#pragma unroll
    for (int i = 0; i < 4; ++i)
      a[i] = *(const bf16x8*)(As + (size_t)(wm * 64 + i * 16 + (lane & 15)) * 64 + ko);
#pragma unroll
    for (int i = 0; i < 4; ++i)
      b[i] = *(const bf16x8*)(Bs + (size_t)(wn * 64 + i * 16 + (lane & 15)) * 64 + ko);
#pragma unroll
    for (int mi = 0; mi < 4; ++mi)
#pragma unroll
      for (int ni = 0; ni < 4; ++ni)
        acc[mi][ni] = __builtin_amdgcn_mfma_f32_16x16x32_bf16(a[mi], b[ni], acc[mi][ni], 0, 0, 0);
  }
}

// ---------------------------------------------------------------------------
// pack
// ---------------------------------------------------------------------------
__global__ __launch_bounds__(256) void pack_kernel(
    const float* __restrict__ noise, const float* __restrict__ erep_w,
    const float* __restrict__ emb_w,
    const float* __restrict__ wih_f, const float* __restrict__ whh_f,
    const float* __restrict__ bih_f, const float* __restrict__ bhh_f,
    const float* __restrict__ wih_b, const float* __restrict__ whh_b,
    const float* __restrict__ bih_b, const float* __restrict__ bhh_b,
    unsigned short* __restrict__ noiseb, unsigned short* __restrict__ erepT,
    unsigned short* __restrict__ embT, unsigned short* __restrict__ lstmW,
    float* __restrict__ lstmB) {
  const int N0 = 4096 * 256;
  const int N1 = 1792 * 256;
  const int N2 = 1024 * 1024;
  const int N3 = 2 * 2048 * 768;
  const int N4 = 2 * 2048;
  const int total = N0 + N1 + N2 + N3 + N4;
  for (int i = blockIdx.x * 256 + threadIdx.x; i < total; i += gridDim.x * 256) {
    int x = i;
    if (x < N0) { noiseb[x] = f2b(noise[x]); continue; }
    x -= N0;
    if (x < N1) { int n = x >> 8, k = x & 255; erepT[x] = f2b(erep_w[k * 1792 + n]); continue; }
    x -= N1;
    if (x < N2) {
      int n = x >> 10, k = x & 1023;
      int o = (n & 63) * 16 + (n >> 6);
      embT[x] = f2b(emb_w[k * 1024 + o]);
      continue;
    }
    x -= N2;
    if (x < N3) {
      int dir = x / (2048 * 768);
      int r = x - dir * (2048 * 768);
      int npk = r / 768, k = r - (r / 768) * 768;
      int blk = npk >> 6, g = (npk >> 4) & 3, u = npk & 15;
      int o = g * 512 + blk * 16 + u;
      const float* wih = dir ? wih_b : wih_f;
      const float* whh = dir ? whh_b : whh_f;
      float v = (k < 256) ? wih[k * 2048 + o] : whh[(k - 256) * 2048 + o];
      lstmW[x] = f2b(v);
      continue;
    }
    x -= N3;
    {
      int dir = x >> 11, npk = x & 2047;
      int blk = npk >> 6, g = (npk >> 4) & 3, u = npk & 15;
      int o = g * 512 + blk * 16 + u;
      lstmB[x] = dir ? (bih_b[o] + bhh_b[o]) : (bih_f[o] + bhh_f[o]);
    }
  }
}

// ---------------------------------------------------------------------------
// rep = softsign(noise @ erep_w + b)
// ---------------------------------------------------------------------------
__global__ __launch_bounds__(256) void gemm_rep_kernel(
    const unsigned short* __restrict__ A, const unsigned short* __restrict__ Bt,
    const float* __restrict__ bias, unsigned short* __restrict__ rep_t) {
  __shared__ unsigned short As[128 * 64];
  __shared__ unsigned short Bs[128 * 64];
  const int lane = threadIdx.x & 63, wv = threadIdx.x >> 6;
  const int wm = wv >> 1, wn = wv & 1;
  const int m0 = blockIdx.y * 128, n0 = blockIdx.x * 128;
  f32x4 acc[4][4];
#pragma unroll
  for (int i = 0; i < 4; ++i)
#pragma unroll
    for (int j = 0; j < 4; ++j) acc[i][j] = (f32x4){0.f, 0.f, 0.f, 0.f};
  for (int k0 = 0; k0 < 256; k0 += 64) {
    stage128x64(A + (size_t)m0 * 256 + k0, 256, As, wv, lane);
    stage128x64(Bt + (size_t)n0 * 256 + k0, 256, Bs, wv, lane);
    __syncthreads();
    mfma_tile(As, Bs, wm, wn, lane, acc);
    __syncthreads();
  }
#pragma unroll
  for (int ni = 0; ni < 4; ++ni) {
    int n = n0 + wn * 64 + ni * 16 + (lane & 15);
    float bv = bias[n];
    int t = n >> 8, l = n & 255;
#pragma unroll
    for (int mi = 0; mi < 4; ++mi)
#pragma unroll
      for (int r = 0; r < 4; ++r) {
        int m = m0 + wm * 64 + mi * 16 + (lane >> 4) * 4 + r;
        float v = acc[mi][ni][r] + bv;
        v = v / (1.f + fabsf(v));
        rep_t[((size_t)t * 4096 + m) * 256 + l] = f2b(v);
      }
  }
}

// ---------------------------------------------------------------------------
// LSTM step, 256x256 core
// ---------------------------------------------------------------------------
__global__ __launch_bounds__(512, 2) void lstm_step256_kernel(
    const unsigned short* __restrict__ rep_t, const unsigned short* __restrict__ Wp,
    const float* __restrict__ biasP, unsigned short* __restrict__ hbuf,
    float* __restrict__ cbuf, unsigned short* __restrict__ lstm1, int step) {
  __shared__ unsigned short AsB[2][256 * 64];
  __shared__ unsigned short BsB[2][256 * 64];
  const int tid = threadIdx.x, lane = tid & 63, wv = tid >> 6;
  const int wm = wv >> 2, wn = wv & 3;
  const int swz = (blockIdx.x & 7) * 32 + (blockIdx.x >> 3);
  const int dir = swz >> 7;
  const int by = (swz & 127) >> 3, bx = swz & 7;
  const int m0 = by * 256, n0 = bx * 256;
  const int t_proc = dir ? (6 - step) : step;
  const unsigned short* W = Wp + (size_t)dir * 2048 * 768;
  const unsigned short* hin = hbuf + ((size_t)(step & 1) * 2 + dir) * (4096 * 512);
  unsigned short* hout = hbuf + ((size_t)((step + 1) & 1) * 2 + dir) * (4096 * 512);
  float* cp = cbuf + (size_t)dir * (4096 * 512);
  const unsigned short* xsrc = rep_t + (size_t)t_proc * 4096 * 256;

  f32x4 acc[8][4];
#pragma unroll
  for (int i = 0; i < 8; ++i)
#pragma unroll
    for (int j = 0; j < 4; ++j) acc[i][j] = (f32x4){0.f, 0.f, 0.f, 0.f};

#define LSTM_STAGE_A(kt, buf)                                                     \
  if ((kt) < 4) stage256x64_swz(xsrc + (size_t)m0 * 256 + (kt) * 64, 256, AsB[buf], tid); \
  else          stage256x64_swz(hin + (size_t)m0 * 512 + ((kt) - 4) * 64, 512, AsB[buf], tid);

  LSTM_STAGE_A(0, 0)
  stage256x64_swz(W + (size_t)n0 * 768 + 0, 768, BsB[0], tid);
  LSTM_STAGE_A(1, 1)
  stage256x64_swz(W + (size_t)n0 * 768 + 64, 768, BsB[1], tid);

  for (int kt = 0; kt < 12; ++kt) {
    const int cur = kt & 1;
    KLOOP_GATE(kt, 12)
    ktile_256(AsB[cur], BsB[cur], wm, wn, lane, acc);
    KLOOP_FREE()
    if (kt + 2 < 12) {
      LSTM_STAGE_A(kt + 2, cur)
      stage256x64_swz(W + (size_t)n0 * 768 + (kt + 2) * 64, 768, BsB[cur], tid);
    }
  }
#undef LSTM_STAGE_A

  const int u = lane & 15;
  const int blk = (n0 + wn * 64) >> 6;
  const int j = blk * 16 + u;
  const float bz0 = biasP[dir * 2048 + blk * 64 + 0 * 16 + u];
  const float bz1 = biasP[dir * 2048 + blk * 64 + 1 * 16 + u];
  const float bz2 = biasP[dir * 2048 + blk * 64 + 2 * 16 + u];
  const float bz3 = biasP[dir * 2048 + blk * 64 + 3 * 16 + u];
#pragma unroll
  for (int mi = 0; mi < 8; ++mi)
#pragma unroll
    for (int r = 0; r < 4; ++r) {
      int row = m0 + wm * 128 + mi * 16 + (lane >> 4) * 4 + r;
      float gi = acc[mi][0][r] + bz0;
      float gf = acc[mi][1][r] + bz1;
      float gg = acc[mi][2][r] + bz2;
      float go = acc[mi][3][r] + bz3;
      size_t ci = (size_t)row * 512 + j;
      float c = sigmoidf(gf) * cp[ci] + sigmoidf(gi) * fast_tanh(gg);
      cp[ci] = c;
      float h = sigmoidf(go) * fast_tanh(c);
      unsigned short hb = f2b(h);
      hout[ci] = hb;
      lstm1[((size_t)row * 7 + t_proc) * 1024 + dir * 512 + j] = hb;
    }
}

// ---------------------------------------------------------------------------
// Fused attention, MFMA Gram (zero shuffles).
// Per block = 1 batch row, 4 waves.
//   LDS: Ehi/Elo/Q as [7][1032] bf16 (row pad -> 2-way banks, free)
//   G1 = Q.Ehi^T + Q.Elo^T, G2 = Q.Q^T via mfma_16x16x32 (rows clamped to <7)
//   recursion (wave 0, f32), output = C @ [Ehi+Elo; Q] on VALU, unrolled.
// ---------------------------------------------------------------------------
__global__ __launch_bounds__(256) void att_fused2_kernel(
    const float* __restrict__ enc, const unsigned short* __restrict__ lstm1,
    unsigned short* __restrict__ att) {
  __shared__ unsigned short Qs[7 * 1032];
  __shared__ unsigned short Ehs[7 * 1032];
  __shared__ unsigned short Els[7 * 1032];
  __shared__ float P[4 * 2 * 64 * 4];
  __shared__ float sG[98];
  __shared__ float sC[7][14];
  __shared__ float sA[16];
  const int tid = threadIdx.x, lane = tid & 63, wv = tid >> 6;
  const int b = blockIdx.x;
  const float* Eb = enc + (size_t)b * 7168;
  const unsigned short* Qb = lstm1 + (size_t)b * 7168;

  if (tid < 98) ((float*)sC)[tid] = 0.f;

  // ---- stage: E -> hi/lo bf16, Q -> bf16 LDS ----
  const f32x4* Eb4 = (const f32x4*)Eb;
#pragma unroll
  for (int r = 0; r < 7; ++r) {
    f32x4 v = Eb4[r * 256 + tid];
    us4 hi, lo;
#pragma unroll
    for (int e = 0; e < 4; ++e) {
      hi[e] = f2b(v[e]);
      lo[e] = f2b(v[e] - b2f(hi[e]));
    }
    *(us4*)&Ehs[r * 1032 + tid * 4] = hi;
    *(us4*)&Els[r * 1032 + tid * 4] = lo;
  }
  const bf16x8* Qb8 = (const bf16x8*)Qb;
#pragma unroll
  for (int r = 0; r < 4; ++r) {
    int idx = r * 256 + tid;
    if (idx < 896) {
      int row = idx >> 7, col = (idx & 127) * 8;
      *(bf16x8*)&Qs[row * 1032 + col] = Qb8[idx];
    }
  }
  __syncthreads();

  // ---- Gram via MFMA: wave wv covers k in [wv*256, wv*256+256) ----
  {
    const int rr = lane & 15;
    const int rowc = rr > 6 ? 6 : rr;            // clamp: no OOB, garbage rows dup row6
    const int kbase = wv * 256 + (lane >> 4) * 8;
    f32x4 g1 = {0.f, 0.f, 0.f, 0.f}, g2 = {0.f, 0.f, 0.f, 0.f};
#pragma unroll
    for (int s = 0; s < 8; ++s) {
      const int k0 = kbase + s * 32;
      bf16x8 aq = *(const bf16x8*)&Qs[rowc * 1032 + k0];
      bf16x8 bh = *(const bf16x8*)&Ehs[rowc * 1032 + k0];
      bf16x8 bl = *(const bf16x8*)&Els[rowc * 1032 + k0];
      g1 = __builtin_amdgcn_mfma_f32_16x16x32_bf16(aq, bh, g1, 0, 0, 0);
      g1 = __builtin_amdgcn_mfma_f32_16x16x32_bf16(aq, bl, g1, 0, 0, 0);
      g2 = __builtin_amdgcn_mfma_f32_16x16x32_bf16(aq, aq, g2, 0, 0, 0);
    }
    *(f32x4*)&P[((wv * 2 + 0) * 64 + lane) * 4] = g1;
    *(f32x4*)&P[((wv * 2 + 1) * 64 + lane) * 4] = g2;
  }
  __syncthreads();

  // ---- gather G entries: G[i][v] (v<7: E-dot; v>=7: Q.Q with m=v-7) ----
  if (tid < 98) {
    int i = tid / 14, v = tid - i * 14;
    int col = v < 7 ? v : v - 7;
    int tile = v < 7 ? 0 : 1;
    int ln = ((i >> 2) << 4) | col;
    int rg = i & 3;
    float s = 0.f;
#pragma unroll
    for (int w = 0; w < 4; ++w) s += P[((w * 2 + tile) * 64 + ln) * 4 + rg];
    sG[i * 14 + v] = s;
  }
  __syncthreads();

  // ---- recursion in coefficient space (wave 0) ----
  if (wv == 0) {
    for (int i = 0; i < 7; ++i) {
      const int nt = 7 + i;
      float s = -1e30f;
      if (lane < 7) {
        s = sG[i * 14 + lane];
      } else if (lane < nt) {
        int jj = lane - 7;
        float a2 = 0.f;
#pragma unroll
        for (int v = 0; v < 14; ++v) a2 += sC[jj][v] * sG[i * 14 + v];
        s = a2;
      }
      float mx = s;
#pragma unroll
      for (int off = 8; off >= 1; off >>= 1) mx = fmaxf(mx, __shfl_xor(mx, off, 16));
      float e = (lane < nt) ? __expf(s - mx) : 0.f;
      float sum = e;
#pragma unroll
      for (int off = 8; off >= 1; off >>= 1) sum += __shfl_xor(sum, off, 16);
      float a = e / sum;
      if (lane < 16) sA[lane] = a;
      if (lane < 14) {
        float c = (lane < 7) ? sA[lane] : 0.f;
        for (int jj = 0; jj < i; ++jj) c += sA[7 + jj] * sC[jj][lane];
        if (lane == 7 + i) c += 1.f;
        sC[i][lane] = c;
      }
    }
  }
  __syncthreads();

  // ---- output: att[i][d] = sum_v C[i][v]*basis[v][d], thread owns 4 dims ----
  {
    const int d0 = tid * 4;
    float acc[7][4];
#pragma unroll
    for (int i = 0; i < 7; ++i)
#pragma unroll
      for (int e = 0; e < 4; ++e) acc[i][e] = 0.f;
#pragma unroll
    for (int t = 0; t < 7; ++t) {
      us4 h = *(const us4*)&Ehs[t * 1032 + d0];
      us4 l = *(const us4*)&Els[t * 1032 + d0];
      float ev[4];
#pragma unroll
      for (int e = 0; e < 4; ++e) ev[e] = b2f(h[e]) + b2f(l[e]);
#pragma unroll
      for (int i = 0; i < 7; ++i) {
        float c = sC[i][t];
#pragma unroll
        for (int e = 0; e < 4; ++e) acc[i][e] += c * ev[e];
      }
    }
#pragma unroll
    for (int m = 0; m < 7; ++m) {
      us4 qv = *(const us4*)&Qs[m * 1032 + d0];
      float qf[4];
#pragma unroll
      for (int e = 0; e < 4; ++e) qf[e] = b2f(qv[e]);
#pragma unroll
      for (int i = m; i < 7; ++i) {     // sC[i][7+m]==0 for i<m
        float c = sC[i][7 + m];
#pragma unroll
        for (int e = 0; e < 4; ++e) acc[i][e] += c * qf[e];
      }
    }
    unsigned short* Ab = att + (size_t)b * 7168;
#pragma unroll
    for (int i = 0; i < 7; ++i) {
      us4 r;
#pragma unroll
      for (int e = 0; e < 4; ++e) r[e] = f2b(acc[i][e]);
      *(us4*)(Ab + i * 1024 + d0) = r;
    }
  }
}

// ---------------------------------------------------------------------------
// up_t = softsign(att @ emb_w + emb_b), 256x256 core
// ---------------------------------------------------------------------------
__global__ __launch_bounds__(512, 2) void gemm_emb256_kernel(
    const unsigned short* __restrict__ A, const unsigned short* __restrict__ Bt,
    const float* __restrict__ bias, unsigned short* __restrict__ up_t) {
  __shared__ unsigned short AsB[2][256 * 64];
  __shared__ unsigned short BsB[2][256 * 64];
  const int tid = threadIdx.x, lane = tid & 63, wv = tid >> 6;
  const int wm = wv >> 2, wn = wv & 3;
  const int swz = (blockIdx.x & 7) * 56 + (blockIdx.x >> 3);
  const int by = swz >> 2, bx = swz & 3;
  const int m0 = by * 256, n0 = bx * 256;

  f32x4 acc[8][4];
#pragma unroll
  for (int i = 0; i < 8; ++i)
#pragma unroll
    for (int j = 0; j < 4; ++j) acc[i][j] = (f32x4){0.f, 0.f, 0.f, 0.f};

  stage256x64_swz(A + (size_t)m0 * 1024 + 0, 1024, AsB[0], tid);
  stage256x64_swz(Bt + (size_t)n0 * 1024 + 0, 1024, BsB[0], tid);
  stage256x64_swz(A + (size_t)m0 * 1024 + 64, 1024, AsB[1], tid);
  stage256x64_swz(Bt + (size_t)n0 * 1024 + 64, 1024, BsB[1], tid);

  for (int kt = 0; kt < 16; ++kt) {
    const int cur = kt & 1;
    KLOOP_GATE(kt, 16)
    ktile_256(AsB[cur], BsB[cur], wm, wn, lane, acc);
    KLOOP_FREE()
    if (kt + 2 < 16) {
      stage256x64_swz(A + (size_t)m0 * 1024 + (kt + 2) * 64, 1024, AsB[cur], tid);
      stage256x64_swz(Bt + (size_t)n0 * 1024 + (kt + 2) * 64, 1024, BsB[cur], tid);
    }
  }

#pragma unroll
  for (int ni = 0; ni < 4; ++ni) {
    int np = n0 + wn * 64 + ni * 16 + (lane & 15);
    int o = (np & 63) * 16 + (np >> 6);
    float bv = bias[o];
#pragma unroll
    for (int mi = 0; mi < 8; ++mi)
#pragma unroll
      for (int r = 0; r < 4; ++r) {
        int m = m0 + wm * 128 + mi * 16 + (lane >> 4) * 4 + r;
        float v = acc[mi][ni][r] + bv;
        v = v / (1.f + fabsf(v));
        up_t[(size_t)m * 1024 + np] = f2b(v);
      }
  }
}

// ---------------------------------------------------------------------------
// dc3
// ---------------------------------------------------------------------------
__global__ __launch_bounds__(256) void dc3_kernel(const unsigned short* __restrict__ up_t,
                                                  const float* __restrict__ w3,
                                                  const float* __restrict__ b3,
                                                  unsigned short* __restrict__ y1_t) {
  const int lane = threadIdx.x & 63, wv = threadIdx.x >> 6;
  const int kq = (lane >> 4) * 8;
  const int oc = lane & 15;
  bf16x8 bf[2][6];
#pragma unroll
  for (int nt = 0; nt < 2; ++nt)
#pragma unroll
    for (int kk = 0; kk < 6; ++kk) {
      bf16x8 v;
#pragma unroll
      for (int t = 0; t < 8; ++t) {
        int k = kk * 32 + kq + t;
        int jj = k >> 6, ic = k & 63;
        v[t] = (short)f2b(w3[((size_t)ic * 32 + nt * 16 + oc) * 3 + jj]);
      }
      bf[nt][kk] = v;
    }
  const float bia0 = b3[oc], bia1 = b3[16 + oc];
  const int base_chunk = blockIdx.x * 32 + wv * 8;
  for (int cc = 0; cc < 8; ++cc) {
    const int chunk = base_chunk + cc;
    int m = chunk * 16 + (lane & 15);
    int img = m / 18, ow = m - img * 18;
    const unsigned short* arow = up_t + (size_t)img * 1024;
    f32x4 acc0 = {0.f, 0.f, 0.f, 0.f}, acc1 = {0.f, 0.f, 0.f, 0.f};
#pragma unroll
    for (int kk = 0; kk < 6; ++kk) {
      int jj = kk >> 1;
      int ic0 = (kk & 1) * 32 + kq;
      int iw = ow - jj;
      bf16x8 a = {0, 0, 0, 0, 0, 0, 0, 0};
      if ((unsigned)iw < 16u) a = *(const bf16x8*)(arow + iw * 64 + ic0);
      acc0 = __builtin_amdgcn_mfma_f32_16x16x32_bf16(a, bf[0][kk], acc0, 0, 0, 0);
      acc1 = __builtin_amdgcn_mfma_f32_16x16x32_bf16(a, bf[1][kk], acc1, 0, 0, 0);
    }
#pragma unroll
    for (int r = 0; r < 4; ++r) {
      int mm = chunk * 16 + (lane >> 4) * 4 + r;
      float v0 = acc0[r] + bia0; v0 = v0 > 0.f ? v0 : 0.01f * v0;
      float v1 = acc1[r] + bia1; v1 = v1 > 0.f ? v1 : 0.01f * v1;
      y1_t[(size_t)mm * 32 + oc] = f2b(v0);
      y1_t[(size_t)mm * 32 + 16 + oc] = f2b(v1);
    }
  }
}

// ---------------------------------------------------------------------------
// dc1
// ---------------------------------------------------------------------------
__global__ __launch_bounds__(256) void dc1_kernel(const unsigned short* __restrict__ y1_t,
                                                  const float* __restrict__ w1,
                                                  const float* __restrict__ b1,
                                                  unsigned short* __restrict__ y2_t) {
  const int lane = threadIdx.x & 63, wv = threadIdx.x >> 6;
  const int kq = (lane >> 4) * 8;
  const int oc = lane & 15;
  bf16x8 bf[5];
#pragma unroll
  for (int kk = 0; kk < 5; ++kk) {
    bf16x8 v;
#pragma unroll
    for (int t = 0; t < 8; ++t) {
      int ic = kq + t;
      v[t] = (short)f2b(w1[((size_t)ic * 16 + oc) * 5 + kk]);
    }
    bf[kk] = v;
  }
  const float bia = b1[oc];
  const int base_chunk = blockIdx.x * 32 + wv * 8;
  for (int cc = 0; cc < 8; ++cc) {
    const int chunk = base_chunk + cc;
    int m = chunk * 16 + (lane & 15);
    int img = m / 22, ow = m - img * 22;
    const unsigned short* abase = y1_t + (size_t)img * 18 * 32;
    f32x4 acc = {0.f, 0.f, 0.f, 0.f};
#pragma unroll
    for (int kk = 0; kk < 5; ++kk) {
      int iw = ow - kk;
      bf16x8 a = {0, 0, 0, 0, 0, 0, 0, 0};
      if ((unsigned)iw < 18u) a = *(const bf16x8*)(abase + iw * 32 + kq);
      acc = __builtin_amdgcn_mfma_f32_16x16x32_bf16(a, bf[kk], acc, 0, 0, 0);
    }
#pragma unroll
    for (int r = 0; r < 4; ++r) {
      int mm = chunk * 16 + (lane >> 4) * 4 + r;
      float v = acc[r] + bia;
      v = v > 0.f ? v : 0.01f * v;
      y2_t[(size_t)mm * 16 + oc] = f2b(v);
    }
  }
}

// ---------------------------------------------------------------------------
// dc2 + softmax over oh
// ---------------------------------------------------------------------------
__global__ __launch_bounds__(256) void dc2_kernel(const unsigned short* __restrict__ y2_t,
                                                  const float* __restrict__ w2,
                                                  const float* __restrict__ b2,
                                                  float* __restrict__ out) {
  int idx = blockIdx.x * 256 + threadIdx.x;
  int img = idx / 24, ow = idx - img * 24;
  float lg0 = b2[0], lg1 = b2[0], lg2 = b2[0];
#pragma unroll
  for (int jj = 0; jj < 3; ++jj) {
    int iw = ow - jj;
    if ((unsigned)iw >= 22u) continue;
    const unsigned short* row = y2_t + ((size_t)img * 22 + iw) * 16;
    bf16x8 v0 = *(const bf16x8*)(row);
    bf16x8 v1 = *(const bf16x8*)(row + 8);
    float x[16];
#pragma unroll
    for (int ic = 0; ic < 8; ++ic) {
      x[ic] = b2f((unsigned short)v0[ic]);
      x[8 + ic] = b2f((unsigned short)v1[ic]);
    }
#pragma unroll
    for (int ic = 0; ic < 16; ++ic) {
      lg0 += x[ic] * w2[ic * 9 + 0 * 3 + jj];
      lg1 += x[ic] * w2[ic * 9 + 1 * 3 + jj];
      lg2 += x[ic] * w2[ic * 9 + 2 * 3 + jj];
    }
  }
  lg0 = lg0 > 0.f ? lg0 : 0.01f * lg0;
  lg1 = lg1 > 0.f ? lg1 : 0.01f * lg1;
  lg2 = lg2 > 0.f ? lg2 : 0.01f * lg2;
  float mx = fmaxf(lg0, fmaxf(lg1, lg2));
  float e0 = __expf(lg0 - mx), e1 = __expf(lg1 - mx), e2 = __expf(lg2 - mx);
  float inv = 1.f / (e0 + e1 + e2);
  size_t ob = (size_t)img * 72 + ow;
  out[ob] = e0 * inv;
  out[ob + 24] = e1 * inv;
  out[ob + 48] = e2 * inv;
}

// ---------------------------------------------------------------------------
extern "C" void kernel_launch(void* const* d_in, const int* in_sizes, int n_in,
                              void* d_out, int out_size, void* d_ws, size_t ws_size,
                              hipStream_t stream) {
  (void)in_sizes; (void)n_in; (void)out_size; (void)ws_size;
  const float* enc    = (const float*)d_in[0];
  const float* noise  = (const float*)d_in[1];
  const float* erep_w = (const float*)d_in[2];
  const float* erep_b = (const float*)d_in[3];
  const float* wih_f  = (const float*)d_in[4];
  const float* whh_f  = (const float*)d_in[5];
  const float* bih_f  = (const float*)d_in[6];
  const float* bhh_f  = (const float*)d_in[7];
  const float* wih_b  = (const float*)d_in[8];
  const float* whh_b  = (const float*)d_in[9];
  const float* bih_b  = (const float*)d_in[10];
  const float* bhh_b  = (const float*)d_in[11];
  const float* emb_w  = (const float*)d_in[12];
  const float* emb_b  = (const float*)d_in[13];
  const float* dc3w   = (const float*)d_in[14];
  const float* dc3b   = (const float*)d_in[15];
  const float* dc1w   = (const float*)d_in[16];
  const float* dc1b   = (const float*)d_in[17];
  const float* dc2w   = (const float*)d_in[18];
  const float* dc2b   = (const float*)d_in[19];
  float* out = (float*)d_out;

  char* p = (char*)d_ws;
  auto carve = [&p](size_t bytes) {
    char* r = p;
    p += (bytes + 255) & ~(size_t)255;
    return r;
  };
  unsigned short* rep_t  = (unsigned short*)carve(7ull * 4096 * 256 * 2);
  unsigned short* lstmW  = (unsigned short*)carve(2ull * 2048 * 768 * 2);
  float*          lstmB  = (float*)carve(2ull * 2048 * 4);
  unsigned short* noiseb = (unsigned short*)carve(4096ull * 256 * 2);
  unsigned short* erepT  = (unsigned short*)carve(1792ull * 256 * 2);
  unsigned short* embT   = (unsigned short*)carve(1024ull * 1024 * 2);
  unsigned short* hbuf   = (unsigned short*)carve(4ull * 4096 * 512 * 2);   // [pp][dir]
  float*          cbuf   = (float*)carve(2ull * 4096 * 512 * 4);            // [dir]
  unsigned short* lstm1  = (unsigned short*)carve(4096ull * 7 * 1024 * 2);
  unsigned short* att    = (unsigned short*)carve(28672ull * 1024 * 2);
  unsigned short* up_t   = (unsigned short*)carve(28672ull * 1024 * 2);
  unsigned short* y1_t   = (unsigned short*)carve(28672ull * 18 * 32 * 2);
  unsigned short* y2_t   = (unsigned short*)carve(28672ull * 22 * 16 * 2);

  hipMemsetAsync(hbuf, 0, 2ull * 4096 * 512 * 2, stream);
  hipMemsetAsync(cbuf, 0, 2ull * 4096 * 512 * 4, stream);

  pack_kernel<<<2048, 256, 0, stream>>>(noise, erep_w, emb_w, wih_f, whh_f, bih_f, bhh_f,
                                        wih_b, whh_b, bih_b, bhh_b,
                                        noiseb, erepT, embT, lstmW, lstmB);
  gemm_rep_kernel<<<dim3(14, 32), 256, 0, stream>>>(noiseb, erepT, erep_b, rep_t);
  for (int s = 0; s < 7; ++s)
    lstm_step256_kernel<<<256, 512, 0, stream>>>(rep_t, lstmW, lstmB, hbuf, cbuf, lstm1, s);
  att_fused2_kernel<<<4096, 256, 0, stream>>>(enc, lstm1, att);
  gemm_emb256_kernel<<<448, 512, 0, stream>>>(att, embT, emb_b, up_t);
  dc3_kernel<<<1008, 256, 0, stream>>>(up_t, dc3w, dc3b, y1_t);
  dc1_kernel<<<1232, 256, 0, stream>>>(y1_t, dc1w, dc1b, y2_t);
  dc2_kernel<<<2688, 256, 0, stream>>>(y2_t, dc2w, dc2b, out);
}

// Round 6
// 512.360 us; speedup vs baseline: 1.3719x; 1.0403x over previous
//
#include <hip/hip_runtime.h>
#include <stdint.h>

// ---------------------------------------------------------------------------
// decoder_80487687127254 : B=4096 T=7 H=512 L=256 D=1024
// ---------------------------------------------------------------------------

typedef __attribute__((ext_vector_type(4))) float f32x4;
typedef __attribute__((ext_vector_type(8))) short bf16x8;
typedef __attribute__((ext_vector_type(4))) unsigned short us4;

__device__ __forceinline__ unsigned short f2b(float f) {
  union { float f; unsigned u; } x; x.f = f;
  unsigned r = x.u + 0x7FFFu + ((x.u >> 16) & 1u);   // RNE
  return (unsigned short)(r >> 16);
}
__device__ __forceinline__ float b2f(unsigned short s) {
  union { unsigned u; float f; } x; x.u = ((unsigned)s) << 16; return x.f;
}
__device__ __forceinline__ float sigmoidf(float x) {
  return 1.f / (1.f + __expf(-x));
}
__device__ __forceinline__ float fast_tanh(float x) {
  x = fminf(15.f, fmaxf(-15.f, x));
  float e = __expf(2.f * x);
  return (e - 1.f) / (e + 1.f);
}

// async global->LDS, 16B per lane; LDS dest must be wave-uniform (HW adds lane*16)
__device__ __forceinline__ void gl_lds16(const void* g, void* l) {
  auto gp = reinterpret_cast<const __attribute__((address_space(1))) unsigned int*>(
      reinterpret_cast<uintptr_t>(g));
  auto lp = reinterpret_cast<__attribute__((address_space(3))) unsigned int*>(
      reinterpret_cast<uintptr_t>(l));
  __builtin_amdgcn_global_load_lds(gp, lp, 16, 0, 0);
}

// ===========================================================================
// 256x256 8-wave GEMM core, 8-PHASE schedule (T3+T4+T5).
// K-tile (BK=64) split into two K-halves [256 rows][32 cols], each a compact
// LDS region with granule swizzle pos = g ^ ((row>>1)&3)  (2-way banks = free).
// Phases per K-tile: (kk0,m0)(kk0,m1)(kk1,m0)(kk1,m1); each phase stages one
// K-half of a future tile (2 gl_lds/thread) and computes 16 MFMA.
// Gates: vmcnt(8) before each kk-entry (4 half-stages newer than needed pair).
// ===========================================================================

// stage one K-half (256 rows x 32 cols): 2 gl_lds per thread, dest linear,
// source granule pre-inverse-swizzled.  src points at (row0, k_half_col0).
__device__ __forceinline__ void stage_half(const unsigned short* src, int ld,
                                           unsigned short* hbase, int tid) {
  const int row_in = tid >> 2;   // 0..127
  const int gidx = tid & 3;      // dest granule position within half
#pragma unroll
  for (int r = 0; r < 2; ++r) {
    int row = r * 128 + row_in;
    int gsrc = gidx ^ ((row >> 1) & 3);
    gl_lds16(src + (size_t)row * ld + gsrc * 8, hbase + r * 4096 + (tid >> 6) * 512);
  }
}

__device__ __forceinline__ bf16x8 lds_fragH(const unsigned short* hbase, int row, int lq) {
  return *(const bf16x8*)(hbase + row * 32 + (lq ^ (((row >> 1) & 3) << 3)));
}

__device__ __forceinline__ void gate8() { asm volatile("s_waitcnt vmcnt(8)" ::: "memory"); }
__device__ __forceinline__ void gate4() { asm volatile("s_waitcnt vmcnt(4)" ::: "memory"); }
__device__ __forceinline__ void gate0() { asm volatile("s_waitcnt vmcnt(0)" ::: "memory"); }

#define PH_TOP()                         \
  __builtin_amdgcn_s_barrier();          \
  __builtin_amdgcn_sched_barrier(0)

// one phase's ds_read + MFMA cluster. MH = m-half (0/1). READB: load B frags.
template<int MH, bool READB>
__device__ __forceinline__ void phase_mfma(const unsigned short* Ah, const unsigned short* Bh,
                                           int wm, int wn, int lane,
                                           bf16x8 (&bfr)[4], f32x4 (&acc)[8][4]) {
  const int lr = lane & 15, lq = (lane >> 4) * 8;
  if (READB) {
#pragma unroll
    for (int ni = 0; ni < 4; ++ni) bfr[ni] = lds_fragH(Bh, wn * 64 + ni * 16 + lr, lq);
  }
  bf16x8 a[4];
#pragma unroll
  for (int i = 0; i < 4; ++i)
    a[i] = lds_fragH(Ah, wm * 128 + (MH * 4 + i) * 16 + lr, lq);
  asm volatile("s_waitcnt lgkmcnt(0)" ::: "memory");
  __builtin_amdgcn_sched_barrier(0);
  __builtin_amdgcn_s_setprio(1);
#pragma unroll
  for (int i = 0; i < 4; ++i)
#pragma unroll
    for (int ni = 0; ni < 4; ++ni)
      acc[MH * 4 + i][ni] =
          __builtin_amdgcn_mfma_f32_16x16x32_bf16(a[i], bfr[ni], acc[MH * 4 + i][ni], 0, 0, 0);
  __builtin_amdgcn_s_setprio(0);
}

// ---------------------------------------------------------------------------
// 128x128 core (kept for gemm_rep)
// ---------------------------------------------------------------------------
__device__ __forceinline__ void stage128x64(const unsigned short* src, int ld,
                                            unsigned short* lds, int wv, int lane) {
#pragma unroll
  for (int r = 0; r < 4; ++r) {
    int row = r * 32 + wv * 8 + (lane >> 3);
    gl_lds16(src + (size_t)row * ld + (lane & 7) * 8, lds + (r * 32 + wv * 8) * 64);
  }
}
__device__ __forceinline__ void mfma_tile(const unsigned short* As, const unsigned short* Bs,
                                          int wm, int wn, int lane, f32x4 acc[4][4]) {
#pragma unroll
  for (int kk = 0; kk < 2; ++kk) {
    int ko = kk * 32 + (lane >> 4) * 8;
    bf16x8 a[4], b[4];
#pragma unroll
    for (int i = 0; i < 4; ++i)
      a[i] = *(const bf16x8*)(As + (size_t)(wm * 64 + i * 16 + (lane & 15)) * 64 + ko);
#pragma unroll
    for (int i = 0; i < 4; ++i)
      b[i] = *(const bf16x8*)(Bs + (size_t)(wn * 64 + i * 16 + (lane & 15)) * 64 + ko);
#pragma unroll
    for (int mi = 0; mi < 4; ++mi)
#pragma unroll
      for (int ni = 0; ni < 4; ++ni)
        acc[mi][ni] = __builtin_amdgcn_mfma_f32_16x16x32_bf16(a[mi], b[ni], acc[mi][ni], 0, 0, 0);
  }
}

// ---------------------------------------------------------------------------
// pack
// ---------------------------------------------------------------------------
__global__ __launch_bounds__(256) void pack_kernel(
    const float* __restrict__ noise, const float* __restrict__ erep_w,
    const float* __restrict__ emb_w,
    const float* __restrict__ wih_f, const float* __restrict__ whh_f,
    const float* __restrict__ bih_f, const float* __restrict__ bhh_f,
    const float* __restrict__ wih_b, const float* __restrict__ whh_b,
    const float* __restrict__ bih_b, const float* __restrict__ bhh_b,
    unsigned short* __restrict__ noiseb, unsigned short* __restrict__ erepT,
    unsigned short* __restrict__ embT, unsigned short* __restrict__ lstmW,
    float* __restrict__ lstmB) {
  const int N0 = 4096 * 256;
  const int N1 = 1792 * 256;
  const int N2 = 1024 * 1024;
  const int N3 = 2 * 2048 * 768;
  const int N4 = 2 * 2048;
  const int total = N0 + N1 + N2 + N3 + N4;
  for (int i = blockIdx.x * 256 + threadIdx.x; i < total; i += gridDim.x * 256) {
    int x = i;
    if (x < N0) { noiseb[x] = f2b(noise[x]); continue; }
    x -= N0;
    if (x < N1) { int n = x >> 8, k = x & 255; erepT[x] = f2b(erep_w[k * 1792 + n]); continue; }
    x -= N1;
    if (x < N2) {
      int n = x >> 10, k = x & 1023;
      int o = (n & 63) * 16 + (n >> 6);
      embT[x] = f2b(emb_w[k * 1024 + o]);
      continue;
    }
    x -= N2;
    if (x < N3) {
      int dir = x / (2048 * 768);
      int r = x - dir * (2048 * 768);
      int npk = r / 768, k = r - (r / 768) * 768;
      int blk = npk >> 6, g = (npk >> 4) & 3, u = npk & 15;
      int o = g * 512 + blk * 16 + u;
      const float* wih = dir ? wih_b : wih_f;
      const float* whh = dir ? whh_b : whh_f;
      float v = (k < 256) ? wih[k * 2048 + o] : whh[(k - 256) * 2048 + o];
      lstmW[x] = f2b(v);
      continue;
    }
    x -= N3;
    {
      int dir = x >> 11, npk = x & 2047;
      int blk = npk >> 6, g = (npk >> 4) & 3, u = npk & 15;
      int o = g * 512 + blk * 16 + u;
      lstmB[x] = dir ? (bih_b[o] + bhh_b[o]) : (bih_f[o] + bhh_f[o]);
    }
  }
}

// ---------------------------------------------------------------------------
// rep = softsign(noise @ erep_w + b)
// ---------------------------------------------------------------------------
__global__ __launch_bounds__(256) void gemm_rep_kernel(
    const unsigned short* __restrict__ A, const unsigned short* __restrict__ Bt,
    const float* __restrict__ bias, unsigned short* __restrict__ rep_t) {
  __shared__ unsigned short As[128 * 64];
  __shared__ unsigned short Bs[128 * 64];
  const int lane = threadIdx.x & 63, wv = threadIdx.x >> 6;
  const int wm = wv >> 1, wn = wv & 1;
  const int m0 = blockIdx.y * 128, n0 = blockIdx.x * 128;
  f32x4 acc[4][4];
#pragma unroll
  for (int i = 0; i < 4; ++i)
#pragma unroll
    for (int j = 0; j < 4; ++j) acc[i][j] = (f32x4){0.f, 0.f, 0.f, 0.f};
  for (int k0 = 0; k0 < 256; k0 += 64) {
    stage128x64(A + (size_t)m0 * 256 + k0, 256, As, wv, lane);
    stage128x64(Bt + (size_t)n0 * 256 + k0, 256, Bs, wv, lane);
    __syncthreads();
    mfma_tile(As, Bs, wm, wn, lane, acc);
    __syncthreads();
  }
#pragma unroll
  for (int ni = 0; ni < 4; ++ni) {
    int n = n0 + wn * 64 + ni * 16 + (lane & 15);
    float bv = bias[n];
    int t = n >> 8, l = n & 255;
#pragma unroll
    for (int mi = 0; mi < 4; ++mi)
#pragma unroll
      for (int r = 0; r < 4; ++r) {
        int m = m0 + wm * 64 + mi * 16 + (lane >> 4) * 4 + r;
        float v = acc[mi][ni][r] + bv;
        v = v / (1.f + fabsf(v));
        rep_t[((size_t)t * 4096 + m) * 256 + l] = f2b(v);
      }
  }
}

// ---------------------------------------------------------------------------
// LSTM step, 256x256 8-phase core. K=768 (12 K-tiles: 4 from x, 8 from h).
// ---------------------------------------------------------------------------
__global__ __launch_bounds__(512, 2) void lstm_step256_kernel(
    const unsigned short* __restrict__ rep_t, const unsigned short* __restrict__ Wp,
    const float* __restrict__ biasP, unsigned short* __restrict__ hbuf,
    float* __restrict__ cbuf, unsigned short* __restrict__ lstm1, int step) {
  __shared__ unsigned short Ax[2][2][8192];   // [buf][khalf][256*32]
  __shared__ unsigned short Bx[2][2][8192];
  const int tid = threadIdx.x, lane = tid & 63, wv = tid >> 6;
  const int wm = wv >> 2, wn = wv & 3;
  const int swz = (blockIdx.x & 7) * 32 + (blockIdx.x >> 3);
  const int dir = swz >> 7;
  const int by = (swz & 127) >> 3, bx = swz & 7;
  const int m0 = by * 256, n0 = bx * 256;
  const int t_proc = dir ? (6 - step) : step;
  const unsigned short* W = Wp + (size_t)dir * 2048 * 768;
  const unsigned short* hin = hbuf + ((size_t)(step & 1) * 2 + dir) * (4096 * 512);
  unsigned short* hout = hbuf + ((size_t)((step + 1) & 1) * 2 + dir) * (4096 * 512);
  float* cp = cbuf + (size_t)dir * (4096 * 512);
  const unsigned short* xsrc = rep_t + (size_t)t_proc * 4096 * 256;

  f32x4 acc[8][4];
#pragma unroll
  for (int i = 0; i < 8; ++i)
#pragma unroll
    for (int j = 0; j < 4; ++j) acc[i][j] = (f32x4){0.f, 0.f, 0.f, 0.f};

#define ASRC_L(kt, h) ((kt) < 4 ? xsrc + (size_t)m0 * 256 + (kt) * 64 + (h) * 32 \
                                : hin + (size_t)m0 * 512 + ((kt) - 4) * 64 + (h) * 32)
#define ALD_L(kt) ((kt) < 4 ? 256 : 512)
#define BSRC_L(kt, h) (W + (size_t)n0 * 768 + (kt) * 64 + (h) * 32)

  // prologue: A0h0,B0h0,A0h1,B0h1,A1h0,B1h0 (12 loads)
  stage_half(ASRC_L(0, 0), ALD_L(0), Ax[0][0], tid);
  stage_half(BSRC_L(0, 0), 768, Bx[0][0], tid);
  stage_half(ASRC_L(0, 1), ALD_L(0), Ax[0][1], tid);
  stage_half(BSRC_L(0, 1), 768, Bx[0][1], tid);
  stage_half(ASRC_L(1, 0), ALD_L(1), Ax[1][0], tid);
  stage_half(BSRC_L(1, 0), 768, Bx[1][0], tid);

  const int NITER = 6;   // 12 K-tiles
  for (int it = 0; it < NITER; ++it) {
    const bool last = (it == NITER - 1);
    const int t1 = 2 * it + 1, t2 = 2 * it + 2, t3 = 2 * it + 3;
    bf16x8 bfr[4];
    // p0: compute buf0 kk0 m0; stage A[t1]h1 -> Ax[1][1]
    gate8(); PH_TOP();
    stage_half(ASRC_L(t1, 1), ALD_L(t1), Ax[1][1], tid);
    phase_mfma<0, true>(Ax[0][0], Bx[0][0], wm, wn, lane, bfr, acc);
    // p1: buf0 kk0 m1; stage B[t1]h1
    PH_TOP();
    stage_half(BSRC_L(t1, 1), 768, Bx[1][1], tid);
    phase_mfma<1, false>(Ax[0][0], Bx[0][0], wm, wn, lane, bfr, acc);
    // p2: buf0 kk1 m0; stage A[t2]h0
    gate8(); PH_TOP();
    if (!last) stage_half(ASRC_L(t2, 0), ALD_L(t2), Ax[0][0], tid);
    phase_mfma<0, true>(Ax[0][1], Bx[0][1], wm, wn, lane, bfr, acc);
    // p3: buf0 kk1 m1; stage B[t2]h0
    PH_TOP();
    if (!last) stage_half(BSRC_L(t2, 0), 768, Bx[0][0], tid);
    phase_mfma<1, false>(Ax[0][1], Bx[0][1], wm, wn, lane, bfr, acc);
    // p4: buf1 kk0 m0; stage A[t2]h1
    if (last) gate4(); else gate8();
    PH_TOP();
    if (!last) stage_half(ASRC_L(t2, 1), ALD_L(t2), Ax[0][1], tid);
    phase_mfma<0, true>(Ax[1][0], Bx[1][0], wm, wn, lane, bfr, acc);
    // p5: buf1 kk0 m1; stage B[t2]h1
    PH_TOP();
    if (!last) stage_half(BSRC_L(t2, 1), 768, Bx[0][1], tid);
    phase_mfma<1, false>(Ax[1][0], Bx[1][0], wm, wn, lane, bfr, acc);
    // p6: buf1 kk1 m0; stage A[t3]h0
    if (last) gate0(); else gate8();
    PH_TOP();
    if (!last) stage_half(ASRC_L(t3, 0), ALD_L(t3), Ax[1][0], tid);
    phase_mfma<0, true>(Ax[1][1], Bx[1][1], wm, wn, lane, bfr, acc);
    // p7: buf1 kk1 m1; stage B[t3]h0
    PH_TOP();
    if (!last) stage_half(BSRC_L(t3, 0), 768, Bx[1][0], tid);
    phase_mfma<1, false>(Ax[1][1], Bx[1][1], wm, wn, lane, bfr, acc);
  }
#undef ASRC_L
#undef ALD_L
#undef BSRC_L

  const int u = lane & 15;
  const int blk = (n0 + wn * 64) >> 6;
  const int j = blk * 16 + u;
  const float bz0 = biasP[dir * 2048 + blk * 64 + 0 * 16 + u];
  const float bz1 = biasP[dir * 2048 + blk * 64 + 1 * 16 + u];
  const float bz2 = biasP[dir * 2048 + blk * 64 + 2 * 16 + u];
  const float bz3 = biasP[dir * 2048 + blk * 64 + 3 * 16 + u];
#pragma unroll
  for (int mi = 0; mi < 8; ++mi)
#pragma unroll
    for (int r = 0; r < 4; ++r) {
      int row = m0 + wm * 128 + mi * 16 + (lane >> 4) * 4 + r;
      float gi = acc[mi][0][r] + bz0;
      float gf = acc[mi][1][r] + bz1;
      float gg = acc[mi][2][r] + bz2;
      float go = acc[mi][3][r] + bz3;
      size_t ci = (size_t)row * 512 + j;
      float c = sigmoidf(gf) * cp[ci] + sigmoidf(gi) * fast_tanh(gg);
      cp[ci] = c;
      float h = sigmoidf(go) * fast_tanh(c);
      unsigned short hb = f2b(h);
      hout[ci] = hb;
      lstm1[((size_t)row * 7 + t_proc) * 1024 + dir * 512 + j] = hb;
    }
}

// ---------------------------------------------------------------------------
// Fused attention, MFMA Gram (unchanged from R5)
// ---------------------------------------------------------------------------
__global__ __launch_bounds__(256) void att_fused2_kernel(
    const float* __restrict__ enc, const unsigned short* __restrict__ lstm1,
    unsigned short* __restrict__ att) {
  __shared__ unsigned short Qs[7 * 1032];
  __shared__ unsigned short Ehs[7 * 1032];
  __shared__ unsigned short Els[7 * 1032];
  __shared__ float P[4 * 2 * 64 * 4];
  __shared__ float sG[98];
  __shared__ float sC[7][14];
  __shared__ float sA[16];
  const int tid = threadIdx.x, lane = tid & 63, wv = tid >> 6;
  const int b = blockIdx.x;
  const float* Eb = enc + (size_t)b * 7168;
  const unsigned short* Qb = lstm1 + (size_t)b * 7168;

  if (tid < 98) ((float*)sC)[tid] = 0.f;

  const f32x4* Eb4 = (const f32x4*)Eb;
#pragma unroll
  for (int r = 0; r < 7; ++r) {
    f32x4 v = Eb4[r * 256 + tid];
    us4 hi, lo;
#pragma unroll
    for (int e = 0; e < 4; ++e) {
      hi[e] = f2b(v[e]);
      lo[e] = f2b(v[e] - b2f(hi[e]));
    }
    *(us4*)&Ehs[r * 1032 + tid * 4] = hi;
    *(us4*)&Els[r * 1032 + tid * 4] = lo;
  }
  const bf16x8* Qb8 = (const bf16x8*)Qb;
#pragma unroll
  for (int r = 0; r < 4; ++r) {
    int idx = r * 256 + tid;
    if (idx < 896) {
      int row = idx >> 7, col = (idx & 127) * 8;
      *(bf16x8*)&Qs[row * 1032 + col] = Qb8[idx];
    }
  }
  __syncthreads();

  {
    const int rr = lane & 15;
    const int rowc = rr > 6 ? 6 : rr;
    const int kbase = wv * 256 + (lane >> 4) * 8;
    f32x4 g1 = {0.f, 0.f, 0.f, 0.f}, g2 = {0.f, 0.f, 0.f, 0.f};
#pragma unroll
    for (int s = 0; s < 8; ++s) {
      const int k0 = kbase + s * 32;
      bf16x8 aq = *(const bf16x8*)&Qs[rowc * 1032 + k0];
      bf16x8 bh = *(const bf16x8*)&Ehs[rowc * 1032 + k0];
      bf16x8 bl = *(const bf16x8*)&Els[rowc * 1032 + k0];
      g1 = __builtin_amdgcn_mfma_f32_16x16x32_bf16(aq, bh, g1, 0, 0, 0);
      g1 = __builtin_amdgcn_mfma_f32_16x16x32_bf16(aq, bl, g1, 0, 0, 0);
      g2 = __builtin_amdgcn_mfma_f32_16x16x32_bf16(aq, aq, g2, 0, 0, 0);
    }
    *(f32x4*)&P[((wv * 2 + 0) * 64 + lane) * 4] = g1;
    *(f32x4*)&P[((wv * 2 + 1) * 64 + lane) * 4] = g2;
  }
  __syncthreads();

  if (tid < 98) {
    int i = tid / 14, v = tid - i * 14;
    int col = v < 7 ? v : v - 7;
    int tile = v < 7 ? 0 : 1;
    int ln = ((i >> 2) << 4) | col;
    int rg = i & 3;
    float s = 0.f;
#pragma unroll
    for (int w = 0; w < 4; ++w) s += P[((w * 2 + tile) * 64 + ln) * 4 + rg];
    sG[i * 14 + v] = s;
  }
  __syncthreads();

  if (wv == 0) {
    for (int i = 0; i < 7; ++i) {
      const int nt = 7 + i;
      float s = -1e30f;
      if (lane < 7) {
        s = sG[i * 14 + lane];
      } else if (lane < nt) {
        int jj = lane - 7;
        float a2 = 0.f;
#pragma unroll
        for (int v = 0; v < 14; ++v) a2 += sC[jj][v] * sG[i * 14 + v];
        s = a2;
      }
      float mx = s;
#pragma unroll
      for (int off = 8; off >= 1; off >>= 1) mx = fmaxf(mx, __shfl_xor(mx, off, 16));
      float e = (lane < nt) ? __expf(s - mx) : 0.f;
      float sum = e;
#pragma unroll
      for (int off = 8; off >= 1; off >>= 1) sum += __shfl_xor(sum, off, 16);
      float a = e / sum;
      if (lane < 16) sA[lane] = a;
      if (lane < 14) {
        float c = (lane < 7) ? sA[lane] : 0.f;
        for (int jj = 0; jj < i; ++jj) c += sA[7 + jj] * sC[jj][lane];
        if (lane == 7 + i) c += 1.f;
        sC[i][lane] = c;
      }
    }
  }
  __syncthreads();

  {
    const int d0 = tid * 4;
    float acc[7][4];
#pragma unroll
    for (int i = 0; i < 7; ++i)
#pragma unroll
      for (int e = 0; e < 4; ++e) acc[i][e] = 0.f;
#pragma unroll
    for (int t = 0; t < 7; ++t) {
      us4 h = *(const us4*)&Ehs[t * 1032 + d0];
      us4 l = *(const us4*)&Els[t * 1032 + d0];
      float ev[4];
#pragma unroll
      for (int e = 0; e < 4; ++e) ev[e] = b2f(h[e]) + b2f(l[e]);
#pragma unroll
      for (int i = 0; i < 7; ++i) {
        float c = sC[i][t];
#pragma unroll
        for (int e = 0; e < 4; ++e) acc[i][e] += c * ev[e];
      }
    }
#pragma unroll
    for (int m = 0; m < 7; ++m) {
      us4 qv = *(const us4*)&Qs[m * 1032 + d0];
      float qf[4];
#pragma unroll
      for (int e = 0; e < 4; ++e) qf[e] = b2f(qv[e]);
#pragma unroll
      for (int i = m; i < 7; ++i) {
        float c = sC[i][7 + m];
#pragma unroll
        for (int e = 0; e < 4; ++e) acc[i][e] += c * qf[e];
      }
    }
    unsigned short* Ab = att + (size_t)b * 7168;
#pragma unroll
    for (int i = 0; i < 7; ++i) {
      us4 r;
#pragma unroll
      for (int e = 0; e < 4; ++e) r[e] = f2b(acc[i][e]);
      *(us4*)(Ab + i * 1024 + d0) = r;
    }
  }
}

// ---------------------------------------------------------------------------
// up_t = softsign(att @ emb_w + emb_b), 256x256 8-phase core. K=1024 (16 tiles)
// ---------------------------------------------------------------------------
__global__ __launch_bounds__(512, 2) void gemm_emb256_kernel(
    const unsigned short* __restrict__ A, const unsigned short* __restrict__ Bt,
    const float* __restrict__ bias, unsigned short* __restrict__ up_t) {
  __shared__ unsigned short Ax[2][2][8192];
  __shared__ unsigned short Bx[2][2][8192];
  const int tid = threadIdx.x, lane = tid & 63, wv = tid >> 6;
  const int wm = wv >> 2, wn = wv & 3;
  const int swz = (blockIdx.x & 7) * 56 + (blockIdx.x >> 3);
  const int by = swz >> 2, bx = swz & 3;
  const int m0 = by * 256, n0 = bx * 256;

  f32x4 acc[8][4];
#pragma unroll
  for (int i = 0; i < 8; ++i)
#pragma unroll
    for (int j = 0; j < 4; ++j) acc[i][j] = (f32x4){0.f, 0.f, 0.f, 0.f};

#define ASRC_E(kt, h) (A + (size_t)m0 * 1024 + (kt) * 64 + (h) * 32)
#define BSRC_E(kt, h) (Bt + (size_t)n0 * 1024 + (kt) * 64 + (h) * 32)

  stage_half(ASRC_E(0, 0), 1024, Ax[0][0], tid);
  stage_half(BSRC_E(0, 0), 1024, Bx[0][0], tid);
  stage_half(ASRC_E(0, 1), 1024, Ax[0][1], tid);
  stage_half(BSRC_E(0, 1), 1024, Bx[0][1], tid);
  stage_half(ASRC_E(1, 0), 1024, Ax[1][0], tid);
  stage_half(BSRC_E(1, 0), 1024, Bx[1][0], tid);

  const int NITER = 8;   // 16 K-tiles
  for (int it = 0; it < NITER; ++it) {
    const bool last = (it == NITER - 1);
    const int t1 = 2 * it + 1, t2 = 2 * it + 2, t3 = 2 * it + 3;
    bf16x8 bfr[4];
    gate8(); PH_TOP();
    stage_half(ASRC_E(t1, 1), 1024, Ax[1][1], tid);
    phase_mfma<0, true>(Ax[0][0], Bx[0][0], wm, wn, lane, bfr, acc);
    PH_TOP();
    stage_half(BSRC_E(t1, 1), 1024, Bx[1][1], tid);
    phase_mfma<1, false>(Ax[0][0], Bx[0][0], wm, wn, lane, bfr, acc);
    gate8(); PH_TOP();
    if (!last) stage_half(ASRC_E(t2, 0), 1024, Ax[0][0], tid);
    phase_mfma<0, true>(Ax[0][1], Bx[0][1], wm, wn, lane, bfr, acc);
    PH_TOP();
    if (!last) stage_half(BSRC_E(t2, 0), 1024, Bx[0][0], tid);
    phase_mfma<1, false>(Ax[0][1], Bx[0][1], wm, wn, lane, bfr, acc);
    if (last) gate4(); else gate8();
    PH_TOP();
    if (!last) stage_half(ASRC_E(t2, 1), 1024, Ax[0][1], tid);
    phase_mfma<0, true>(Ax[1][0], Bx[1][0], wm, wn, lane, bfr, acc);
    PH_TOP();
    if (!last) stage_half(BSRC_E(t2, 1), 1024, Bx[0][1], tid);
    phase_mfma<1, false>(Ax[1][0], Bx[1][0], wm, wn, lane, bfr, acc);
    if (last) gate0(); else gate8();
    PH_TOP();
    if (!last) stage_half(ASRC_E(t3, 0), 1024, Ax[1][0], tid);
    phase_mfma<0, true>(Ax[1][1], Bx[1][1], wm, wn, lane, bfr, acc);
    PH_TOP();
    if (!last) stage_half(BSRC_E(t3, 0), 1024, Bx[1][0], tid);
    phase_mfma<1, false>(Ax[1][1], Bx[1][1], wm, wn, lane, bfr, acc);
  }
#undef ASRC_E
#undef BSRC_E

#pragma unroll
  for (int ni = 0; ni < 4; ++ni) {
    int np = n0 + wn * 64 + ni * 16 + (lane & 15);
    int o = (np & 63) * 16 + (np >> 6);
    float bv = bias[o];
#pragma unroll
    for (int mi = 0; mi < 8; ++mi)
#pragma unroll
      for (int r = 0; r < 4; ++r) {
        int m = m0 + wm * 128 + mi * 16 + (lane >> 4) * 4 + r;
        float v = acc[mi][ni][r] + bv;
        v = v / (1.f + fabsf(v));
        up_t[(size_t)m * 1024 + np] = f2b(v);
      }
  }
}

// ---------------------------------------------------------------------------
// dc3
// ---------------------------------------------------------------------------
__global__ __launch_bounds__(256) void dc3_kernel(const unsigned short* __restrict__ up_t,
                                                  const float* __restrict__ w3,
                                                  const float* __restrict__ b3,
                                                  unsigned short* __restrict__ y1_t) {
  const int lane = threadIdx.x & 63, wv = threadIdx.x >> 6;
  const int kq = (lane >> 4) * 8;
  const int oc = lane & 15;
  bf16x8 bf[2][6];
#pragma unroll
  for (int nt = 0; nt < 2; ++nt)
#pragma unroll
    for (int kk = 0; kk < 6; ++kk) {
      bf16x8 v;
#pragma unroll
      for (int t = 0; t < 8; ++t) {
        int k = kk * 32 + kq + t;
        int jj = k >> 6, ic = k & 63;
        v[t] = (short)f2b(w3[((size_t)ic * 32 + nt * 16 + oc) * 3 + jj]);
      }
      bf[nt][kk] = v;
    }
  const float bia0 = b3[oc], bia1 = b3[16 + oc];
  const int base_chunk = blockIdx.x * 32 + wv * 8;
  for (int cc = 0; cc < 8; ++cc) {
    const int chunk = base_chunk + cc;
    int m = chunk * 16 + (lane & 15);
    int img = m / 18, ow = m - img * 18;
    const unsigned short* arow = up_t + (size_t)img * 1024;
    f32x4 acc0 = {0.f, 0.f, 0.f, 0.f}, acc1 = {0.f, 0.f, 0.f, 0.f};
#pragma unroll
    for (int kk = 0; kk < 6; ++kk) {
      int jj = kk >> 1;
      int ic0 = (kk & 1) * 32 + kq;
      int iw = ow - jj;
      bf16x8 a = {0, 0, 0, 0, 0, 0, 0, 0};
      if ((unsigned)iw < 16u) a = *(const bf16x8*)(arow + iw * 64 + ic0);
      acc0 = __builtin_amdgcn_mfma_f32_16x16x32_bf16(a, bf[0][kk], acc0, 0, 0, 0);
      acc1 = __builtin_amdgcn_mfma_f32_16x16x32_bf16(a, bf[1][kk], acc1, 0, 0, 0);
    }
#pragma unroll
    for (int r = 0; r < 4; ++r) {
      int mm = chunk * 16 + (lane >> 4) * 4 + r;
      float v0 = acc0[r] + bia0; v0 = v0 > 0.f ? v0 : 0.01f * v0;
      float v1 = acc1[r] + bia1; v1 = v1 > 0.f ? v1 : 0.01f * v1;
      y1_t[(size_t)mm * 32 + oc] = f2b(v0);
      y1_t[(size_t)mm * 32 + 16 + oc] = f2b(v1);
    }
  }
}

// ---------------------------------------------------------------------------
// dc1
// ---------------------------------------------------------------------------
__global__ __launch_bounds__(256) void dc1_kernel(const unsigned short* __restrict__ y1_t,
                                                  const float* __restrict__ w1,
                                                  const float* __restrict__ b1,
                                                  unsigned short* __restrict__ y2_t) {
  const int lane = threadIdx.x & 63, wv = threadIdx.x >> 6;
  const int kq = (lane >> 4) * 8;
  const int oc = lane & 15;
  bf16x8 bf[5];
#pragma unroll
  for (int kk = 0; kk < 5; ++kk) {
    bf16x8 v;
#pragma unroll
    for (int t = 0; t < 8; ++t) {
      int ic = kq + t;
      v[t] = (short)f2b(w1[((size_t)ic * 16 + oc) * 5 + kk]);
    }
    bf[kk] = v;
  }
  const float bia = b1[oc];
  const int base_chunk = blockIdx.x * 32 + wv * 8;
  for (int cc = 0; cc < 8; ++cc) {
    const int chunk = base_chunk + cc;
    int m = chunk * 16 + (lane & 15);
    int img = m / 22, ow = m - img * 22;
    const unsigned short* abase = y1_t + (size_t)img * 18 * 32;
    f32x4 acc = {0.f, 0.f, 0.f, 0.f};
#pragma unroll
    for (int kk = 0; kk < 5; ++kk) {
      int iw = ow - kk;
      bf16x8 a = {0, 0, 0, 0, 0, 0, 0, 0};
      if ((unsigned)iw < 18u) a = *(const bf16x8*)(abase + iw * 32 + kq);
      acc = __builtin_amdgcn_mfma_f32_16x16x32_bf16(a, bf[kk], acc, 0, 0, 0);
    }
#pragma unroll
    for (int r = 0; r < 4; ++r) {
      int mm = chunk * 16 + (lane >> 4) * 4 + r;
      float v = acc[r] + bia;
      v = v > 0.f ? v : 0.01f * v;
      y2_t[(size_t)mm * 16 + oc] = f2b(v);
    }
  }
}

// ---------------------------------------------------------------------------
// dc2 + softmax over oh
// ---------------------------------------------------------------------------
__global__ __launch_bounds__(256) void dc2_kernel(const unsigned short* __restrict__ y2_t,
                                                  const float* __restrict__ w2,
                                                  const float* __restrict__ b2,
                                                  float* __restrict__ out) {
  int idx = blockIdx.x * 256 + threadIdx.x;
  int img = idx / 24, ow = idx - img * 24;
  float lg0 = b2[0], lg1 = b2[0], lg2 = b2[0];
#pragma unroll
  for (int jj = 0; jj < 3; ++jj) {
    int iw = ow - jj;
    if ((unsigned)iw >= 22u) continue;
    const unsigned short* row = y2_t + ((size_t)img * 22 + iw) * 16;
    bf16x8 v0 = *(const bf16x8*)(row);
    bf16x8 v1 = *(const bf16x8*)(row + 8);
    float x[16];
#pragma unroll
    for (int ic = 0; ic < 8; ++ic) {
      x[ic] = b2f((unsigned short)v0[ic]);
      x[8 + ic] = b2f((unsigned short)v1[ic]);
    }
#pragma unroll
    for (int ic = 0; ic < 16; ++ic) {
      lg0 += x[ic] * w2[ic * 9 + 0 * 3 + jj];
      lg1 += x[ic] * w2[ic * 9 + 1 * 3 + jj];
      lg2 += x[ic] * w2[ic * 9 + 2 * 3 + jj];
    }
  }
  lg0 = lg0 > 0.f ? lg0 : 0.01f * lg0;
  lg1 = lg1 > 0.f ? lg1 : 0.01f * lg1;
  lg2 = lg2 > 0.f ? lg2 : 0.01f * lg2;
  float mx = fmaxf(lg0, fmaxf(lg1, lg2));
  float e0 = __expf(lg0 - mx), e1 = __expf(lg1 - mx), e2 = __expf(lg2 - mx);
  float inv = 1.f / (e0 + e1 + e2);
  size_t ob = (size_t)img * 72 + ow;
  out[ob] = e0 * inv;
  out[ob + 24] = e1 * inv;
  out[ob + 48] = e2 * inv;
}

// ---------------------------------------------------------------------------
extern "C" void kernel_launch(void* const* d_in, const int* in_sizes, int n_in,
                              void* d_out, int out_size, void* d_ws, size_t ws_size,
                              hipStream_t stream) {
  (void)in_sizes; (void)n_in; (void)out_size; (void)ws_size;
  const float* enc    = (const float*)d_in[0];
  const float* noise  = (const float*)d_in[1];
  const float* erep_w = (const float*)d_in[2];
  const float* erep_b = (const float*)d_in[3];
  const float* wih_f  = (const float*)d_in[4];
  const float* whh_f  = (const float*)d_in[5];
  const float* bih_f  = (const float*)d_in[6];
  const float* bhh_f  = (const float*)d_in[7];
  const float* wih_b  = (const float*)d_in[8];
  const float* whh_b  = (const float*)d_in[9];
  const float* bih_b  = (const float*)d_in[10];
  const float* bhh_b  = (const float*)d_in[11];
  const float* emb_w  = (const float*)d_in[12];
  const float* emb_b  = (const float*)d_in[13];
  const float* dc3w   = (const float*)d_in[14];
  const float* dc3b   = (const float*)d_in[15];
  const float* dc1w   = (const float*)d_in[16];
  const float* dc1b   = (const float*)d_in[17];
  const float* dc2w   = (const float*)d_in[18];
  const float* dc2b   = (const float*)d_in[19];
  float* out = (float*)d_out;

  char* p = (char*)d_ws;
  auto carve = [&p](size_t bytes) {
    char* r = p;
    p += (bytes + 255) & ~(size_t)255;
    return r;
  };
  unsigned short* rep_t  = (unsigned short*)carve(7ull * 4096 * 256 * 2);
  unsigned short* lstmW  = (unsigned short*)carve(2ull * 2048 * 768 * 2);
  float*          lstmB  = (float*)carve(2ull * 2048 * 4);
  unsigned short* noiseb = (unsigned short*)carve(4096ull * 256 * 2);
  unsigned short* erepT  = (unsigned short*)carve(1792ull * 256 * 2);
  unsigned short* embT   = (unsigned short*)carve(1024ull * 1024 * 2);
  unsigned short* hbuf   = (unsigned short*)carve(4ull * 4096 * 512 * 2);   // [pp][dir]
  float*          cbuf   = (float*)carve(2ull * 4096 * 512 * 4);            // [dir]
  unsigned short* lstm1  = (unsigned short*)carve(4096ull * 7 * 1024 * 2);
  unsigned short* att    = (unsigned short*)carve(28672ull * 1024 * 2);
  unsigned short* up_t   = (unsigned short*)carve(28672ull * 1024 * 2);
  unsigned short* y1_t   = (unsigned short*)carve(28672ull * 18 * 32 * 2);
  unsigned short* y2_t   = (unsigned short*)carve(28672ull * 22 * 16 * 2);

  hipMemsetAsync(hbuf, 0, 2ull * 4096 * 512 * 2, stream);
  hipMemsetAsync(cbuf, 0, 2ull * 4096 * 512 * 4, stream);

  pack_kernel<<<2048, 256, 0, stream>>>(noise, erep_w, emb_w, wih_f, whh_f, bih_f, bhh_f,
                                        wih_b, whh_b, bih_b, bhh_b,
                                        noiseb, erepT, embT, lstmW, lstmB);
  gemm_rep_kernel<<<dim3(14, 32), 256, 0, stream>>>(noiseb, erepT, erep_b, rep_t);
  for (int s = 0; s < 7; ++s)
    lstm_step256_kernel<<<256, 512, 0, stream>>>(rep_t, lstmW, lstmB, hbuf, cbuf, lstm1, s);
  att_fused2_kernel<<<4096, 256, 0, stream>>>(enc, lstm1, att);
  gemm_emb256_kernel<<<448, 512, 0, stream>>>(att, embT, emb_b, up_t);
  dc3_kernel<<<1008, 256, 0, stream>>>(up_t, dc3w, dc3b, y1_t);
  dc1_kernel<<<1232, 256, 0, stream>>>(y1_t, dc1w, dc1b, y2_t);
  dc2_kernel<<<2688, 256, 0, stream>>>(y2_t, dc2w, dc2b, out);
}

// Round 7
// 510.028 us; speedup vs baseline: 1.3782x; 1.0046x over previous
//
#include <hip/hip_runtime.h>
#include <stdint.h>

// ---------------------------------------------------------------------------
// decoder_80487687127254 : B=4096 T=7 H=512 L=256 D=1024
// ---------------------------------------------------------------------------

typedef __attribute__((ext_vector_type(4))) float f32x4;
typedef __attribute__((ext_vector_type(8))) short bf16x8;
typedef __attribute__((ext_vector_type(4))) unsigned short us4;

__device__ __forceinline__ unsigned short f2b(float f) {
  union { float f; unsigned u; } x; x.f = f;
  unsigned r = x.u + 0x7FFFu + ((x.u >> 16) & 1u);   // RNE
  return (unsigned short)(r >> 16);
}
__device__ __forceinline__ float b2f(unsigned short s) {
  union { unsigned u; float f; } x; x.u = ((unsigned)s) << 16; return x.f;
}
__device__ __forceinline__ float sigmoidf(float x) {
  return 1.f / (1.f + __expf(-x));
}
__device__ __forceinline__ float fast_tanh(float x) {
  x = fminf(15.f, fmaxf(-15.f, x));
  float e = __expf(2.f * x);
  return (e - 1.f) / (e + 1.f);
}

// async global->LDS, 16B per lane; LDS dest must be wave-uniform (HW adds lane*16)
__device__ __forceinline__ void gl_lds16(const void* g, void* l) {
  auto gp = reinterpret_cast<const __attribute__((address_space(1))) unsigned int*>(
      reinterpret_cast<uintptr_t>(g));
  auto lp = reinterpret_cast<__attribute__((address_space(3))) unsigned int*>(
      reinterpret_cast<uintptr_t>(l));
  __builtin_amdgcn_global_load_lds(gp, lp, 16, 0, 0);
}

// ===========================================================================
// 256x256 8-wave GEMM core, BK=32, 4-deep LDS ring, 1 barrier / K-tile.
// Tile buffer = [256 rows][32 cols] bf16 (16 KB), granule-swizzled:
//   dest granule gd at (row) holds source granule gd ^ ((row>>1)&3)
//   -> frag reads are 2-way bank aliased (free, m136).
// While computing tile t (slot t&3), stage tile t+3 (slot (t-1)&3, whose
// readers finished before t's entry barrier).  Entry gate vmcnt(8) = the
// 8 loads of tiles t+1,t+2 remain in flight; barrier makes t's LDS valid
// for all waves.  Per tile: 12 ds_read_b128 issued early, two MFMA
// clusters of 16 gated by lgkmcnt(4)/lgkmcnt(0), stages interleaved.
// ===========================================================================

// stage one 256x32 tile: 2 gl_lds per thread, dest linear, source granule
// pre-inverse-swizzled.  src points at (row0, col0).
__device__ __forceinline__ void stage_half(const unsigned short* src, int ld,
                                           unsigned short* hbase, int tid) {
  const int row_in = tid >> 2;   // 0..127
  const int gidx = tid & 3;      // dest granule position
#pragma unroll
  for (int r = 0; r < 2; ++r) {
    int row = r * 128 + row_in;
    int gsrc = gidx ^ ((row >> 1) & 3);
    gl_lds16(src + (size_t)row * ld + gsrc * 8, hbase + r * 4096 + (tid >> 6) * 512);
  }
}

__device__ __forceinline__ bf16x8 lds_fragH(const unsigned short* hbase, int row, int lq) {
  return *(const bf16x8*)(hbase + row * 32 + (lq ^ (((row >> 1) & 3) << 3)));
}

template <int N>
__device__ __forceinline__ void gate() {
  if constexpr (N == 8) asm volatile("s_waitcnt vmcnt(8)" ::: "memory");
  else if constexpr (N == 4) asm volatile("s_waitcnt vmcnt(4)" ::: "memory");
  else asm volatile("s_waitcnt vmcnt(0)" ::: "memory");
}

#define TILE_TOP(N)                     \
  gate<N>();                            \
  __builtin_amdgcn_s_barrier();         \
  __builtin_amdgcn_sched_barrier(0)

// one K-tile (BK=32): 12 ds_reads early, 2x16 MFMA, stages interleaved.
template <class FA, class FB>
__device__ __forceinline__ void tile32(const unsigned short* Ab, const unsigned short* Bb,
                                       int wm, int wn, int lane, f32x4 (&acc)[8][4],
                                       FA stageA, FB stageB) {
  const int lr = lane & 15, lq = (lane >> 4) * 8;
  bf16x8 a[8], b[4];
#pragma unroll
  for (int i = 0; i < 4; ++i) a[i] = lds_fragH(Ab, wm * 128 + i * 16 + lr, lq);
#pragma unroll
  for (int n = 0; n < 4; ++n) b[n] = lds_fragH(Bb, wn * 64 + n * 16 + lr, lq);
  __builtin_amdgcn_sched_barrier(0);   // pin: first 8 lgkm ops are the above
#pragma unroll
  for (int i = 4; i < 8; ++i) a[i] = lds_fragH(Ab, wm * 128 + i * 16 + lr, lq);
  stageA();
  asm volatile("s_waitcnt lgkmcnt(4)" ::: "memory");   // a0-3, b0-3 landed
  __builtin_amdgcn_sched_barrier(0);
  __builtin_amdgcn_s_setprio(1);
#pragma unroll
  for (int i = 0; i < 4; ++i)
#pragma unroll
    for (int n = 0; n < 4; ++n)
      acc[i][n] = __builtin_amdgcn_mfma_f32_16x16x32_bf16(a[i], b[n], acc[i][n], 0, 0, 0);
  __builtin_amdgcn_s_setprio(0);
  stageB();
  asm volatile("s_waitcnt lgkmcnt(0)" ::: "memory");   // a4-7 landed
  __builtin_amdgcn_sched_barrier(0);
  __builtin_amdgcn_s_setprio(1);
#pragma unroll
  for (int i = 4; i < 8; ++i)
#pragma unroll
    for (int n = 0; n < 4; ++n)
      acc[i][n] = __builtin_amdgcn_mfma_f32_16x16x32_bf16(a[i], b[n], acc[i][n], 0, 0, 0);
  __builtin_amdgcn_s_setprio(0);
}

// ---------------------------------------------------------------------------
// 128x128 core (kept for gemm_rep)
// ---------------------------------------------------------------------------
__device__ __forceinline__ void stage128x64(const unsigned short* src, int ld,
                                            unsigned short* lds, int wv, int lane) {
#pragma unroll
  for (int r = 0; r < 4; ++r) {
    int row = r * 32 + wv * 8 + (lane >> 3);
    gl_lds16(src + (size_t)row * ld + (lane & 7) * 8, lds + (r * 32 + wv * 8) * 64);
  }
}
__device__ __forceinline__ void mfma_tile(const unsigned short* As, const unsigned short* Bs,
                                          int wm, int wn, int lane, f32x4 acc[4][4]) {
#pragma unroll
  for (int kk = 0; kk < 2; ++kk) {
    int ko = kk * 32 + (lane >> 4) * 8;
    bf16x8 a[4], b[4];
#pragma unroll
    for (int i = 0; i < 4; ++i)
      a[i] = *(const bf16x8*)(As + (size_t)(wm * 64 + i * 16 + (lane & 15)) * 64 + ko);
#pragma unroll
    for (int i = 0; i < 4; ++i)
      b[i] = *(const bf16x8*)(Bs + (size_t)(wn * 64 + i * 16 + (lane & 15)) * 64 + ko);
#pragma unroll
    for (int mi = 0; mi < 4; ++mi)
#pragma unroll
      for (int ni = 0; ni < 4; ++ni)
        acc[mi][ni] = __builtin_amdgcn_mfma_f32_16x16x32_bf16(a[mi], b[ni], acc[mi][ni], 0, 0, 0);
  }
}

// ---------------------------------------------------------------------------
// pack
// ---------------------------------------------------------------------------
__global__ __launch_bounds__(256) void pack_kernel(
    const float* __restrict__ noise, const float* __restrict__ erep_w,
    const float* __restrict__ emb_w,
    const float* __restrict__ wih_f, const float* __restrict__ whh_f,
    const float* __restrict__ bih_f, const float* __restrict__ bhh_f,
    const float* __restrict__ wih_b, const float* __restrict__ whh_b,
    const float* __restrict__ bih_b, const float* __restrict__ bhh_b,
    unsigned short* __restrict__ noiseb, unsigned short* __restrict__ erepT,
    unsigned short* __restrict__ embT, unsigned short* __restrict__ lstmW,
    float* __restrict__ lstmB) {
  const int N0 = 4096 * 256;
  const int N1 = 1792 * 256;
  const int N2 = 1024 * 1024;
  const int N3 = 2 * 2048 * 768;
  const int N4 = 2 * 2048;
  const int total = N0 + N1 + N2 + N3 + N4;
  for (int i = blockIdx.x * 256 + threadIdx.x; i < total; i += gridDim.x * 256) {
    int x = i;
    if (x < N0) { noiseb[x] = f2b(noise[x]); continue; }
    x -= N0;
    if (x < N1) { int n = x >> 8, k = x & 255; erepT[x] = f2b(erep_w[k * 1792 + n]); continue; }
    x -= N1;
    if (x < N2) {
      int n = x >> 10, k = x & 1023;
      int o = (n & 63) * 16 + (n >> 6);
      embT[x] = f2b(emb_w[k * 1024 + o]);
      continue;
    }
    x -= N2;
    if (x < N3) {
      int dir = x / (2048 * 768);
      int r = x - dir * (2048 * 768);
      int npk = r / 768, k = r - (r / 768) * 768;
      int blk = npk >> 6, g = (npk >> 4) & 3, u = npk & 15;
      int o = g * 512 + blk * 16 + u;
      const float* wih = dir ? wih_b : wih_f;
      const float* whh = dir ? whh_b : whh_f;
      float v = (k < 256) ? wih[k * 2048 + o] : whh[(k - 256) * 2048 + o];
      lstmW[x] = f2b(v);
      continue;
    }
    x -= N3;
    {
      int dir = x >> 11, npk = x & 2047;
      int blk = npk >> 6, g = (npk >> 4) & 3, u = npk & 15;
      int o = g * 512 + blk * 16 + u;
      lstmB[x] = dir ? (bih_b[o] + bhh_b[o]) : (bih_f[o] + bhh_f[o]);
    }
  }
}

// ---------------------------------------------------------------------------
// rep = softsign(noise @ erep_w + b)
// ---------------------------------------------------------------------------
__global__ __launch_bounds__(256) void gemm_rep_kernel(
    const unsigned short* __restrict__ A, const unsigned short* __restrict__ Bt,
    const float* __restrict__ bias, unsigned short* __restrict__ rep_t) {
  __shared__ unsigned short As[128 * 64];
  __shared__ unsigned short Bs[128 * 64];
  const int lane = threadIdx.x & 63, wv = threadIdx.x >> 6;
  const int wm = wv >> 1, wn = wv & 1;
  const int m0 = blockIdx.y * 128, n0 = blockIdx.x * 128;
  f32x4 acc[4][4];
#pragma unroll
  for (int i = 0; i < 4; ++i)
#pragma unroll
    for (int j = 0; j < 4; ++j) acc[i][j] = (f32x4){0.f, 0.f, 0.f, 0.f};
  for (int k0 = 0; k0 < 256; k0 += 64) {
    stage128x64(A + (size_t)m0 * 256 + k0, 256, As, wv, lane);
    stage128x64(Bt + (size_t)n0 * 256 + k0, 256, Bs, wv, lane);
    __syncthreads();
    mfma_tile(As, Bs, wm, wn, lane, acc);
    __syncthreads();
  }
#pragma unroll
  for (int ni = 0; ni < 4; ++ni) {
    int n = n0 + wn * 64 + ni * 16 + (lane & 15);
    float bv = bias[n];
    int t = n >> 8, l = n & 255;
#pragma unroll
    for (int mi = 0; mi < 4; ++mi)
#pragma unroll
      for (int r = 0; r < 4; ++r) {
        int m = m0 + wm * 64 + mi * 16 + (lane >> 4) * 4 + r;
        float v = acc[mi][ni][r] + bv;
        v = v / (1.f + fabsf(v));
        rep_t[((size_t)t * 4096 + m) * 256 + l] = f2b(v);
      }
  }
}

// ---------------------------------------------------------------------------
// LSTM step, 256x256 ring core. K=768 -> 24 BK=32 tiles (8 x-tiles, 16 h-tiles)
// ---------------------------------------------------------------------------
__global__ __launch_bounds__(512, 2) void lstm_step256_kernel(
    const unsigned short* __restrict__ rep_t, const unsigned short* __restrict__ Wp,
    const float* __restrict__ biasP, unsigned short* __restrict__ hbuf,
    float* __restrict__ cbuf, unsigned short* __restrict__ lstm1, int step) {
  __shared__ unsigned short Ar[4][8192];
  __shared__ unsigned short Br[4][8192];
  const int tid = threadIdx.x, lane = tid & 63, wv = tid >> 6;
  const int wm = wv >> 2, wn = wv & 3;
  const int swz = (blockIdx.x & 7) * 32 + (blockIdx.x >> 3);
  const int dir = swz >> 7;
  const int by = (swz & 127) >> 3, bx = swz & 7;
  const int m0 = by * 256, n0 = bx * 256;
  const int t_proc = dir ? (6 - step) : step;
  const unsigned short* W = Wp + (size_t)dir * 2048 * 768;
  const unsigned short* hin = hbuf + ((size_t)(step & 1) * 2 + dir) * (4096 * 512);
  unsigned short* hout = hbuf + ((size_t)((step + 1) & 1) * 2 + dir) * (4096 * 512);
  float* cp = cbuf + (size_t)dir * (4096 * 512);
  const unsigned short* xsrc = rep_t + (size_t)t_proc * 4096 * 256;

  f32x4 acc[8][4];
#pragma unroll
  for (int i = 0; i < 8; ++i)
#pragma unroll
    for (int j = 0; j < 4; ++j) acc[i][j] = (f32x4){0.f, 0.f, 0.f, 0.f};

  auto asrc = [&](int tt) {
    return tt < 8 ? xsrc + (size_t)m0 * 256 + tt * 32
                  : hin + (size_t)m0 * 512 + (tt - 8) * 32;
  };
  auto ald = [&](int tt) { return tt < 8 ? 256 : 512; };

  // prologue: tiles 0,1,2 (A,B interleaved, oldest first)
  stage_half(asrc(0), ald(0), Ar[0], tid);
  stage_half(W + (size_t)n0 * 768 + 0 * 32, 768, Br[0], tid);
  stage_half(asrc(1), ald(1), Ar[1], tid);
  stage_half(W + (size_t)n0 * 768 + 1 * 32, 768, Br[1], tid);
  stage_half(asrc(2), ald(2), Ar[2], tid);
  stage_half(W + (size_t)n0 * 768 + 2 * 32, 768, Br[2], tid);

  for (int t = 0; t <= 20; ++t) {   // NT=24, stage while t+3 <= 23
    TILE_TOP(8);
    const int tt = t + 3;
    tile32(Ar[t & 3], Br[t & 3], wm, wn, lane, acc,
           [&] { stage_half(asrc(tt), ald(tt), Ar[tt & 3], tid); },
           [&] { stage_half(W + (size_t)n0 * 768 + tt * 32, 768, Br[tt & 3], tid); });
  }
  TILE_TOP(8);
  tile32(Ar[21 & 3], Br[21 & 3], wm, wn, lane, acc, [&] {}, [&] {});
  TILE_TOP(4);
  tile32(Ar[22 & 3], Br[22 & 3], wm, wn, lane, acc, [&] {}, [&] {});
  TILE_TOP(0);
  tile32(Ar[23 & 3], Br[23 & 3], wm, wn, lane, acc, [&] {}, [&] {});

  const int u = lane & 15;
  const int blk = (n0 + wn * 64) >> 6;
  const int j = blk * 16 + u;
  const float bz0 = biasP[dir * 2048 + blk * 64 + 0 * 16 + u];
  const float bz1 = biasP[dir * 2048 + blk * 64 + 1 * 16 + u];
  const float bz2 = biasP[dir * 2048 + blk * 64 + 2 * 16 + u];
  const float bz3 = biasP[dir * 2048 + blk * 64 + 3 * 16 + u];
#pragma unroll
  for (int mi = 0; mi < 8; ++mi)
#pragma unroll
    for (int r = 0; r < 4; ++r) {
      int row = m0 + wm * 128 + mi * 16 + (lane >> 4) * 4 + r;
      float gi = acc[mi][0][r] + bz0;
      float gf = acc[mi][1][r] + bz1;
      float gg = acc[mi][2][r] + bz2;
      float go = acc[mi][3][r] + bz3;
      size_t ci = (size_t)row * 512 + j;
      float c = sigmoidf(gf) * cp[ci] + sigmoidf(gi) * fast_tanh(gg);
      cp[ci] = c;
      float h = sigmoidf(go) * fast_tanh(c);
      unsigned short hb = f2b(h);
      hout[ci] = hb;
      lstm1[((size_t)row * 7 + t_proc) * 1024 + dir * 512 + j] = hb;
    }
}

// ---------------------------------------------------------------------------
// Fused attention, MFMA Gram (unchanged)
// ---------------------------------------------------------------------------
__global__ __launch_bounds__(256) void att_fused2_kernel(
    const float* __restrict__ enc, const unsigned short* __restrict__ lstm1,
    unsigned short* __restrict__ att) {
  __shared__ unsigned short Qs[7 * 1032];
  __shared__ unsigned short Ehs[7 * 1032];
  __shared__ unsigned short Els[7 * 1032];
  __shared__ float P[4 * 2 * 64 * 4];
  __shared__ float sG[98];
  __shared__ float sC[7][14];
  __shared__ float sA[16];
  const int tid = threadIdx.x, lane = tid & 63, wv = tid >> 6;
  const int b = blockIdx.x;
  const float* Eb = enc + (size_t)b * 7168;
  const unsigned short* Qb = lstm1 + (size_t)b * 7168;

  if (tid < 98) ((float*)sC)[tid] = 0.f;

  const f32x4* Eb4 = (const f32x4*)Eb;
#pragma unroll
  for (int r = 0; r < 7; ++r) {
    f32x4 v = Eb4[r * 256 + tid];
    us4 hi, lo;
#pragma unroll
    for (int e = 0; e < 4; ++e) {
      hi[e] = f2b(v[e]);
      lo[e] = f2b(v[e] - b2f(hi[e]));
    }
    *(us4*)&Ehs[r * 1032 + tid * 4] = hi;
    *(us4*)&Els[r * 1032 + tid * 4] = lo;
  }
  const bf16x8* Qb8 = (const bf16x8*)Qb;
#pragma unroll
  for (int r = 0; r < 4; ++r) {
    int idx = r * 256 + tid;
    if (idx < 896) {
      int row = idx >> 7, col = (idx & 127) * 8;
      *(bf16x8*)&Qs[row * 1032 + col] = Qb8[idx];
    }
  }
  __syncthreads();

  {
    const int rr = lane & 15;
    const int rowc = rr > 6 ? 6 : rr;
    const int kbase = wv * 256 + (lane >> 4) * 8;
    f32x4 g1 = {0.f, 0.f, 0.f, 0.f}, g2 = {0.f, 0.f, 0.f, 0.f};
#pragma unroll
    for (int s = 0; s < 8; ++s) {
      const int k0 = kbase + s * 32;
      bf16x8 aq = *(const bf16x8*)&Qs[rowc * 1032 + k0];
      bf16x8 bh = *(const bf16x8*)&Ehs[rowc * 1032 + k0];
      bf16x8 bl = *(const bf16x8*)&Els[rowc * 1032 + k0];
      g1 = __builtin_amdgcn_mfma_f32_16x16x32_bf16(aq, bh, g1, 0, 0, 0);
      g1 = __builtin_amdgcn_mfma_f32_16x16x32_bf16(aq, bl, g1, 0, 0, 0);
      g2 = __builtin_amdgcn_mfma_f32_16x16x32_bf16(aq, aq, g2, 0, 0, 0);
    }
    *(f32x4*)&P[((wv * 2 + 0) * 64 + lane) * 4] = g1;
    *(f32x4*)&P[((wv * 2 + 1) * 64 + lane) * 4] = g2;
  }
  __syncthreads();

  if (tid < 98) {
    int i = tid / 14, v = tid - i * 14;
    int col = v < 7 ? v : v - 7;
    int tile = v < 7 ? 0 : 1;
    int ln = ((i >> 2) << 4) | col;
    int rg = i & 3;
    float s = 0.f;
#pragma unroll
    for (int w = 0; w < 4; ++w) s += P[((w * 2 + tile) * 64 + ln) * 4 + rg];
    sG[i * 14 + v] = s;
  }
  __syncthreads();

  if (wv == 0) {
    for (int i = 0; i < 7; ++i) {
      const int nt = 7 + i;
      float s = -1e30f;
      if (lane < 7) {
        s = sG[i * 14 + lane];
      } else if (lane < nt) {
        int jj = lane - 7;
        float a2 = 0.f;
#pragma unroll
        for (int v = 0; v < 14; ++v) a2 += sC[jj][v] * sG[i * 14 + v];
        s = a2;
      }
      float mx = s;
#pragma unroll
      for (int off = 8; off >= 1; off >>= 1) mx = fmaxf(mx, __shfl_xor(mx, off, 16));
      float e = (lane < nt) ? __expf(s - mx) : 0.f;
      float sum = e;
#pragma unroll
      for (int off = 8; off >= 1; off >>= 1) sum += __shfl_xor(sum, off, 16);
      float a = e / sum;
      if (lane < 16) sA[lane] = a;
      if (lane < 14) {
        float c = (lane < 7) ? sA[lane] : 0.f;
        for (int jj = 0; jj < i; ++jj) c += sA[7 + jj] * sC[jj][lane];
        if (lane == 7 + i) c += 1.f;
        sC[i][lane] = c;
      }
    }
  }
  __syncthreads();

  {
    const int d0 = tid * 4;
    float acc[7][4];
#pragma unroll
    for (int i = 0; i < 7; ++i)
#pragma unroll
      for (int e = 0; e < 4; ++e) acc[i][e] = 0.f;
#pragma unroll
    for (int t = 0; t < 7; ++t) {
      us4 h = *(const us4*)&Ehs[t * 1032 + d0];
      us4 l = *(const us4*)&Els[t * 1032 + d0];
      float ev[4];
#pragma unroll
      for (int e = 0; e < 4; ++e) ev[e] = b2f(h[e]) + b2f(l[e]);
#pragma unroll
      for (int i = 0; i < 7; ++i) {
        float c = sC[i][t];
#pragma unroll
        for (int e = 0; e < 4; ++e) acc[i][e] += c * ev[e];
      }
    }
#pragma unroll
    for (int m = 0; m < 7; ++m) {
      us4 qv = *(const us4*)&Qs[m * 1032 + d0];
      float qf[4];
#pragma unroll
      for (int e = 0; e < 4; ++e) qf[e] = b2f(qv[e]);
#pragma unroll
      for (int i = m; i < 7; ++i) {
        float c = sC[i][7 + m];
#pragma unroll
        for (int e = 0; e < 4; ++e) acc[i][e] += c * qf[e];
      }
    }
    unsigned short* Ab = att + (size_t)b * 7168;
#pragma unroll
    for (int i = 0; i < 7; ++i) {
      us4 r;
#pragma unroll
      for (int e = 0; e < 4; ++e) r[e] = f2b(acc[i][e]);
      *(us4*)(Ab + i * 1024 + d0) = r;
    }
  }
}

// ---------------------------------------------------------------------------
// up_t = softsign(att @ emb_w + emb_b), 256x256 ring core. K=1024 -> 32 tiles
// ---------------------------------------------------------------------------
__global__ __launch_bounds__(512, 2) void gemm_emb256_kernel(
    const unsigned short* __restrict__ A, const unsigned short* __restrict__ Bt,
    const float* __restrict__ bias, unsigned short* __restrict__ up_t) {
  __shared__ unsigned short Ar[4][8192];
  __shared__ unsigned short Br[4][8192];
  const int tid = threadIdx.x, lane = tid & 63, wv = tid >> 6;
  const int wm = wv >> 2, wn = wv & 3;
  const int swz = (blockIdx.x & 7) * 56 + (blockIdx.x >> 3);
  const int by = swz >> 2, bx = swz & 3;
  const int m0 = by * 256, n0 = bx * 256;

  f32x4 acc[8][4];
#pragma unroll
  for (int i = 0; i < 8; ++i)
#pragma unroll
    for (int j = 0; j < 4; ++j) acc[i][j] = (f32x4){0.f, 0.f, 0.f, 0.f};

  const unsigned short* Abase = A + (size_t)m0 * 1024;
  const unsigned short* Bbase = Bt + (size_t)n0 * 1024;

  stage_half(Abase + 0 * 32, 1024, Ar[0], tid);
  stage_half(Bbase + 0 * 32, 1024, Br[0], tid);
  stage_half(Abase + 1 * 32, 1024, Ar[1], tid);
  stage_half(Bbase + 1 * 32, 1024, Br[1], tid);
  stage_half(Abase + 2 * 32, 1024, Ar[2], tid);
  stage_half(Bbase + 2 * 32, 1024, Br[2], tid);

  for (int t = 0; t <= 28; ++t) {   // NT=32, stage while t+3 <= 31
    TILE_TOP(8);
    const int tt = t + 3;
    tile32(Ar[t & 3], Br[t & 3], wm, wn, lane, acc,
           [&] { stage_half(Abase + tt * 32, 1024, Ar[tt & 3], tid); },
           [&] { stage_half(Bbase + tt * 32, 1024, Br[tt & 3], tid); });
  }
  TILE_TOP(8);
  tile32(Ar[29 & 3], Br[29 & 3], wm, wn, lane, acc, [&] {}, [&] {});
  TILE_TOP(4);
  tile32(Ar[30 & 3], Br[30 & 3], wm, wn, lane, acc, [&] {}, [&] {});
  TILE_TOP(0);
  tile32(Ar[31 & 3], Br[31 & 3], wm, wn, lane, acc, [&] {}, [&] {});

#pragma unroll
  for (int ni = 0; ni < 4; ++ni) {
    int np = n0 + wn * 64 + ni * 16 + (lane & 15);
    int o = (np & 63) * 16 + (np >> 6);
    float bv = bias[o];
#pragma unroll
    for (int mi = 0; mi < 8; ++mi)
#pragma unroll
      for (int r = 0; r < 4; ++r) {
        int m = m0 + wm * 128 + mi * 16 + (lane >> 4) * 4 + r;
        float v = acc[mi][ni][r] + bv;
        v = v / (1.f + fabsf(v));
        up_t[(size_t)m * 1024 + np] = f2b(v);
      }
  }
}

// ---------------------------------------------------------------------------
// dc3
// ---------------------------------------------------------------------------
__global__ __launch_bounds__(256) void dc3_kernel(const unsigned short* __restrict__ up_t,
                                                  const float* __restrict__ w3,
                                                  const float* __restrict__ b3,
                                                  unsigned short* __restrict__ y1_t) {
  const int lane = threadIdx.x & 63, wv = threadIdx.x >> 6;
  const int kq = (lane >> 4) * 8;
  const int oc = lane & 15;
  bf16x8 bf[2][6];
#pragma unroll
  for (int nt = 0; nt < 2; ++nt)
#pragma unroll
    for (int kk = 0; kk < 6; ++kk) {
      bf16x8 v;
#pragma unroll
      for (int t = 0; t < 8; ++t) {
        int k = kk * 32 + kq + t;
        int jj = k >> 6, ic = k & 63;
        v[t] = (short)f2b(w3[((size_t)ic * 32 + nt * 16 + oc) * 3 + jj]);
      }
      bf[nt][kk] = v;
    }
  const float bia0 = b3[oc], bia1 = b3[16 + oc];
  const int base_chunk = blockIdx.x * 32 + wv * 8;
  for (int cc = 0; cc < 8; ++cc) {
    const int chunk = base_chunk + cc;
    int m = chunk * 16 + (lane & 15);
    int img = m / 18, ow = m - img * 18;
    const unsigned short* arow = up_t + (size_t)img * 1024;
    f32x4 acc0 = {0.f, 0.f, 0.f, 0.f}, acc1 = {0.f, 0.f, 0.f, 0.f};
#pragma unroll
    for (int kk = 0; kk < 6; ++kk) {
      int jj = kk >> 1;
      int ic0 = (kk & 1) * 32 + kq;
      int iw = ow - jj;
      bf16x8 a = {0, 0, 0, 0, 0, 0, 0, 0};
      if ((unsigned)iw < 16u) a = *(const bf16x8*)(arow + iw * 64 + ic0);
      acc0 = __builtin_amdgcn_mfma_f32_16x16x32_bf16(a, bf[0][kk], acc0, 0, 0, 0);
      acc1 = __builtin_amdgcn_mfma_f32_16x16x32_bf16(a, bf[1][kk], acc1, 0, 0, 0);
    }
#pragma unroll
    for (int r = 0; r < 4; ++r) {
      int mm = chunk * 16 + (lane >> 4) * 4 + r;
      float v0 = acc0[r] + bia0; v0 = v0 > 0.f ? v0 : 0.01f * v0;
      float v1 = acc1[r] + bia1; v1 = v1 > 0.f ? v1 : 0.01f * v1;
      y1_t[(size_t)mm * 32 + oc] = f2b(v0);
      y1_t[(size_t)mm * 32 + 16 + oc] = f2b(v1);
    }
  }
}

// ---------------------------------------------------------------------------
// dc1
// ---------------------------------------------------------------------------
__global__ __launch_bounds__(256) void dc1_kernel(const unsigned short* __restrict__ y1_t,
                                                  const float* __restrict__ w1,
                                                  const float* __restrict__ b1,
                                                  unsigned short* __restrict__ y2_t) {
  const int lane = threadIdx.x & 63, wv = threadIdx.x >> 6;
  const int kq = (lane >> 4) * 8;
  const int oc = lane & 15;
  bf16x8 bf[5];
#pragma unroll
  for (int kk = 0; kk < 5; ++kk) {
    bf16x8 v;
#pragma unroll
    for (int t = 0; t < 8; ++t) {
      int ic = kq + t;
      v[t] = (short)f2b(w1[((size_t)ic * 16 + oc) * 5 + kk]);
    }
    bf[kk] = v;
  }
  const float bia = b1[oc];
  const int base_chunk = blockIdx.x * 32 + wv * 8;
  for (int cc = 0; cc < 8; ++cc) {
    const int chunk = base_chunk + cc;
    int m = chunk * 16 + (lane & 15);
    int img = m / 22, ow = m - img * 22;
    const unsigned short* abase = y1_t + (size_t)img * 18 * 32;
    f32x4 acc = {0.f, 0.f, 0.f, 0.f};
#pragma unroll
    for (int kk = 0; kk < 5; ++kk) {
      int iw = ow - kk;
      bf16x8 a = {0, 0, 0, 0, 0, 0, 0, 0};
      if ((unsigned)iw < 18u) a = *(const bf16x8*)(abase + iw * 32 + kq);
      acc = __builtin_amdgcn_mfma_f32_16x16x32_bf16(a, bf[kk], acc, 0, 0, 0);
    }
#pragma unroll
    for (int r = 0; r < 4; ++r) {
      int mm = chunk * 16 + (lane >> 4) * 4 + r;
      float v = acc[r] + bia;
      v = v > 0.f ? v : 0.01f * v;
      y2_t[(size_t)mm * 16 + oc] = f2b(v);
    }
  }
}

// ---------------------------------------------------------------------------
// dc2 + softmax over oh
// ---------------------------------------------------------------------------
__global__ __launch_bounds__(256) void dc2_kernel(const unsigned short* __restrict__ y2_t,
                                                  const float* __restrict__ w2,
                                                  const float* __restrict__ b2,
                                                  float* __restrict__ out) {
  int idx = blockIdx.x * 256 + threadIdx.x;
  int img = idx / 24, ow = idx - img * 24;
  float lg0 = b2[0], lg1 = b2[0], lg2 = b2[0];
#pragma unroll
  for (int jj = 0; jj < 3; ++jj) {
    int iw = ow - jj;
    if ((unsigned)iw >= 22u) continue;
    const unsigned short* row = y2_t + ((size_t)img * 22 + iw) * 16;
    bf16x8 v0 = *(const bf16x8*)(row);
    bf16x8 v1 = *(const bf16x8*)(row + 8);
    float x[16];
#pragma unroll
    for (int ic = 0; ic < 8; ++ic) {
      x[ic] = b2f((unsigned short)v0[ic]);
      x[8 + ic] = b2f((unsigned short)v1[ic]);
    }
#pragma unroll
    for (int ic = 0; ic < 16; ++ic) {
      lg0 += x[ic] * w2[ic * 9 + 0 * 3 + jj];
      lg1 += x[ic] * w2[ic * 9 + 1 * 3 + jj];
      lg2 += x[ic] * w2[ic * 9 + 2 * 3 + jj];
    }
  }
  lg0 = lg0 > 0.f ? lg0 : 0.01f * lg0;
  lg1 = lg1 > 0.f ? lg1 : 0.01f * lg1;
  lg2 = lg2 > 0.f ? lg2 : 0.01f * lg2;
  float mx = fmaxf(lg0, fmaxf(lg1, lg2));
  float e0 = __expf(lg0 - mx), e1 = __expf(lg1 - mx), e2 = __expf(lg2 - mx);
  float inv = 1.f / (e0 + e1 + e2);
  size_t ob = (size_t)img * 72 + ow;
  out[ob] = e0 * inv;
  out[ob + 24] = e1 * inv;
  out[ob + 48] = e2 * inv;
}

// ---------------------------------------------------------------------------
extern "C" void kernel_launch(void* const* d_in, const int* in_sizes, int n_in,
                              void* d_out, int out_size, void* d_ws, size_t ws_size,
                              hipStream_t stream) {
  (void)in_sizes; (void)n_in; (void)out_size; (void)ws_size;
  const float* enc    = (const float*)d_in[0];
  const float* noise  = (const float*)d_in[1];
  const float* erep_w = (const float*)d_in[2];
  const float* erep_b = (const float*)d_in[3];
  const float* wih_f  = (const float*)d_in[4];
  const float* whh_f  = (const float*)d_in[5];
  const float* bih_f  = (const float*)d_in[6];
  const float* bhh_f  = (const float*)d_in[7];
  const float* wih_b  = (const float*)d_in[8];
  const float* whh_b  = (const float*)d_in[9];
  const float* bih_b  = (const float*)d_in[10];
  const float* bhh_b  = (const float*)d_in[11];
  const float* emb_w  = (const float*)d_in[12];
  const float* emb_b  = (const float*)d_in[13];
  const float* dc3w   = (const float*)d_in[14];
  const float* dc3b   = (const float*)d_in[15];
  const float* dc1w   = (const float*)d_in[16];
  const float* dc1b   = (const float*)d_in[17];
  const float* dc2w   = (const float*)d_in[18];
  const float* dc2b   = (const float*)d_in[19];
  float* out = (float*)d_out;

  char* p = (char*)d_ws;
  auto carve = [&p](size_t bytes) {
    char* r = p;
    p += (bytes + 255) & ~(size_t)255;
    return r;
  };
  unsigned short* rep_t  = (unsigned short*)carve(7ull * 4096 * 256 * 2);
  unsigned short* lstmW  = (unsigned short*)carve(2ull * 2048 * 768 * 2);
  float*          lstmB  = (float*)carve(2ull * 2048 * 4);
  unsigned short* noiseb = (unsigned short*)carve(4096ull * 256 * 2);
  unsigned short* erepT  = (unsigned short*)carve(1792ull * 256 * 2);
  unsigned short* embT   = (unsigned short*)carve(1024ull * 1024 * 2);
  unsigned short* hbuf   = (unsigned short*)carve(4ull * 4096 * 512 * 2);   // [pp][dir]
  float*          cbuf   = (float*)carve(2ull * 4096 * 512 * 4);            // [dir]
  unsigned short* lstm1  = (unsigned short*)carve(4096ull * 7 * 1024 * 2);
  unsigned short* att    = (unsigned short*)carve(28672ull * 1024 * 2);
  unsigned short* up_t   = (unsigned short*)carve(28672ull * 1024 * 2);
  unsigned short* y1_t   = (unsigned short*)carve(28672ull * 18 * 32 * 2);
  unsigned short* y2_t   = (unsigned short*)carve(28672ull * 22 * 16 * 2);

  hipMemsetAsync(hbuf, 0, 2ull * 4096 * 512 * 2, stream);
  hipMemsetAsync(cbuf, 0, 2ull * 4096 * 512 * 4, stream);

  pack_kernel<<<2048, 256, 0, stream>>>(noise, erep_w, emb_w, wih_f, whh_f, bih_f, bhh_f,
                                        wih_b, whh_b, bih_b, bhh_b,
                                        noiseb, erepT, embT, lstmW, lstmB);
  gemm_rep_kernel<<<dim3(14, 32), 256, 0, stream>>>(noiseb, erepT, erep_b, rep_t);
  for (int s = 0; s < 7; ++s)
    lstm_step256_kernel<<<256, 512, 0, stream>>>(rep_t, lstmW, lstmB, hbuf, cbuf, lstm1, s);
  att_fused2_kernel<<<4096, 256, 0, stream>>>(enc, lstm1, att);
  gemm_emb256_kernel<<<448, 512, 0, stream>>>(att, embT, emb_b, up_t);
  dc3_kernel<<<1008, 256, 0, stream>>>(up_t, dc3w, dc3b, y1_t);
  dc1_kernel<<<1232, 256, 0, stream>>>(y1_t, dc1w, dc1b, y2_t);
  dc2_kernel<<<2688, 256, 0, stream>>>(y2_t, dc2w, dc2b, out);
}

// Round 8
// 495.041 us; speedup vs baseline: 1.4199x; 1.0303x over previous
//
#include <hip/hip_runtime.h>
#include <stdint.h>

// ---------------------------------------------------------------------------
// decoder_80487687127254 : B=4096 T=7 H=512 L=256 D=1024
// ---------------------------------------------------------------------------

typedef __attribute__((ext_vector_type(4))) float f32x4;
typedef __attribute__((ext_vector_type(8))) short bf16x8;
typedef __attribute__((ext_vector_type(4))) unsigned short us4;

__device__ __forceinline__ unsigned short f2b(float f) {
  union { float f; unsigned u; } x; x.f = f;
  unsigned r = x.u + 0x7FFFu + ((x.u >> 16) & 1u);   // RNE
  return (unsigned short)(r >> 16);
}
__device__ __forceinline__ float b2f(unsigned short s) {
  union { unsigned u; float f; } x; x.u = ((unsigned)s) << 16; return x.f;
}
__device__ __forceinline__ float sigmoidf(float x) {
  return 1.f / (1.f + __expf(-x));
}
__device__ __forceinline__ float fast_tanh(float x) {
  x = fminf(15.f, fmaxf(-15.f, x));
  float e = __expf(2.f * x);
  return (e - 1.f) / (e + 1.f);
}

// async global->LDS, 16B per lane; LDS dest must be wave-uniform (HW adds lane*16)
__device__ __forceinline__ void gl_lds16(const void* g, void* l) {
  auto gp = reinterpret_cast<const __attribute__((address_space(1))) unsigned int*>(
      reinterpret_cast<uintptr_t>(g));
  auto lp = reinterpret_cast<__attribute__((address_space(3))) unsigned int*>(
      reinterpret_cast<uintptr_t>(l));
  __builtin_amdgcn_global_load_lds(gp, lp, 16, 0, 0);
}

// ===========================================================================
// 256x256 8-wave GEMM core, BK=32, 4-deep LDS ring.
// m201-style schedule: reads of tile t+1 are issued at the END of tile t
// (pre-barrier, overlapping other waves' MFMA) and drained by lgkmcnt(0)
// AFTER tile t+1's barrier.  The top-of-tile gate vmcnt(4) certifies tile
// t+1's stores (outstanding = {t+1,t+2} = 8 loads; vmcnt drains oldest-
// first), so the pre-issued reads are race-free.  One barrier per K-tile,
// 32 MFMA per barrier.
// ===========================================================================

// stage one 256x32 tile: 2 gl_lds per thread, dest linear, source granule
// pre-inverse-swizzled (verified R5-R7: bank conflicts = 0).
__device__ __forceinline__ void stage_half(const unsigned short* src, int ld,
                                           unsigned short* hbase, int tid) {
  const int row_in = tid >> 2;   // 0..127
  const int gidx = tid & 3;      // dest granule position
#pragma unroll
  for (int r = 0; r < 2; ++r) {
    int row = r * 128 + row_in;
    int gsrc = gidx ^ ((row >> 1) & 3);
    gl_lds16(src + (size_t)row * ld + gsrc * 8, hbase + r * 4096 + (tid >> 6) * 512);
  }
}

__device__ __forceinline__ bf16x8 lds_fragH(const unsigned short* hbase, int row, int lq) {
  return *(const bf16x8*)(hbase + row * 32 + (lq ^ (((row >> 1) & 3) << 3)));
}

// issue the 12 ds_read_b128 for one K-tile into registers
__device__ __forceinline__ void tile_reads(const unsigned short* Ab, const unsigned short* Bb,
                                           int wm, int wn, int lane,
                                           bf16x8 (&a)[8], bf16x8 (&b)[4]) {
  const int lr = lane & 15, lq = (lane >> 4) * 8;
#pragma unroll
  for (int i = 0; i < 8; ++i) a[i] = lds_fragH(Ab, wm * 128 + i * 16 + lr, lq);
#pragma unroll
  for (int n = 0; n < 4; ++n) b[n] = lds_fragH(Bb, wn * 64 + n * 16 + lr, lq);
}

__device__ __forceinline__ void tile_mfma(bf16x8 (&a)[8], bf16x8 (&b)[4], f32x4 (&acc)[8][4]) {
  __builtin_amdgcn_s_setprio(1);
#pragma unroll
  for (int i = 0; i < 8; ++i)
#pragma unroll
    for (int n = 0; n < 4; ++n)
      acc[i][n] = __builtin_amdgcn_mfma_f32_16x16x32_bf16(a[i], b[n], acc[i][n], 0, 0, 0);
  __builtin_amdgcn_s_setprio(0);
}

#define RING_TOP(t, NT)                                                   \
  if ((t) < (NT)-2) asm volatile("s_waitcnt vmcnt(4)" ::: "memory");      \
  else              asm volatile("s_waitcnt vmcnt(0)" ::: "memory");      \
  __builtin_amdgcn_s_barrier();                                           \
  __builtin_amdgcn_sched_barrier(0);                                      \
  asm volatile("s_waitcnt lgkmcnt(0)" ::: "memory");                      \
  __builtin_amdgcn_sched_barrier(0);

// ---------------------------------------------------------------------------
// 128x128 core (kept for gemm_rep)
// ---------------------------------------------------------------------------
__device__ __forceinline__ void stage128x64(const unsigned short* src, int ld,
                                            unsigned short* lds, int wv, int lane) {
#pragma unroll
  for (int r = 0; r < 4; ++r) {
    int row = r * 32 + wv * 8 + (lane >> 3);
    gl_lds16(src + (size_t)row * ld + (lane & 7) * 8, lds + (r * 32 + wv * 8) * 64);
  }
}
__device__ __forceinline__ void mfma_tile(const unsigned short* As, const unsigned short* Bs,
                                          int wm, int wn, int lane, f32x4 acc[4][4]) {
#pragma unroll
  for (int kk = 0; kk < 2; ++kk) {
    int ko = kk * 32 + (lane >> 4) * 8;
    bf16x8 a[4], b[4];
#pragma unroll
    for (int i = 0; i < 4; ++i)
      a[i] = *(const bf16x8*)(As + (size_t)(wm * 64 + i * 16 + (lane & 15)) * 64 + ko);
#pragma unroll
    for (int i = 0; i < 4; ++i)
      b[i] = *(const bf16x8*)(Bs + (size_t)(wn * 64 + i * 16 + (lane & 15)) * 64 + ko);
#pragma unroll
    for (int mi = 0; mi < 4; ++mi)
#pragma unroll
      for (int ni = 0; ni < 4; ++ni)
        acc[mi][ni] = __builtin_amdgcn_mfma_f32_16x16x32_bf16(a[mi], b[ni], acc[mi][ni], 0, 0, 0);
  }
}

// ---------------------------------------------------------------------------
// pack
// ---------------------------------------------------------------------------
__global__ __launch_bounds__(256) void pack_kernel(
    const float* __restrict__ noise, const float* __restrict__ erep_w,
    const float* __restrict__ emb_w,
    const float* __restrict__ wih_f, const float* __restrict__ whh_f,
    const float* __restrict__ bih_f, const float* __restrict__ bhh_f,
    const float* __restrict__ wih_b, const float* __restrict__ whh_b,
    const float* __restrict__ bih_b, const float* __restrict__ bhh_b,
    unsigned short* __restrict__ noiseb, unsigned short* __restrict__ erepT,
    unsigned short* __restrict__ embT, unsigned short* __restrict__ lstmW,
    float* __restrict__ lstmB) {
  const int N0 = 4096 * 256;
  const int N1 = 1792 * 256;
  const int N2 = 1024 * 1024;
  const int N3 = 2 * 2048 * 768;
  const int N4 = 2 * 2048;
  const int total = N0 + N1 + N2 + N3 + N4;
  for (int i = blockIdx.x * 256 + threadIdx.x; i < total; i += gridDim.x * 256) {
    int x = i;
    if (x < N0) { noiseb[x] = f2b(noise[x]); continue; }
    x -= N0;
    if (x < N1) { int n = x >> 8, k = x & 255; erepT[x] = f2b(erep_w[k * 1792 + n]); continue; }
    x -= N1;
    if (x < N2) {
      int n = x >> 10, k = x & 1023;
      int o = (n & 63) * 16 + (n >> 6);
      embT[x] = f2b(emb_w[k * 1024 + o]);
      continue;
    }
    x -= N2;
    if (x < N3) {
      int dir = x / (2048 * 768);
      int r = x - dir * (2048 * 768);
      int npk = r / 768, k = r - (r / 768) * 768;
      int blk = npk >> 6, g = (npk >> 4) & 3, u = npk & 15;
      int o = g * 512 + blk * 16 + u;
      const float* wih = dir ? wih_b : wih_f;
      const float* whh = dir ? whh_b : whh_f;
      float v = (k < 256) ? wih[k * 2048 + o] : whh[(k - 256) * 2048 + o];
      lstmW[x] = f2b(v);
      continue;
    }
    x -= N3;
    {
      int dir = x >> 11, npk = x & 2047;
      int blk = npk >> 6, g = (npk >> 4) & 3, u = npk & 15;
      int o = g * 512 + blk * 16 + u;
      lstmB[x] = dir ? (bih_b[o] + bhh_b[o]) : (bih_f[o] + bhh_f[o]);
    }
  }
}

// ---------------------------------------------------------------------------
// rep = softsign(noise @ erep_w + b)
// ---------------------------------------------------------------------------
__global__ __launch_bounds__(256) void gemm_rep_kernel(
    const unsigned short* __restrict__ A, const unsigned short* __restrict__ Bt,
    const float* __restrict__ bias, unsigned short* __restrict__ rep_t) {
  __shared__ unsigned short As[128 * 64];
  __shared__ unsigned short Bs[128 * 64];
  const int lane = threadIdx.x & 63, wv = threadIdx.x >> 6;
  const int wm = wv >> 1, wn = wv & 1;
  const int m0 = blockIdx.y * 128, n0 = blockIdx.x * 128;
  f32x4 acc[4][4];
#pragma unroll
  for (int i = 0; i < 4; ++i)
#pragma unroll
    for (int j = 0; j < 4; ++j) acc[i][j] = (f32x4){0.f, 0.f, 0.f, 0.f};
  for (int k0 = 0; k0 < 256; k0 += 64) {
    stage128x64(A + (size_t)m0 * 256 + k0, 256, As, wv, lane);
    stage128x64(Bt + (size_t)n0 * 256 + k0, 256, Bs, wv, lane);
    __syncthreads();
    mfma_tile(As, Bs, wm, wn, lane, acc);
    __syncthreads();
  }
#pragma unroll
  for (int ni = 0; ni < 4; ++ni) {
    int n = n0 + wn * 64 + ni * 16 + (lane & 15);
    float bv = bias[n];
    int t = n >> 8, l = n & 255;
#pragma unroll
    for (int mi = 0; mi < 4; ++mi)
#pragma unroll
      for (int r = 0; r < 4; ++r) {
        int m = m0 + wm * 64 + mi * 16 + (lane >> 4) * 4 + r;
        float v = acc[mi][ni][r] + bv;
        v = v / (1.f + fabsf(v));
        rep_t[((size_t)t * 4096 + m) * 256 + l] = f2b(v);
      }
  }
}

// ---------------------------------------------------------------------------
// LSTM step, 256x256 ring core (m201-style pre-issued reads). K=768 -> 24 tiles
// c-state stored bf16.
// ---------------------------------------------------------------------------
__global__ __launch_bounds__(512, 2) void lstm_step256_kernel(
    const unsigned short* __restrict__ rep_t, const unsigned short* __restrict__ Wp,
    const float* __restrict__ biasP, unsigned short* __restrict__ hbuf,
    unsigned short* __restrict__ cbuf, unsigned short* __restrict__ lstm1, int step) {
  __shared__ unsigned short Ar[4][8192];
  __shared__ unsigned short Br[4][8192];
  const int tid = threadIdx.x, lane = tid & 63, wv = tid >> 6;
  const int wm = wv >> 2, wn = wv & 3;
  const int swz = (blockIdx.x & 7) * 32 + (blockIdx.x >> 3);
  const int dir = swz >> 7;
  const int by = (swz & 127) >> 3, bx = swz & 7;
  const int m0 = by * 256, n0 = bx * 256;
  const int t_proc = dir ? (6 - step) : step;
  const unsigned short* W = Wp + (size_t)dir * 2048 * 768;
  const unsigned short* hin = hbuf + ((size_t)(step & 1) * 2 + dir) * (4096 * 512);
  unsigned short* hout = hbuf + ((size_t)((step + 1) & 1) * 2 + dir) * (4096 * 512);
  unsigned short* cp = cbuf + (size_t)dir * (4096 * 512);
  const unsigned short* xsrc = rep_t + (size_t)t_proc * 4096 * 256;

  f32x4 acc[8][4];
#pragma unroll
  for (int i = 0; i < 8; ++i)
#pragma unroll
    for (int j = 0; j < 4; ++j) acc[i][j] = (f32x4){0.f, 0.f, 0.f, 0.f};

  auto asrc = [&](int tt) {
    return tt < 8 ? xsrc + (size_t)m0 * 256 + tt * 32
                  : hin + (size_t)m0 * 512 + (tt - 8) * 32;
  };
  auto ald = [&](int tt) { return tt < 8 ? 256 : 512; };

  // prologue: tiles 0,1,2 (oldest pair first), certify tile 0, pre-issue reads
  stage_half(asrc(0), ald(0), Ar[0], tid);
  stage_half(W + (size_t)n0 * 768 + 0 * 32, 768, Br[0], tid);
  stage_half(asrc(1), ald(1), Ar[1], tid);
  stage_half(W + (size_t)n0 * 768 + 1 * 32, 768, Br[1], tid);
  stage_half(asrc(2), ald(2), Ar[2], tid);
  stage_half(W + (size_t)n0 * 768 + 2 * 32, 768, Br[2], tid);
  asm volatile("s_waitcnt vmcnt(8)" ::: "memory");   // tile 0 stores landed
  __builtin_amdgcn_s_barrier();
  __builtin_amdgcn_sched_barrier(0);
  bf16x8 a[8], b[4];
  tile_reads(Ar[0], Br[0], wm, wn, lane, a, b);

  for (int t = 0; t < 24; ++t) {
    RING_TOP(t, 24)
    tile_mfma(a, b, acc);
    if (t + 3 < 24) {
      stage_half(asrc(t + 3), ald(t + 3), Ar[(t + 3) & 3], tid);
      stage_half(W + (size_t)n0 * 768 + (t + 3) * 32, 768, Br[(t + 3) & 3], tid);
    }
    if (t + 1 < 24) tile_reads(Ar[(t + 1) & 3], Br[(t + 1) & 3], wm, wn, lane, a, b);
  }

  const int u = lane & 15;
  const int blk = (n0 + wn * 64) >> 6;
  const int j = blk * 16 + u;
  const float bz0 = biasP[dir * 2048 + blk * 64 + 0 * 16 + u];
  const float bz1 = biasP[dir * 2048 + blk * 64 + 1 * 16 + u];
  const float bz2 = biasP[dir * 2048 + blk * 64 + 2 * 16 + u];
  const float bz3 = biasP[dir * 2048 + blk * 64 + 3 * 16 + u];
#pragma unroll
  for (int mi = 0; mi < 8; ++mi)
#pragma unroll
    for (int r = 0; r < 4; ++r) {
      int row = m0 + wm * 128 + mi * 16 + (lane >> 4) * 4 + r;
      float gi = acc[mi][0][r] + bz0;
      float gf = acc[mi][1][r] + bz1;
      float gg = acc[mi][2][r] + bz2;
      float go = acc[mi][3][r] + bz3;
      size_t ci = (size_t)row * 512 + j;
      float c = sigmoidf(gf) * b2f(cp[ci]) + sigmoidf(gi) * fast_tanh(gg);
      cp[ci] = f2b(c);
      float h = sigmoidf(go) * fast_tanh(c);
      unsigned short hb = f2b(h);
      hout[ci] = hb;
      lstm1[((size_t)row * 7 + t_proc) * 1024 + dir * 512 + j] = hb;
    }
}

// ---------------------------------------------------------------------------
// Fused attention v3: bf16 E (no hi/lo), wave-local staging (no barrier
// before Gram), 2 block barriers total.  ~38 KB LDS -> 4 blocks/CU.
// ---------------------------------------------------------------------------
__global__ __launch_bounds__(256) void att_fused3_kernel(
    const float* __restrict__ enc, const unsigned short* __restrict__ lstm1,
    unsigned short* __restrict__ att) {
  __shared__ unsigned short Qs[7 * 1032];
  __shared__ unsigned short Es[7 * 1032];
  __shared__ float P[8 * 256];
  __shared__ float sG[98];
  __shared__ float sC[7][14];
  __shared__ float sA[16];
  const int tid = threadIdx.x, lane = tid & 63, wv = tid >> 6;
  const int b = blockIdx.x;
  const float* Eb = enc + (size_t)b * 7168;
  const unsigned short* Qb = lstm1 + (size_t)b * 7168;

  if (tid < 98) ((float*)sC)[tid] = 0.f;

  // ---- stage: thread tid owns dims [4*tid, 4*tid+4) for all 7 rows ----
  const f32x4* Eb4 = (const f32x4*)Eb;
  const int d0 = tid * 4;
#pragma unroll
  for (int r = 0; r < 7; ++r) {
    f32x4 v = Eb4[r * 256 + tid];
    us4 hi;
#pragma unroll
    for (int e = 0; e < 4; ++e) hi[e] = f2b(v[e]);
    *(us4*)&Es[r * 1032 + d0] = hi;
    *(us4*)&Qs[r * 1032 + d0] = *(const us4*)(Qb + r * 1024 + d0);
  }
  // wave-local: Gram reads only this wave's 256-dim slice -> lgkm drain only
  asm volatile("s_waitcnt lgkmcnt(0)" ::: "memory");
  __builtin_amdgcn_sched_barrier(0);

  // ---- Gram via MFMA: wave wv covers k in [wv*256, wv*256+256) ----
  {
    const int rr = lane & 15;
    const int rowc = rr % 7;    // duplicate rows broadcast (same address)
    const int kbase = wv * 256 + (lane >> 4) * 8;
    f32x4 g1 = {0.f, 0.f, 0.f, 0.f}, g2 = {0.f, 0.f, 0.f, 0.f};
#pragma unroll
    for (int s = 0; s < 8; ++s) {
      const int k0 = kbase + s * 32;
      bf16x8 aq = *(const bf16x8*)&Qs[rowc * 1032 + k0];
      bf16x8 be = *(const bf16x8*)&Es[rowc * 1032 + k0];
      g1 = __builtin_amdgcn_mfma_f32_16x16x32_bf16(aq, be, g1, 0, 0, 0);
      g2 = __builtin_amdgcn_mfma_f32_16x16x32_bf16(aq, aq, g2, 0, 0, 0);
    }
    *(f32x4*)&P[((wv * 2 + 0) * 64 + lane) * 4] = g1;
    *(f32x4*)&P[((wv * 2 + 1) * 64 + lane) * 4] = g2;
  }
  __syncthreads();

  // ---- gather G + recursion (wave 0) ----
  if (tid < 98) {
    int i = tid / 14, v = tid - i * 14;
    int col = v < 7 ? v : v - 7;
    int tile = v < 7 ? 0 : 1;
    int ln = ((i >> 2) << 4) | col;
    int rg = i & 3;
    float s = 0.f;
#pragma unroll
    for (int w = 0; w < 4; ++w) s += P[((w * 2 + tile) * 64 + ln) * 4 + rg];
    sG[i * 14 + v] = s;
  }
  __syncthreads();
  if (wv == 0) {
    for (int i = 0; i < 7; ++i) {
      const int nt = 7 + i;
      float s = -1e30f;
      if (lane < 7) {
        s = sG[i * 14 + lane];
      } else if (lane < nt) {
        int jj = lane - 7;
        float a2 = 0.f;
#pragma unroll
        for (int v = 0; v < 14; ++v) a2 += sC[jj][v] * sG[i * 14 + v];
        s = a2;
      }
      float mx = s;
#pragma unroll
      for (int off = 8; off >= 1; off >>= 1) mx = fmaxf(mx, __shfl_xor(mx, off, 16));
      float e = (lane < nt) ? __expf(s - mx) : 0.f;
      float sum = e;
#pragma unroll
      for (int off = 8; off >= 1; off >>= 1) sum += __shfl_xor(sum, off, 16);
      float aw = e / sum;
      if (lane < 16) sA[lane] = aw;
      if (lane < 14) {
        float c = (lane < 7) ? sA[lane] : 0.f;
        for (int jj = 0; jj < i; ++jj) c += sA[7 + jj] * sC[jj][lane];
        if (lane == 7 + i) c += 1.f;
        sC[i][lane] = c;
      }
    }
  }
  __syncthreads();

  // ---- output: att[i][d] = sum_v C[i][v]*basis[v][d] (thread-local reads) ----
  {
    float acc[7][4];
#pragma unroll
    for (int i = 0; i < 7; ++i)
#pragma unroll
      for (int e = 0; e < 4; ++e) acc[i][e] = 0.f;
#pragma unroll
    for (int t = 0; t < 7; ++t) {
      us4 ev = *(const us4*)&Es[t * 1032 + d0];
      float evf[4];
#pragma unroll
      for (int e = 0; e < 4; ++e) evf[e] = b2f(ev[e]);
#pragma unroll
      for (int i = 0; i < 7; ++i) {
        float c = sC[i][t];
#pragma unroll
        for (int e = 0; e < 4; ++e) acc[i][e] += c * evf[e];
      }
    }
#pragma unroll
    for (int m = 0; m < 7; ++m) {
      us4 qv = *(const us4*)&Qs[m * 1032 + d0];
      float qf[4];
#pragma unroll
      for (int e = 0; e < 4; ++e) qf[e] = b2f(qv[e]);
#pragma unroll
      for (int i = m; i < 7; ++i) {   // sC[i][7+m]==0 for i<m
        float c = sC[i][7 + m];
#pragma unroll
        for (int e = 0; e < 4; ++e) acc[i][e] += c * qf[e];
      }
    }
    unsigned short* Ab = att + (size_t)b * 7168;
#pragma unroll
    for (int i = 0; i < 7; ++i) {
      us4 r;
#pragma unroll
      for (int e = 0; e < 4; ++e) r[e] = f2b(acc[i][e]);
      *(us4*)(Ab + i * 1024 + d0) = r;
    }
  }
}

// ---------------------------------------------------------------------------
// up_t = softsign(att @ emb_w + emb_b), ring core, K=1024 -> 32 tiles
// ---------------------------------------------------------------------------
__global__ __launch_bounds__(512, 2) void gemm_emb256_kernel(
    const unsigned short* __restrict__ A, const unsigned short* __restrict__ Bt,
    const float* __restrict__ bias, unsigned short* __restrict__ up_t) {
  __shared__ unsigned short Ar[4][8192];
  __shared__ unsigned short Br[4][8192];
  const int tid = threadIdx.x, lane = tid & 63, wv = tid >> 6;
  const int wm = wv >> 2, wn = wv & 3;
  const int swz = (blockIdx.x & 7) * 56 + (blockIdx.x >> 3);
  const int by = swz >> 2, bx = swz & 3;
  const int m0 = by * 256, n0 = bx * 256;

  f32x4 acc[8][4];
#pragma unroll
  for (int i = 0; i < 8; ++i)
#pragma unroll
    for (int j = 0; j < 4; ++j) acc[i][j] = (f32x4){0.f, 0.f, 0.f, 0.f};

  const unsigned short* Abase = A + (size_t)m0 * 1024;
  const unsigned short* Bbase = Bt + (size_t)n0 * 1024;

  stage_half(Abase + 0 * 32, 1024, Ar[0], tid);
  stage_half(Bbase + 0 * 32, 1024, Br[0], tid);
  stage_half(Abase + 1 * 32, 1024, Ar[1], tid);
  stage_half(Bbase + 1 * 32, 1024, Br[1], tid);
  stage_half(Abase + 2 * 32, 1024, Ar[2], tid);
  stage_half(Bbase + 2 * 32, 1024, Br[2], tid);
  asm volatile("s_waitcnt vmcnt(8)" ::: "memory");
  __builtin_amdgcn_s_barrier();
  __builtin_amdgcn_sched_barrier(0);
  bf16x8 a[8], b[4];
  tile_reads(Ar[0], Br[0], wm, wn, lane, a, b);

  for (int t = 0; t < 32; ++t) {
    RING_TOP(t, 32)
    tile_mfma(a, b, acc);
    if (t + 3 < 32) {
      stage_half(Abase + (t + 3) * 32, 1024, Ar[(t + 3) & 3], tid);
      stage_half(Bbase + (t + 3) * 32, 1024, Br[(t + 3) & 3], tid);
    }
    if (t + 1 < 32) tile_reads(Ar[(t + 1) & 3], Br[(t + 1) & 3], wm, wn, lane, a, b);
  }

#pragma unroll
  for (int ni = 0; ni < 4; ++ni) {
    int np = n0 + wn * 64 + ni * 16 + (lane & 15);
    int o = (np & 63) * 16 + (np >> 6);
    float bv = bias[o];
#pragma unroll
    for (int mi = 0; mi < 8; ++mi)
#pragma unroll
      for (int r = 0; r < 4; ++r) {
        int m = m0 + wm * 128 + mi * 16 + (lane >> 4) * 4 + r;
        float v = acc[mi][ni][r] + bv;
        v = v / (1.f + fabsf(v));
        up_t[(size_t)m * 1024 + np] = f2b(v);
      }
  }
}

// ---------------------------------------------------------------------------
// dc3
// ---------------------------------------------------------------------------
__global__ __launch_bounds__(256) void dc3_kernel(const unsigned short* __restrict__ up_t,
                                                  const float* __restrict__ w3,
                                                  const float* __restrict__ b3,
                                                  unsigned short* __restrict__ y1_t) {
  const int lane = threadIdx.x & 63, wv = threadIdx.x >> 6;
  const int kq = (lane >> 4) * 8;
  const int oc = lane & 15;
  bf16x8 bf[2][6];
#pragma unroll
  for (int nt = 0; nt < 2; ++nt)
#pragma unroll
    for (int kk = 0; kk < 6; ++kk) {
      bf16x8 v;
#pragma unroll
      for (int t = 0; t < 8; ++t) {
        int k = kk * 32 + kq + t;
        int jj = k >> 6, ic = k & 63;
        v[t] = (short)f2b(w3[((size_t)ic * 32 + nt * 16 + oc) * 3 + jj]);
      }
      bf[nt][kk] = v;
    }
  const float bia0 = b3[oc], bia1 = b3[16 + oc];
  const int base_chunk = blockIdx.x * 32 + wv * 8;
  for (int cc = 0; cc < 8; ++cc) {
    const int chunk = base_chunk + cc;
    int m = chunk * 16 + (lane & 15);
    int img = m / 18, ow = m - img * 18;
    const unsigned short* arow = up_t + (size_t)img * 1024;
    f32x4 acc0 = {0.f, 0.f, 0.f, 0.f}, acc1 = {0.f, 0.f, 0.f, 0.f};
#pragma unroll
    for (int kk = 0; kk < 6; ++kk) {
      int jj = kk >> 1;
      int ic0 = (kk & 1) * 32 + kq;
      int iw = ow - jj;
      bf16x8 a = {0, 0, 0, 0, 0, 0, 0, 0};
      if ((unsigned)iw < 16u) a = *(const bf16x8*)(arow + iw * 64 + ic0);
      acc0 = __builtin_amdgcn_mfma_f32_16x16x32_bf16(a, bf[0][kk], acc0, 0, 0, 0);
      acc1 = __builtin_amdgcn_mfma_f32_16x16x32_bf16(a, bf[1][kk], acc1, 0, 0, 0);
    }
#pragma unroll
    for (int r = 0; r < 4; ++r) {
      int mm = chunk * 16 + (lane >> 4) * 4 + r;
      float v0 = acc0[r] + bia0; v0 = v0 > 0.f ? v0 : 0.01f * v0;
      float v1 = acc1[r] + bia1; v1 = v1 > 0.f ? v1 : 0.01f * v1;
      y1_t[(size_t)mm * 32 + oc] = f2b(v0);
      y1_t[(size_t)mm * 32 + 16 + oc] = f2b(v1);
    }
  }
}

// ---------------------------------------------------------------------------
// dc1
// ---------------------------------------------------------------------------
__global__ __launch_bounds__(256) void dc1_kernel(const unsigned short* __restrict__ y1_t,
                                                  const float* __restrict__ w1,
                                                  const float* __restrict__ b1,
                                                  unsigned short* __restrict__ y2_t) {
  const int lane = threadIdx.x & 63, wv = threadIdx.x >> 6;
  const int kq = (lane >> 4) * 8;
  const int oc = lane & 15;
  bf16x8 bf[5];
#pragma unroll
  for (int kk = 0; kk < 5; ++kk) {
    bf16x8 v;
#pragma unroll
    for (int t = 0; t < 8; ++t) {
      int ic = kq + t;
      v[t] = (short)f2b(w1[((size_t)ic * 16 + oc) * 5 + kk]);
    }
    bf[kk] = v;
  }
  const float bia = b1[oc];
  const int base_chunk = blockIdx.x * 32 + wv * 8;
  for (int cc = 0; cc < 8; ++cc) {
    const int chunk = base_chunk + cc;
    int m = chunk * 16 + (lane & 15);
    int img = m / 22, ow = m - img * 22;
    const unsigned short* abase = y1_t + (size_t)img * 18 * 32;
    f32x4 acc = {0.f, 0.f, 0.f, 0.f};
#pragma unroll
    for (int kk = 0; kk < 5; ++kk) {
      int iw = ow - kk;
      bf16x8 a = {0, 0, 0, 0, 0, 0, 0, 0};
      if ((unsigned)iw < 18u) a = *(const bf16x8*)(abase + iw * 32 + kq);
      acc = __builtin_amdgcn_mfma_f32_16x16x32_bf16(a, bf[kk], acc, 0, 0, 0);
    }
#pragma unroll
    for (int r = 0; r < 4; ++r) {
      int mm = chunk * 16 + (lane >> 4) * 4 + r;
      float v = acc[r] + bia;
      v = v > 0.f ? v : 0.01f * v;
      y2_t[(size_t)mm * 16 + oc] = f2b(v);
    }
  }
}

// ---------------------------------------------------------------------------
// dc2 + softmax over oh
// ---------------------------------------------------------------------------
__global__ __launch_bounds__(256) void dc2_kernel(const unsigned short* __restrict__ y2_t,
                                                  const float* __restrict__ w2,
                                                  const float* __restrict__ b2,
                                                  float* __restrict__ out) {
  int idx = blockIdx.x * 256 + threadIdx.x;
  int img = idx / 24, ow = idx - img * 24;
  float lg0 = b2[0], lg1 = b2[0], lg2 = b2[0];
#pragma unroll
  for (int jj = 0; jj < 3; ++jj) {
    int iw = ow - jj;
    if ((unsigned)iw >= 22u) continue;
    const unsigned short* row = y2_t + ((size_t)img * 22 + iw) * 16;
    bf16x8 v0 = *(const bf16x8*)(row);
    bf16x8 v1 = *(const bf16x8*)(row + 8);
    float x[16];
#pragma unroll
    for (int ic = 0; ic < 8; ++ic) {
      x[ic] = b2f((unsigned short)v0[ic]);
      x[8 + ic] = b2f((unsigned short)v1[ic]);
    }
#pragma unroll
    for (int ic = 0; ic < 16; ++ic) {
      lg0 += x[ic] * w2[ic * 9 + 0 * 3 + jj];
      lg1 += x[ic] * w2[ic * 9 + 1 * 3 + jj];
      lg2 += x[ic] * w2[ic * 9 + 2 * 3 + jj];
    }
  }
  lg0 = lg0 > 0.f ? lg0 : 0.01f * lg0;
  lg1 = lg1 > 0.f ? lg1 : 0.01f * lg1;
  lg2 = lg2 > 0.f ? lg2 : 0.01f * lg2;
  float mx = fmaxf(lg0, fmaxf(lg1, lg2));
  float e0 = __expf(lg0 - mx), e1 = __expf(lg1 - mx), e2 = __expf(lg2 - mx);
  float inv = 1.f / (e0 + e1 + e2);
  size_t ob = (size_t)img * 72 + ow;
  out[ob] = e0 * inv;
  out[ob + 24] = e1 * inv;
  out[ob + 48] = e2 * inv;
}

// ---------------------------------------------------------------------------
extern "C" void kernel_launch(void* const* d_in, const int* in_sizes, int n_in,
                              void* d_out, int out_size, void* d_ws, size_t ws_size,
                              hipStream_t stream) {
  (void)in_sizes; (void)n_in; (void)out_size; (void)ws_size;
  const float* enc    = (const float*)d_in[0];
  const float* noise  = (const float*)d_in[1];
  const float* erep_w = (const float*)d_in[2];
  const float* erep_b = (const float*)d_in[3];
  const float* wih_f  = (const float*)d_in[4];
  const float* whh_f  = (const float*)d_in[5];
  const float* bih_f  = (const float*)d_in[6];
  const float* bhh_f  = (const float*)d_in[7];
  const float* wih_b  = (const float*)d_in[8];
  const float* whh_b  = (const float*)d_in[9];
  const float* bih_b  = (const float*)d_in[10];
  const float* bhh_b  = (const float*)d_in[11];
  const float* emb_w  = (const float*)d_in[12];
  const float* emb_b  = (const float*)d_in[13];
  const float* dc3w   = (const float*)d_in[14];
  const float* dc3b   = (const float*)d_in[15];
  const float* dc1w   = (const float*)d_in[16];
  const float* dc1b   = (const float*)d_in[17];
  const float* dc2w   = (const float*)d_in[18];
  const float* dc2b   = (const float*)d_in[19];
  float* out = (float*)d_out;

  char* p = (char*)d_ws;
  auto carve = [&p](size_t bytes) {
    char* r = p;
    p += (bytes + 255) & ~(size_t)255;
    return r;
  };
  unsigned short* rep_t  = (unsigned short*)carve(7ull * 4096 * 256 * 2);
  unsigned short* lstmW  = (unsigned short*)carve(2ull * 2048 * 768 * 2);
  float*          lstmB  = (float*)carve(2ull * 2048 * 4);
  unsigned short* noiseb = (unsigned short*)carve(4096ull * 256 * 2);
  unsigned short* erepT  = (unsigned short*)carve(1792ull * 256 * 2);
  unsigned short* embT   = (unsigned short*)carve(1024ull * 1024 * 2);
  unsigned short* hbuf   = (unsigned short*)carve(4ull * 4096 * 512 * 2);   // [pp][dir]
  unsigned short* cbuf   = (unsigned short*)carve(2ull * 4096 * 512 * 2);   // [dir] bf16
  unsigned short* lstm1  = (unsigned short*)carve(4096ull * 7 * 1024 * 2);
  unsigned short* att    = (unsigned short*)carve(28672ull * 1024 * 2);
  unsigned short* up_t   = (unsigned short*)carve(28672ull * 1024 * 2);
  unsigned short* y1_t   = (unsigned short*)carve(28672ull * 18 * 32 * 2);
  unsigned short* y2_t   = (unsigned short*)carve(28672ull * 22 * 16 * 2);

  hipMemsetAsync(hbuf, 0, 2ull * 4096 * 512 * 2, stream);
  hipMemsetAsync(cbuf, 0, 2ull * 4096 * 512 * 2, stream);

  pack_kernel<<<2048, 256, 0, stream>>>(noise, erep_w, emb_w, wih_f, whh_f, bih_f, bhh_f,
                                        wih_b, whh_b, bih_b, bhh_b,
                                        noiseb, erepT, embT, lstmW, lstmB);
  gemm_rep_kernel<<<dim3(14, 32), 256, 0, stream>>>(noiseb, erepT, erep_b, rep_t);
  for (int s = 0; s < 7; ++s)
    lstm_step256_kernel<<<256, 512, 0, stream>>>(rep_t, lstmW, lstmB, hbuf, cbuf, lstm1, s);
  att_fused3_kernel<<<4096, 256, 0, stream>>>(enc, lstm1, att);
  gemm_emb256_kernel<<<448, 512, 0, stream>>>(att, embT, emb_b, up_t);
  dc3_kernel<<<1008, 256, 0, stream>>>(up_t, dc3w, dc3b, y1_t);
  dc1_kernel<<<1232, 256, 0, stream>>>(y1_t, dc1w, dc1b, y2_t);
  dc2_kernel<<<2688, 256, 0, stream>>>(y2_t, dc2w, dc2b, out);
}